// Round 1
// baseline (649.450 us; speedup 1.0000x reference)
//
#include <hip/hip_runtime.h>
#include <math.h>

// Problem constants (shapes fixed by the reference)
#define D 128
#define HH 128
#define CC 64
#define NLAYERS 3
#define LN_EPS 1e-5f

// ---------------------------------------------------------------------------
// Setup kernels: degree, CSR build (count -> scan -> scatter)
// ---------------------------------------------------------------------------

__global__ void k_zero_cnt(int* __restrict__ cnt, int n) {
    int i = blockIdx.x * blockDim.x + threadIdx.x;
    if (i < n) cnt[i] = 0;
}

__global__ void k_count(const int* __restrict__ dst, int* __restrict__ cnt, int E) {
    int i = blockIdx.x * blockDim.x + threadIdx.x;
    if (i < E) atomicAdd(&cnt[dst[i]], 1);
}

__global__ void k_dinv(const int* __restrict__ cnt, float* __restrict__ dinv, int N) {
    int i = blockIdx.x * blockDim.x + threadIdx.x;
    if (i < N) dinv[i] = rsqrtf(1.0f + (float)cnt[i]);
}

// Per-block exclusive scan of cnt (1024 elems/block), writes block sums.
__global__ void k_scan_a(const int* __restrict__ cnt, int* __restrict__ rowptr,
                         int* __restrict__ bsum, int N) {
    __shared__ int s[1024];
    int tid = threadIdx.x;
    int i = blockIdx.x * 1024 + tid;
    int v = (i < N) ? cnt[i] : 0;
    s[tid] = v;
    __syncthreads();
    for (int off = 1; off < 1024; off <<= 1) {
        int t = (tid >= off) ? s[tid - off] : 0;
        __syncthreads();
        s[tid] += t;
        __syncthreads();
    }
    if (i < N) rowptr[i] = s[tid] - v;   // exclusive within block
    if (tid == 1023) bsum[blockIdx.x] = s[tid];
}

// Exclusive scan of block sums (single wave; nb <= 64)
__global__ void k_scan_b(int* __restrict__ bsum, int nb) {
    int t = threadIdx.x;
    int v = (t < nb) ? bsum[t] : 0;
    int incl = v;
    for (int off = 1; off < 64; off <<= 1) {
        int u = __shfl_up(incl, off, 64);
        if (t >= off) incl += u;
    }
    if (t < nb) bsum[t] = incl - v;
}

__global__ void k_scan_c(int* __restrict__ rowptr, const int* __restrict__ bsum,
                         int* __restrict__ cursor, int N, int E) {
    int i = blockIdx.x * blockDim.x + threadIdx.x;
    if (i < N) {
        int v = rowptr[i] + bsum[i >> 10];
        rowptr[i] = v;
        cursor[i] = v;
    }
    if (i == 0) rowptr[N] = E;
}

__global__ void k_scatter(const int* __restrict__ src, const int* __restrict__ dst,
                          int* __restrict__ cursor, int* __restrict__ colsrc, int E) {
    int i = blockIdx.x * blockDim.x + threadIdx.x;
    if (i < E) {
        int p = atomicAdd(&cursor[dst[i]], 1);
        colsrc[p] = src[i];
    }
}

// ---------------------------------------------------------------------------
// GEMM: OUT[N][128] = A[N][Kdim] @ W[Kdim][128] (+bias) (+relu)
// A is split: k < ksplit reads A0 (stride sA0), else A1 (stride sA1) at k-ksplit.
// Block: 256 threads = 32 colT x 8 rowT; each thread computes 4 rows x 4 cols.
// Block tile: 32 rows x 128 cols; K tiled by 32; A-tile transposed in LDS.
// ---------------------------------------------------------------------------
__global__ __launch_bounds__(256) void k_gemm(
    const float* __restrict__ A0, int sA0,
    const float* __restrict__ A1, int sA1, int ksplit,
    const float* __restrict__ W, const float* __restrict__ bias,
    float* __restrict__ OUT, int sOut,
    int N, int Kdim, int do_relu)
{
    __shared__ float at[32 * 36];    // [kk][r], padded to 36 to keep b128 reads clean
    __shared__ float wt[32 * 128];   // [kk][c]

    int tid = threadIdx.x;
    int colT = tid & 31;
    int rowT = tid >> 5;
    int c0 = colT * 4;
    int r0 = rowT * 4;
    int row0 = blockIdx.x * 32;

    float acc[4][4] = {};

    for (int k0 = 0; k0 < Kdim; k0 += 32) {
        // ---- stage A tile (transposed) ----
        {
            int idx = tid * 4;
            int r = idx >> 5;
            int kk = idx & 31;
            int row = row0 + r;
            int k = k0 + kk;
            float4 v = make_float4(0.f, 0.f, 0.f, 0.f);
            if (row < N) {
                const float* p = (k < ksplit)
                    ? (A0 + (size_t)row * sA0 + k)
                    : (A1 + (size_t)row * sA1 + (k - ksplit));
                v = *(const float4*)p;
            }
            at[(kk + 0) * 36 + r] = v.x;
            at[(kk + 1) * 36 + r] = v.y;
            at[(kk + 2) * 36 + r] = v.z;
            at[(kk + 3) * 36 + r] = v.w;
        }
        // ---- stage W tile ----
        for (int t = tid; t < 1024; t += 256) {
            int kk = t >> 5;
            int c4 = (t & 31) << 2;
            *(float4*)&wt[kk * 128 + c4] = *(const float4*)&W[(size_t)(k0 + kk) * 128 + c4];
        }
        __syncthreads();

        #pragma unroll 8
        for (int kk = 0; kk < 32; ++kk) {
            float4 a = *(const float4*)&at[kk * 36 + r0];
            float4 w = *(const float4*)&wt[kk * 128 + c0];
            acc[0][0] += a.x * w.x; acc[0][1] += a.x * w.y; acc[0][2] += a.x * w.z; acc[0][3] += a.x * w.w;
            acc[1][0] += a.y * w.x; acc[1][1] += a.y * w.y; acc[1][2] += a.y * w.z; acc[1][3] += a.y * w.w;
            acc[2][0] += a.z * w.x; acc[2][1] += a.z * w.y; acc[2][2] += a.z * w.z; acc[2][3] += a.z * w.w;
            acc[3][0] += a.w * w.x; acc[3][1] += a.w * w.y; acc[3][2] += a.w * w.z; acc[3][3] += a.w * w.w;
        }
        __syncthreads();
    }

    float4 bv = make_float4(0.f, 0.f, 0.f, 0.f);
    if (bias) bv = *(const float4*)&bias[c0];
    #pragma unroll
    for (int i = 0; i < 4; ++i) {
        int row = row0 + r0 + i;
        if (row < N) {
            float4 o;
            o.x = acc[i][0] + bv.x;
            o.y = acc[i][1] + bv.y;
            o.z = acc[i][2] + bv.z;
            o.w = acc[i][3] + bv.w;
            if (do_relu) {
                o.x = fmaxf(o.x, 0.f); o.y = fmaxf(o.y, 0.f);
                o.z = fmaxf(o.z, 0.f); o.w = fmaxf(o.w, 0.f);
            }
            *(float4*)&OUT[(size_t)row * sOut + c0] = o;
        }
    }
}

// ---------------------------------------------------------------------------
// Aggregation (symmetric-normalized, self-loop) + bias + LayerNorm + ReLU.
// One 64-lane wave per node; each lane owns 2 features (float2).
// Writes to feats with row stride 3*128.
// ---------------------------------------------------------------------------
__global__ __launch_bounds__(256) void k_agg_ln(
    const float* __restrict__ hW,
    const int* __restrict__ rowptr, const int* __restrict__ colsrc,
    const float* __restrict__ dinv,
    const float* __restrict__ bg, const float* __restrict__ g,
    const float* __restrict__ b,
    float* __restrict__ outF, int N)
{
    int wid = blockIdx.x * 4 + (threadIdx.x >> 6);
    int lane = threadIdx.x & 63;
    if (wid >= N) return;

    int f0 = lane * 2;
    float di = dinv[wid];
    float sc = di * di;

    float2 hv = *(const float2*)(hW + (size_t)wid * HH + f0);
    float ax = hv.x * sc;
    float ay = hv.y * sc;

    int e0 = rowptr[wid];
    int e1 = rowptr[wid + 1];
    for (int e = e0; e < e1; ++e) {
        int s = colsrc[e];
        float c = dinv[s] * di;
        float2 v = *(const float2*)(hW + (size_t)s * HH + f0);
        ax += v.x * c;
        ay += v.y * c;
    }
    ax += bg[f0];
    ay += bg[f0 + 1];

    // LayerNorm over the 128 features held across the wave (2/lane)
    float ssum = ax + ay;
    #pragma unroll
    for (int off = 32; off; off >>= 1) ssum += __shfl_xor(ssum, off, 64);
    float mu = ssum * (1.0f / 128.0f);
    float dx = ax - mu, dy = ay - mu;
    float vsum = dx * dx + dy * dy;
    #pragma unroll
    for (int off = 32; off; off >>= 1) vsum += __shfl_xor(vsum, off, 64);
    float rstd = rsqrtf(vsum * (1.0f / 128.0f) + LN_EPS);

    float ox = g[f0] * dx * rstd + b[f0];
    float oy = g[f0 + 1] * dy * rstd + b[f0 + 1];
    ox = fmaxf(ox, 0.f);
    oy = fmaxf(oy, 0.f);

    float2 o = make_float2(ox, oy);
    *(float2*)(outF + (size_t)wid * (NLAYERS * HH) + f0) = o;
}

// ---------------------------------------------------------------------------
// Final MLP layer 2 (128 -> 64) + softmax. One wave per node; lane = class.
// ---------------------------------------------------------------------------
__global__ __launch_bounds__(256) void k_mlp2(
    const float* __restrict__ z1, const float* __restrict__ W2,
    const float* __restrict__ b2, float* __restrict__ out, int N)
{
    int wid = blockIdx.x * 4 + (threadIdx.x >> 6);
    int lane = threadIdx.x & 63;
    if (wid >= N) return;

    const float* z = z1 + (size_t)wid * HH;
    float acc = b2[lane];
    #pragma unroll 8
    for (int k = 0; k < HH; k += 4) {
        float4 zv = *(const float4*)&z[k];
        acc += zv.x * W2[(k + 0) * CC + lane];
        acc += zv.y * W2[(k + 1) * CC + lane];
        acc += zv.z * W2[(k + 2) * CC + lane];
        acc += zv.w * W2[(k + 3) * CC + lane];
    }
    float m = acc;
    #pragma unroll
    for (int off = 32; off; off >>= 1) m = fmaxf(m, __shfl_xor(m, off, 64));
    float p = __expf(acc - m);
    float s = p;
    #pragma unroll
    for (int off = 32; off; off >>= 1) s += __shfl_xor(s, off, 64);
    out[(size_t)wid * CC + lane] = p / s;
}

// ---------------------------------------------------------------------------
// Host launcher
// ---------------------------------------------------------------------------
extern "C" void kernel_launch(void* const* d_in, const int* in_sizes, int n_in,
                              void* d_out, int out_size, void* d_ws, size_t ws_size,
                              hipStream_t stream) {
    const float* x   = (const float*)d_in[0];
    const int*   ei  = (const int*)  d_in[1];
    const float* Wg  = (const float*)d_in[2];
    const float* bg  = (const float*)d_in[3];
    const float* lng = (const float*)d_in[4];
    const float* lnb = (const float*)d_in[5];
    const float* W1  = (const float*)d_in[6];
    const float* b1  = (const float*)d_in[7];
    const float* W2  = (const float*)d_in[8];
    const float* b2  = (const float*)d_in[9];
    float* out = (float*)d_out;

    const int N = in_sizes[0] / D;
    const int E = in_sizes[1] / 2;
    const int* srcp = ei;
    const int* dstp = ei + E;

    // Workspace carve-up (512B aligned)
    char* ws = (char*)d_ws;
    size_t off = 0;
    auto alloc = [&](size_t bytes) -> void* {
        void* p = ws + off;
        off += (bytes + 511) & ~(size_t)511;
        return p;
    };
    int*   cnt    = (int*)  alloc((size_t)N * 4);
    int*   rowptr = (int*)  alloc((size_t)(N + 1) * 4);
    int*   cursor = (int*)  alloc((size_t)N * 4);
    int*   bsum   = (int*)  alloc(64 * 4);
    int*   colsrc = (int*)  alloc((size_t)E * 4);
    float* dinv   = (float*)alloc((size_t)N * 4);
    float* hW     = (float*)alloc((size_t)N * HH * 4);   // also reused as z1
    float* feats  = (float*)alloc((size_t)N * (NLAYERS * HH) * 4);

    const int B = 256;
    const int gN = (N + B - 1) / B;
    const int gE = (E + B - 1) / B;
    const int nsb = (N + 1023) / 1024;

    k_zero_cnt<<<gN, B, 0, stream>>>(cnt, N);
    k_count<<<gE, B, 0, stream>>>(dstp, cnt, E);
    k_dinv<<<gN, B, 0, stream>>>(cnt, dinv, N);
    k_scan_a<<<nsb, 1024, 0, stream>>>(cnt, rowptr, bsum, N);
    k_scan_b<<<1, 64, 0, stream>>>(bsum, nsb);
    k_scan_c<<<gN, B, 0, stream>>>(rowptr, bsum, cursor, N, E);
    k_scatter<<<gE, B, 0, stream>>>(srcp, dstp, cursor, colsrc, E);

    const int gemmBlocks = (N + 31) / 32;
    const int waveBlocks = (N + 3) / 4;

    for (int l = 0; l < NLAYERS; ++l) {
        const float* A  = (l == 0) ? x : (feats + (size_t)(l - 1) * HH);
        const int    sA = (l == 0) ? D : (NLAYERS * HH);
        // hW = h @ Wg[l]   (NO bias here: bias must be added after aggregation)
        k_gemm<<<gemmBlocks, B, 0, stream>>>(A, sA, A, sA, D,
                                             Wg + (size_t)l * D * HH, nullptr,
                                             hW, HH, N, D, 0);
        k_agg_ln<<<waveBlocks, B, 0, stream>>>(hW, rowptr, colsrc, dinv,
                                               bg + (size_t)l * HH,
                                               lng + (size_t)l * HH,
                                               lnb + (size_t)l * HH,
                                               feats + (size_t)l * HH, N);
    }

    // z1 = relu([x | feats] @ W1 + b1)  -> reuse hW buffer
    k_gemm<<<gemmBlocks, B, 0, stream>>>(x, D, feats, NLAYERS * HH, D,
                                         W1, b1, hW, HH, N, D + NLAYERS * HH, 1);

    // out = softmax(z1 @ W2 + b2)
    k_mlp2<<<waveBlocks, B, 0, stream>>>(hW, W2, b2, out, N);
}

// Round 2
// 573.656 us; speedup vs baseline: 1.1321x; 1.1321x over previous
//
#include <hip/hip_runtime.h>
#include <math.h>

// Problem constants (shapes fixed by the reference)
#define D 128
#define HH 128
#define CC 64
#define NLAYERS 3
#define LN_EPS 1e-5f

typedef __attribute__((ext_vector_type(8))) short bf16x8;
typedef __attribute__((ext_vector_type(4))) float f32x4;
typedef unsigned short u16;
typedef unsigned int u32;

// round-to-nearest-even fp32 -> bf16 bits
__device__ __forceinline__ u16 f2bf(float f) {
    u32 u = __float_as_uint(f);
    u32 r = u + 0x7FFFu + ((u >> 16) & 1u);
    return (u16)(r >> 16);
}
__device__ __forceinline__ float bf2f(u16 h) {
    return __uint_as_float(((u32)h) << 16);
}

// ---------------------------------------------------------------------------
// Setup kernels: degree, CSR build (count -> scan -> scatter)
// ---------------------------------------------------------------------------

__global__ void k_zero_cnt(int* __restrict__ cnt, int n) {
    int i = blockIdx.x * blockDim.x + threadIdx.x;
    if (i < n) cnt[i] = 0;
}

__global__ void k_count(const int* __restrict__ dst, int* __restrict__ cnt, int E) {
    int i = blockIdx.x * blockDim.x + threadIdx.x;
    if (i < E) atomicAdd(&cnt[dst[i]], 1);
}

__global__ void k_dinv(const int* __restrict__ cnt, float* __restrict__ dinv, int N) {
    int i = blockIdx.x * blockDim.x + threadIdx.x;
    if (i < N) dinv[i] = rsqrtf(1.0f + (float)cnt[i]);
}

__global__ void k_scan_a(const int* __restrict__ cnt, int* __restrict__ rowptr,
                         int* __restrict__ bsum, int N) {
    __shared__ int s[1024];
    int tid = threadIdx.x;
    int i = blockIdx.x * 1024 + tid;
    int v = (i < N) ? cnt[i] : 0;
    s[tid] = v;
    __syncthreads();
    for (int off = 1; off < 1024; off <<= 1) {
        int t = (tid >= off) ? s[tid - off] : 0;
        __syncthreads();
        s[tid] += t;
        __syncthreads();
    }
    if (i < N) rowptr[i] = s[tid] - v;
    if (tid == 1023) bsum[blockIdx.x] = s[tid];
}

__global__ void k_scan_b(int* __restrict__ bsum, int nb) {
    int t = threadIdx.x;
    int v = (t < nb) ? bsum[t] : 0;
    int incl = v;
    for (int off = 1; off < 64; off <<= 1) {
        int u = __shfl_up(incl, off, 64);
        if (t >= off) incl += u;
    }
    if (t < nb) bsum[t] = incl - v;
}

__global__ void k_scan_c(int* __restrict__ rowptr, const int* __restrict__ bsum,
                         int* __restrict__ cursor, int N, int E) {
    int i = blockIdx.x * blockDim.x + threadIdx.x;
    if (i < N) {
        int v = rowptr[i] + bsum[i >> 10];
        rowptr[i] = v;
        cursor[i] = v;
    }
    if (i == 0) rowptr[N] = E;
}

__global__ void k_scatter(const int* __restrict__ src, const int* __restrict__ dst,
                          int* __restrict__ cursor, int* __restrict__ colsrc, int E) {
    int i = blockIdx.x * blockDim.x + threadIdx.x;
    if (i < E) {
        int p = atomicAdd(&cursor[dst[i]], 1);
        colsrc[p] = src[i];
    }
}

// ---------------------------------------------------------------------------
// Split conversions: x -> xc cols 0:128 (hi/lo bf16); weights -> MFMA-tiled hi/lo
// ---------------------------------------------------------------------------

__global__ void k_split_x(const float* __restrict__ x, u16* __restrict__ xh,
                          u16* __restrict__ xl, int total) {
    int i = blockIdx.x * blockDim.x + threadIdx.x;
    if (i >= total) return;
    int row = i >> 7, c = i & 127;
    float v = x[i];
    u16 h = f2bf(v);
    u16 l = f2bf(v - bf2f(h));
    xh[(size_t)row * 512 + c] = h;
    xl[(size_t)row * 512 + c] = l;
}

// W[K][128] (row-major) -> tiled [kc][q][n][j] where k = kc*32 + q*8 + j
__global__ void k_tile_w(const float* __restrict__ W, u16* __restrict__ th,
                         u16* __restrict__ tl, int KN) {
    int idx = blockIdx.x * blockDim.x + threadIdx.x;
    if (idx >= KN) return;
    int k = idx >> 7, n = idx & 127;
    int kc = k >> 5, q = (k >> 3) & 3, j = k & 7;
    float v = W[idx];
    u16 h = f2bf(v);
    u16 l = f2bf(v - bf2f(h));
    int o = ((kc * 4 + q) * 128 + n) * 8 + j;
    th[o] = h;
    tl[o] = l;
}

// ---------------------------------------------------------------------------
// Split-bf16 MFMA GEMM: OUT[N][128] = A[N][Kdim] @ W[Kdim][128] (+bias)(+relu)
// A given as hi/lo bf16 in xc layout (row stride 512, column offset colOff).
// W given pre-tiled hi/lo (fragment-contiguous). Block: 256 thr = 4 waves,
// tile 64 rows x 128 cols; wave tile 32x64 = 2x4 tiles of 16x16; BK=32.
// C = Ah@Wh + Ah@Wl + Al@Wh  (split-precision, ~2^-17 relative error)
// ---------------------------------------------------------------------------
__global__ __launch_bounds__(256) void k_gemm_mfma(
    const u16* __restrict__ Ahi, const u16* __restrict__ Alo, int colOff,
    const u16* __restrict__ Bhi, const u16* __restrict__ Blo,
    const float* __restrict__ bias, float* __restrict__ OUT,
    int N, int Kdim, int do_relu)
{
    __shared__ u16 sAh[4 * 64 * 8];    // [q][r][j]
    __shared__ u16 sAl[4 * 64 * 8];
    __shared__ u16 sBh[4 * 128 * 8];   // [q][n][j]
    __shared__ u16 sBl[4 * 128 * 8];

    const int tid  = threadIdx.x;
    const int lane = tid & 63;
    const int wave = tid >> 6;
    const int wr   = wave & 1;   // row half -> 32 rows
    const int wc   = wave >> 1;  // col half -> 64 cols
    const int quad = lane >> 4;
    const int l15  = lane & 15;
    const int row0 = blockIdx.x * 64;

    // A staging: thread handles (q = tid>>6, r = tid&63), one 16B hi + 16B lo
    const int sq = tid >> 6;
    const int sr = tid & 63;
    int arow = row0 + sr;
    if (arow >= N) arow = N - 1;                  // clamp: OOB rows read valid data, write masked
    const size_t aoff = (size_t)arow * 512 + colOff + sq * 8;

    // B staging: elements u in {tid, tid+256}: q = u>>7, n = u&127
    const int bq0 = tid >> 7, bn0 = tid & 127;
    const int bq1 = bq0 + 2;

    f32x4 acc[2][4];
    #pragma unroll
    for (int i = 0; i < 2; ++i)
        #pragma unroll
        for (int j = 0; j < 4; ++j)
            #pragma unroll
            for (int r = 0; r < 4; ++r) acc[i][j][r] = 0.f;

    const int nch = Kdim >> 5;
    for (int kc = 0; kc < nch; ++kc) {
        if (kc) __syncthreads();
        // ---- stage A tile (hi+lo)
        *(uint4*)&sAh[(sq * 64 + sr) * 8] = *(const uint4*)(Ahi + aoff + kc * 32);
        *(uint4*)&sAl[(sq * 64 + sr) * 8] = *(const uint4*)(Alo + aoff + kc * 32);
        // ---- stage B tile (hi+lo), pre-tiled so copies are contiguous
        {
            const size_t base = (size_t)kc * 4096;
            *(uint4*)&sBh[(bq0 * 128 + bn0) * 8] = *(const uint4*)&Bhi[base + (bq0 * 128 + bn0) * 8];
            *(uint4*)&sBh[(bq1 * 128 + bn0) * 8] = *(const uint4*)&Bhi[base + (bq1 * 128 + bn0) * 8];
            *(uint4*)&sBl[(bq0 * 128 + bn0) * 8] = *(const uint4*)&Blo[base + (bq0 * 128 + bn0) * 8];
            *(uint4*)&sBl[(bq1 * 128 + bn0) * 8] = *(const uint4*)&Blo[base + (bq1 * 128 + bn0) * 8];
        }
        __syncthreads();

        bf16x8 ah[2], al[2], bh[4], bl[4];
        #pragma unroll
        for (int i = 0; i < 2; ++i) {
            int r = wr * 32 + i * 16 + l15;
            ah[i] = *(const bf16x8*)&sAh[(quad * 64 + r) * 8];
            al[i] = *(const bf16x8*)&sAl[(quad * 64 + r) * 8];
        }
        #pragma unroll
        for (int j = 0; j < 4; ++j) {
            int n = wc * 64 + j * 16 + l15;
            bh[j] = *(const bf16x8*)&sBh[(quad * 128 + n) * 8];
            bl[j] = *(const bf16x8*)&sBl[(quad * 128 + n) * 8];
        }
        #pragma unroll
        for (int i = 0; i < 2; ++i)
            #pragma unroll
            for (int j = 0; j < 4; ++j) {
                acc[i][j] = __builtin_amdgcn_mfma_f32_16x16x32_bf16(ah[i], bh[j], acc[i][j], 0, 0, 0);
                acc[i][j] = __builtin_amdgcn_mfma_f32_16x16x32_bf16(ah[i], bl[j], acc[i][j], 0, 0, 0);
                acc[i][j] = __builtin_amdgcn_mfma_f32_16x16x32_bf16(al[i], bh[j], acc[i][j], 0, 0, 0);
            }
    }

    // epilogue: C/D layout col = lane&15, row = quad*4 + reg
    #pragma unroll
    for (int i = 0; i < 2; ++i) {
        #pragma unroll
        for (int j = 0; j < 4; ++j) {
            int col = wc * 64 + j * 16 + l15;
            float bv = bias ? bias[col] : 0.f;
            #pragma unroll
            for (int r = 0; r < 4; ++r) {
                int grow = row0 + wr * 32 + i * 16 + quad * 4 + r;
                if (grow < N) {
                    float v = acc[i][j][r] + bv;
                    if (do_relu) v = fmaxf(v, 0.f);
                    OUT[(size_t)grow * 128 + col] = v;
                }
            }
        }
    }
}

// ---------------------------------------------------------------------------
// Aggregation (symmetric-normalized, self-loop) + bias + LayerNorm + ReLU.
// One 64-lane wave per node; lane owns 2 features. Writes bf16 hi/lo into xc.
// ---------------------------------------------------------------------------
__global__ __launch_bounds__(256) void k_agg_ln(
    const float* __restrict__ hW,
    const int* __restrict__ rowptr, const int* __restrict__ colsrc,
    const float* __restrict__ dinv,
    const float* __restrict__ bg, const float* __restrict__ g,
    const float* __restrict__ b,
    u16* __restrict__ outHi, u16* __restrict__ outLo, int N)
{
    int wid = blockIdx.x * 4 + (threadIdx.x >> 6);
    int lane = threadIdx.x & 63;
    if (wid >= N) return;

    int f0 = lane * 2;
    float di = dinv[wid];
    float sc = di * di;

    float2 hv = *(const float2*)(hW + (size_t)wid * HH + f0);
    float ax = hv.x * sc;
    float ay = hv.y * sc;

    int e0 = rowptr[wid];
    int e1 = rowptr[wid + 1];
    for (int e = e0; e < e1; ++e) {
        int s = colsrc[e];
        float c = dinv[s] * di;
        float2 v = *(const float2*)(hW + (size_t)s * HH + f0);
        ax += v.x * c;
        ay += v.y * c;
    }
    ax += bg[f0];
    ay += bg[f0 + 1];

    float ssum = ax + ay;
    #pragma unroll
    for (int off = 32; off; off >>= 1) ssum += __shfl_xor(ssum, off, 64);
    float mu = ssum * (1.0f / 128.0f);
    float dx = ax - mu, dy = ay - mu;
    float vsum = dx * dx + dy * dy;
    #pragma unroll
    for (int off = 32; off; off >>= 1) vsum += __shfl_xor(vsum, off, 64);
    float rstd = rsqrtf(vsum * (1.0f / 128.0f) + LN_EPS);

    float ox = fmaxf(g[f0] * dx * rstd + b[f0], 0.f);
    float oy = fmaxf(g[f0 + 1] * dy * rstd + b[f0 + 1], 0.f);

    u16 hx = f2bf(ox); u16 lx = f2bf(ox - bf2f(hx));
    u16 hy = f2bf(oy); u16 ly = f2bf(oy - bf2f(hy));
    *(u32*)&outHi[(size_t)wid * 512 + f0] = (u32)hx | ((u32)hy << 16);
    *(u32*)&outLo[(size_t)wid * 512 + f0] = (u32)lx | ((u32)ly << 16);
}

// ---------------------------------------------------------------------------
// Final MLP layer 2 (128 -> 64) + softmax. One wave per node; lane = class.
// ---------------------------------------------------------------------------
__global__ __launch_bounds__(256) void k_mlp2(
    const float* __restrict__ z1, const float* __restrict__ W2,
    const float* __restrict__ b2, float* __restrict__ out, int N)
{
    int wid = blockIdx.x * 4 + (threadIdx.x >> 6);
    int lane = threadIdx.x & 63;
    if (wid >= N) return;

    const float* z = z1 + (size_t)wid * HH;
    float acc = b2[lane];
    #pragma unroll 8
    for (int k = 0; k < HH; k += 4) {
        float4 zv = *(const float4*)&z[k];
        acc += zv.x * W2[(k + 0) * CC + lane];
        acc += zv.y * W2[(k + 1) * CC + lane];
        acc += zv.z * W2[(k + 2) * CC + lane];
        acc += zv.w * W2[(k + 3) * CC + lane];
    }
    float m = acc;
    #pragma unroll
    for (int off = 32; off; off >>= 1) m = fmaxf(m, __shfl_xor(m, off, 64));
    float p = __expf(acc - m);
    float s = p;
    #pragma unroll
    for (int off = 32; off; off >>= 1) s += __shfl_xor(s, off, 64);
    out[(size_t)wid * CC + lane] = p / s;
}

// ---------------------------------------------------------------------------
// Host launcher
// ---------------------------------------------------------------------------
extern "C" void kernel_launch(void* const* d_in, const int* in_sizes, int n_in,
                              void* d_out, int out_size, void* d_ws, size_t ws_size,
                              hipStream_t stream) {
    const float* x   = (const float*)d_in[0];
    const int*   ei  = (const int*)  d_in[1];
    const float* Wg  = (const float*)d_in[2];
    const float* bg  = (const float*)d_in[3];
    const float* lng = (const float*)d_in[4];
    const float* lnb = (const float*)d_in[5];
    const float* W1  = (const float*)d_in[6];
    const float* b1  = (const float*)d_in[7];
    const float* W2  = (const float*)d_in[8];
    const float* b2  = (const float*)d_in[9];
    float* out = (float*)d_out;

    const int N = in_sizes[0] / D;
    const int E = in_sizes[1] / 2;
    const int* srcp = ei;
    const int* dstp = ei + E;

    char* ws = (char*)d_ws;
    size_t off = 0;
    auto alloc = [&](size_t bytes) -> void* {
        void* p = ws + off;
        off += (bytes + 511) & ~(size_t)511;
        return p;
    };
    int*   cnt    = (int*)  alloc((size_t)N * 4);
    int*   rowptr = (int*)  alloc((size_t)(N + 1) * 4);
    int*   cursor = (int*)  alloc((size_t)N * 4);
    int*   bsum   = (int*)  alloc(64 * 4);
    int*   colsrc = (int*)  alloc((size_t)E * 4);
    float* dinv   = (float*)alloc((size_t)N * 4);
    float* hW     = (float*)alloc((size_t)N * HH * 4);       // GEMM fp32 out; reused as z1
    u16*   xcH    = (u16*)  alloc((size_t)N * 512 * 2);      // [x|f1|f2|f3] hi
    u16*   xcL    = (u16*)  alloc((size_t)N * 512 * 2);      // lo
    u16*   WgtH   = (u16*)  alloc((size_t)NLAYERS * D * HH * 2);
    u16*   WgtL   = (u16*)  alloc((size_t)NLAYERS * D * HH * 2);
    u16*   W1tH   = (u16*)  alloc((size_t)(D + NLAYERS * HH) * HH * 2);
    u16*   W1tL   = (u16*)  alloc((size_t)(D + NLAYERS * HH) * HH * 2);

    const int B = 256;
    const int gN = (N + B - 1) / B;
    const int gE = (E + B - 1) / B;
    const int nsb = (N + 1023) / 1024;

    k_zero_cnt<<<gN, B, 0, stream>>>(cnt, N);
    k_count<<<gE, B, 0, stream>>>(dstp, cnt, E);
    k_dinv<<<gN, B, 0, stream>>>(cnt, dinv, N);
    k_scan_a<<<nsb, 1024, 0, stream>>>(cnt, rowptr, bsum, N);
    k_scan_b<<<1, 64, 0, stream>>>(bsum, nsb);
    k_scan_c<<<gN, B, 0, stream>>>(rowptr, bsum, cursor, N, E);
    k_scatter<<<gE, B, 0, stream>>>(srcp, dstp, cursor, colsrc, E);

    // Split conversions
    k_split_x<<<(N * D + B - 1) / B, B, 0, stream>>>(x, xcH, xcL, N * D);
    for (int l = 0; l < NLAYERS; ++l)
        k_tile_w<<<(D * HH + B - 1) / B, B, 0, stream>>>(Wg + (size_t)l * D * HH,
                                                         WgtH + (size_t)l * D * HH,
                                                         WgtL + (size_t)l * D * HH, D * HH);
    k_tile_w<<<((D + NLAYERS * HH) * HH + B - 1) / B, B, 0, stream>>>(W1, W1tH, W1tL,
                                                                      (D + NLAYERS * HH) * HH);

    const int gemmBlocks = (N + 63) / 64;
    const int waveBlocks = (N + 3) / 4;

    for (int l = 0; l < NLAYERS; ++l) {
        // hW = h @ Wg[l]  (bias added after aggregation)
        k_gemm_mfma<<<gemmBlocks, B, 0, stream>>>(xcH, xcL, l * HH,
                                                  WgtH + (size_t)l * D * HH,
                                                  WgtL + (size_t)l * D * HH,
                                                  nullptr, hW, N, D, 0);
        k_agg_ln<<<waveBlocks, B, 0, stream>>>(hW, rowptr, colsrc, dinv,
                                               bg + (size_t)l * HH,
                                               lng + (size_t)l * HH,
                                               lnb + (size_t)l * HH,
                                               xcH + (size_t)(l + 1) * HH,
                                               xcL + (size_t)(l + 1) * HH, N);
    }

    // z1 = relu([x|f1|f2|f3] @ W1 + b1) -> hW
    k_gemm_mfma<<<gemmBlocks, B, 0, stream>>>(xcH, xcL, 0, W1tH, W1tL,
                                              b1, hW, N, D + NLAYERS * HH, 1);

    // out = softmax(z1 @ W2 + b2)
    k_mlp2<<<waveBlocks, B, 0, stream>>>(hW, W2, b2, out, N);
}

// Round 3
// 440.890 us; speedup vs baseline: 1.4730x; 1.3011x over previous
//
#include <hip/hip_runtime.h>
#include <math.h>

// Problem constants (shapes fixed by the reference)
#define D 128
#define HH 128
#define CC 64
#define NLAYERS 3
#define LN_EPS 1e-5f

typedef __attribute__((ext_vector_type(8))) short bf16x8;
typedef __attribute__((ext_vector_type(4))) float f32x4;
typedef unsigned short u16;
typedef unsigned int u32;

// round-to-nearest-even fp32 -> bf16 bits
__device__ __forceinline__ u16 f2bf(float f) {
    u32 u = __float_as_uint(f);
    u32 r = u + 0x7FFFu + ((u >> 16) & 1u);
    return (u16)(r >> 16);
}
__device__ __forceinline__ float bf2f(u16 h) {
    return __uint_as_float(((u32)h) << 16);
}

// ---------------------------------------------------------------------------
// Setup kernels: degree, CSR build (count -> scan -> scatter)
// ---------------------------------------------------------------------------

__global__ void k_zero_cnt(int* __restrict__ cnt, int n) {
    int i = blockIdx.x * blockDim.x + threadIdx.x;
    if (i < n) cnt[i] = 0;
}

__global__ void k_count(const int* __restrict__ dst, int* __restrict__ cnt, int E) {
    int i = blockIdx.x * blockDim.x + threadIdx.x;
    if (i < E) atomicAdd(&cnt[dst[i]], 1);
}

__global__ void k_dinv(const int* __restrict__ cnt, float* __restrict__ dinv, int N) {
    int i = blockIdx.x * blockDim.x + threadIdx.x;
    if (i < N) dinv[i] = rsqrtf(1.0f + (float)cnt[i]);
}

__global__ void k_scan_a(const int* __restrict__ cnt, int* __restrict__ rowptr,
                         int* __restrict__ bsum, int N) {
    __shared__ int s[1024];
    int tid = threadIdx.x;
    int i = blockIdx.x * 1024 + tid;
    int v = (i < N) ? cnt[i] : 0;
    s[tid] = v;
    __syncthreads();
    for (int off = 1; off < 1024; off <<= 1) {
        int t = (tid >= off) ? s[tid - off] : 0;
        __syncthreads();
        s[tid] += t;
        __syncthreads();
    }
    if (i < N) rowptr[i] = s[tid] - v;
    if (tid == 1023) bsum[blockIdx.x] = s[tid];
}

__global__ void k_scan_b(int* __restrict__ bsum, int nb) {
    int t = threadIdx.x;
    int v = (t < nb) ? bsum[t] : 0;
    int incl = v;
    for (int off = 1; off < 64; off <<= 1) {
        int u = __shfl_up(incl, off, 64);
        if (t >= off) incl += u;
    }
    if (t < nb) bsum[t] = incl - v;
}

__global__ void k_scan_c(int* __restrict__ rowptr, const int* __restrict__ bsum,
                         int* __restrict__ cursor, int N, int E) {
    int i = blockIdx.x * blockDim.x + threadIdx.x;
    if (i < N) {
        int v = rowptr[i] + bsum[i >> 10];
        rowptr[i] = v;
        cursor[i] = v;
    }
    if (i == 0) rowptr[N] = E;
}

__global__ void k_scatter(const int* __restrict__ src, const int* __restrict__ dst,
                          int* __restrict__ cursor, int* __restrict__ colsrc, int E) {
    int i = blockIdx.x * blockDim.x + threadIdx.x;
    if (i < E) {
        int p = atomicAdd(&cursor[dst[i]], 1);
        colsrc[p] = src[i];
    }
}

// ---------------------------------------------------------------------------
// Split conversions: x -> xc cols 0:128 (hi/lo bf16); weights -> MFMA-tiled hi/lo
// ---------------------------------------------------------------------------

__global__ void k_split_x(const float* __restrict__ x, u16* __restrict__ xh,
                          u16* __restrict__ xl, int total) {
    int i = blockIdx.x * blockDim.x + threadIdx.x;
    if (i >= total) return;
    int row = i >> 7, c = i & 127;
    float v = x[i];
    u16 h = f2bf(v);
    u16 l = f2bf(v - bf2f(h));
    xh[(size_t)row * 512 + c] = h;
    xl[(size_t)row * 512 + c] = l;
}

// W[K][Ncols] (row-major, Ncols = 1<<nshift) -> tiled [kc][q][n][j], k = kc*32+q*8+j
__global__ void k_tile_w(const float* __restrict__ W, u16* __restrict__ th,
                         u16* __restrict__ tl, int KN, int nshift) {
    int idx = blockIdx.x * blockDim.x + threadIdx.x;
    if (idx >= KN) return;
    int k = idx >> nshift, n = idx & ((1 << nshift) - 1);
    int kc = k >> 5, q = (k >> 3) & 3, j = k & 7;
    float v = W[idx];
    u16 h = f2bf(v);
    u16 l = f2bf(v - bf2f(h));
    int o = (((kc * 4 + q) << nshift) + n) * 8 + j;
    th[o] = h;
    tl[o] = l;
}

// ---------------------------------------------------------------------------
// Split-bf16 MFMA GEMM: OUT[N][128] = A[N][Kdim] @ W[Kdim][128] (+bias)(+relu)
// C = Ah@Wh + Ah@Wl + Al@Wh  (split-precision, ~2^-17 relative error)
// ---------------------------------------------------------------------------
__global__ __launch_bounds__(256) void k_gemm_mfma(
    const u16* __restrict__ Ahi, const u16* __restrict__ Alo, int colOff,
    const u16* __restrict__ Bhi, const u16* __restrict__ Blo,
    const float* __restrict__ bias, float* __restrict__ OUT,
    int N, int Kdim, int do_relu)
{
    __shared__ u16 sAh[4 * 64 * 8];    // [q][r][j]
    __shared__ u16 sAl[4 * 64 * 8];
    __shared__ u16 sBh[4 * 128 * 8];   // [q][n][j]
    __shared__ u16 sBl[4 * 128 * 8];

    const int tid  = threadIdx.x;
    const int lane = tid & 63;
    const int wave = tid >> 6;
    const int wr   = wave & 1;   // row half -> 32 rows
    const int wc   = wave >> 1;  // col half -> 64 cols
    const int quad = lane >> 4;
    const int l15  = lane & 15;
    const int row0 = blockIdx.x * 64;

    const int sq = tid >> 6;
    const int sr = tid & 63;
    int arow = row0 + sr;
    if (arow >= N) arow = N - 1;
    const size_t aoff = (size_t)arow * 512 + colOff + sq * 8;

    const int bq0 = tid >> 7, bn0 = tid & 127;
    const int bq1 = bq0 + 2;

    f32x4 acc[2][4];
    #pragma unroll
    for (int i = 0; i < 2; ++i)
        #pragma unroll
        for (int j = 0; j < 4; ++j)
            #pragma unroll
            for (int r = 0; r < 4; ++r) acc[i][j][r] = 0.f;

    const int nch = Kdim >> 5;
    for (int kc = 0; kc < nch; ++kc) {
        if (kc) __syncthreads();
        *(uint4*)&sAh[(sq * 64 + sr) * 8] = *(const uint4*)(Ahi + aoff + kc * 32);
        *(uint4*)&sAl[(sq * 64 + sr) * 8] = *(const uint4*)(Alo + aoff + kc * 32);
        {
            const size_t base = (size_t)kc * 4096;
            *(uint4*)&sBh[(bq0 * 128 + bn0) * 8] = *(const uint4*)&Bhi[base + (bq0 * 128 + bn0) * 8];
            *(uint4*)&sBh[(bq1 * 128 + bn0) * 8] = *(const uint4*)&Bhi[base + (bq1 * 128 + bn0) * 8];
            *(uint4*)&sBl[(bq0 * 128 + bn0) * 8] = *(const uint4*)&Blo[base + (bq0 * 128 + bn0) * 8];
            *(uint4*)&sBl[(bq1 * 128 + bn0) * 8] = *(const uint4*)&Blo[base + (bq1 * 128 + bn0) * 8];
        }
        __syncthreads();

        bf16x8 ah[2], al[2], bh[4], bl[4];
        #pragma unroll
        for (int i = 0; i < 2; ++i) {
            int r = wr * 32 + i * 16 + l15;
            ah[i] = *(const bf16x8*)&sAh[(quad * 64 + r) * 8];
            al[i] = *(const bf16x8*)&sAl[(quad * 64 + r) * 8];
        }
        #pragma unroll
        for (int j = 0; j < 4; ++j) {
            int n = wc * 64 + j * 16 + l15;
            bh[j] = *(const bf16x8*)&sBh[(quad * 128 + n) * 8];
            bl[j] = *(const bf16x8*)&sBl[(quad * 128 + n) * 8];
        }
        #pragma unroll
        for (int i = 0; i < 2; ++i)
            #pragma unroll
            for (int j = 0; j < 4; ++j) {
                acc[i][j] = __builtin_amdgcn_mfma_f32_16x16x32_bf16(ah[i], bh[j], acc[i][j], 0, 0, 0);
                acc[i][j] = __builtin_amdgcn_mfma_f32_16x16x32_bf16(ah[i], bl[j], acc[i][j], 0, 0, 0);
                acc[i][j] = __builtin_amdgcn_mfma_f32_16x16x32_bf16(al[i], bh[j], acc[i][j], 0, 0, 0);
            }
    }

    #pragma unroll
    for (int i = 0; i < 2; ++i) {
        #pragma unroll
        for (int j = 0; j < 4; ++j) {
            int col = wc * 64 + j * 16 + l15;
            float bv = bias ? bias[col] : 0.f;
            #pragma unroll
            for (int r = 0; r < 4; ++r) {
                int grow = row0 + wr * 32 + i * 16 + quad * 4 + r;
                if (grow < N) {
                    float v = acc[i][j][r] + bv;
                    if (do_relu) v = fmaxf(v, 0.f);
                    OUT[(size_t)grow * 128 + col] = v;
                }
            }
        }
    }
}

// ---------------------------------------------------------------------------
// Aggregation (symmetric-normalized, self-loop) + bias + LayerNorm + ReLU.
// One 64-lane wave per node; lane owns 2 features. Edge loop unrolled x2.
// ---------------------------------------------------------------------------
__global__ __launch_bounds__(256) void k_agg_ln(
    const float* __restrict__ hW,
    const int* __restrict__ rowptr, const int* __restrict__ colsrc,
    const float* __restrict__ dinv,
    const float* __restrict__ bg, const float* __restrict__ g,
    const float* __restrict__ b,
    u16* __restrict__ outHi, u16* __restrict__ outLo, int N)
{
    int wid = blockIdx.x * 4 + (threadIdx.x >> 6);
    int lane = threadIdx.x & 63;
    if (wid >= N) return;

    int f0 = lane * 2;
    float di = dinv[wid];
    float sc = di * di;

    float2 hv = *(const float2*)(hW + (size_t)wid * HH + f0);
    float ax = hv.x * sc;
    float ay = hv.y * sc;
    float ax1 = 0.f, ay1 = 0.f;

    int e0 = rowptr[wid];
    int e1 = rowptr[wid + 1];
    int e = e0;
    for (; e + 2 <= e1; e += 2) {
        int s0 = colsrc[e];
        int s1 = colsrc[e + 1];
        float c0 = dinv[s0] * di;
        float c1 = dinv[s1] * di;
        float2 v0 = *(const float2*)(hW + (size_t)s0 * HH + f0);
        float2 v1 = *(const float2*)(hW + (size_t)s1 * HH + f0);
        ax += v0.x * c0; ay += v0.y * c0;
        ax1 += v1.x * c1; ay1 += v1.y * c1;
    }
    if (e < e1) {
        int s = colsrc[e];
        float c = dinv[s] * di;
        float2 v = *(const float2*)(hW + (size_t)s * HH + f0);
        ax += v.x * c; ay += v.y * c;
    }
    ax += ax1; ay += ay1;
    ax += bg[f0];
    ay += bg[f0 + 1];

    float ssum = ax + ay;
    #pragma unroll
    for (int off = 32; off; off >>= 1) ssum += __shfl_xor(ssum, off, 64);
    float mu = ssum * (1.0f / 128.0f);
    float dx = ax - mu, dy = ay - mu;
    float vsum = dx * dx + dy * dy;
    #pragma unroll
    for (int off = 32; off; off >>= 1) vsum += __shfl_xor(vsum, off, 64);
    float rstd = rsqrtf(vsum * (1.0f / 128.0f) + LN_EPS);

    float ox = fmaxf(g[f0] * dx * rstd + b[f0], 0.f);
    float oy = fmaxf(g[f0 + 1] * dy * rstd + b[f0 + 1], 0.f);

    u16 hx = f2bf(ox); u16 lx = f2bf(ox - bf2f(hx));
    u16 hy = f2bf(oy); u16 ly = f2bf(oy - bf2f(hy));
    *(u32*)&outHi[(size_t)wid * 512 + f0] = (u32)hx | ((u32)hy << 16);
    *(u32*)&outLo[(size_t)wid * 512 + f0] = (u32)lx | ((u32)ly << 16);
}

// ---------------------------------------------------------------------------
// MLP layer 2 (128 -> 64) + softmax, via split-bf16 MFMA.
// Block = 256 thr (4 waves), tile 64 rows x 64 cols, K=128.
// z1 (fp32) staged to LDS as hi/lo bf16; W2 pre-tiled hi/lo read from L2.
// Softmax fused in C-layout: row's 64 classes = 4 j-tiles x 16 lanes (same quad).
// ---------------------------------------------------------------------------
__global__ __launch_bounds__(256) void k_mlp2_mfma(
    const float* __restrict__ z1,
    const u16* __restrict__ Bhi, const u16* __restrict__ Blo,
    const float* __restrict__ b2, float* __restrict__ out, int N)
{
    __shared__ u16 sZh[64 * 128];   // [(qq*64 + r)*8 + j], k = qq*8+j
    __shared__ u16 sZl[64 * 128];

    const int tid  = threadIdx.x;
    const int lane = tid & 63;
    const int wave = tid >> 6;
    const int quad = lane >> 4;
    const int l15  = lane & 15;
    const int row0 = blockIdx.x * 64;

    // ---- stage z1 tile: thread handles row r = tid>>2, k-range kq*32..+32
    {
        const int r  = tid >> 2;
        const int kq = tid & 3;
        int arow = row0 + r;
        if (arow >= N) arow = N - 1;
        const float* src = z1 + (size_t)arow * 128 + kq * 32;
        #pragma unroll
        for (int p = 0; p < 4; ++p) {          // p = i-pair; covers k = kq*32 + p*8 .. +7
            float4 v0 = *(const float4*)(src + p * 8);
            float4 v1 = *(const float4*)(src + p * 8 + 4);
            u16 h[8], l[8];
            float vv[8] = {v0.x, v0.y, v0.z, v0.w, v1.x, v1.y, v1.z, v1.w};
            #pragma unroll
            for (int t = 0; t < 8; ++t) {
                h[t] = f2bf(vv[t]);
                l[t] = f2bf(vv[t] - bf2f(h[t]));
            }
            int qq = kq * 4 + p;               // k = qq*8 + j
            *(uint4*)&sZh[(qq * 64 + r) * 8] = *(uint4*)h;
            *(uint4*)&sZl[(qq * 64 + r) * 8] = *(uint4*)l;
        }
    }
    __syncthreads();

    f32x4 acc[4];
    #pragma unroll
    for (int j = 0; j < 4; ++j)
        #pragma unroll
        for (int r = 0; r < 4; ++r) acc[j][r] = 0.f;

    #pragma unroll
    for (int kc = 0; kc < 4; ++kc) {
        int qq = kc * 4 + quad;
        bf16x8 ah = *(const bf16x8*)&sZh[(qq * 64 + wave * 16 + l15) * 8];
        bf16x8 al = *(const bf16x8*)&sZl[(qq * 64 + wave * 16 + l15) * 8];
        #pragma unroll
        for (int jt = 0; jt < 4; ++jt) {
            int n = jt * 16 + l15;
            bf16x8 bh = *(const bf16x8*)&Bhi[(qq * 64 + n) * 8];
            bf16x8 bl = *(const bf16x8*)&Blo[(qq * 64 + n) * 8];
            acc[jt] = __builtin_amdgcn_mfma_f32_16x16x32_bf16(ah, bh, acc[jt], 0, 0, 0);
            acc[jt] = __builtin_amdgcn_mfma_f32_16x16x32_bf16(ah, bl, acc[jt], 0, 0, 0);
            acc[jt] = __builtin_amdgcn_mfma_f32_16x16x32_bf16(al, bh, acc[jt], 0, 0, 0);
        }
    }

    // bias + softmax + store. Row = row0 + wave*16 + quad*4 + r; col = jt*16 + l15.
    #pragma unroll
    for (int jt = 0; jt < 4; ++jt) {
        float bv = b2[jt * 16 + l15];
        #pragma unroll
        for (int r = 0; r < 4; ++r) acc[jt][r] += bv;
    }
    #pragma unroll
    for (int r = 0; r < 4; ++r) {
        float m = fmaxf(fmaxf(acc[0][r], acc[1][r]), fmaxf(acc[2][r], acc[3][r]));
        #pragma unroll
        for (int mask = 8; mask; mask >>= 1) m = fmaxf(m, __shfl_xor(m, mask, 64));
        float p0 = __expf(acc[0][r] - m);
        float p1 = __expf(acc[1][r] - m);
        float p2 = __expf(acc[2][r] - m);
        float p3 = __expf(acc[3][r] - m);
        float s = p0 + p1 + p2 + p3;
        #pragma unroll
        for (int mask = 8; mask; mask >>= 1) s += __shfl_xor(s, mask, 64);
        float inv = 1.0f / s;
        int grow = row0 + wave * 16 + quad * 4 + r;
        if (grow < N) {
            float* o = out + (size_t)grow * CC + l15;
            o[0]  = p0 * inv;
            o[16] = p1 * inv;
            o[32] = p2 * inv;
            o[48] = p3 * inv;
        }
    }
}

// ---------------------------------------------------------------------------
// Host launcher
// ---------------------------------------------------------------------------
extern "C" void kernel_launch(void* const* d_in, const int* in_sizes, int n_in,
                              void* d_out, int out_size, void* d_ws, size_t ws_size,
                              hipStream_t stream) {
    const float* x   = (const float*)d_in[0];
    const int*   ei  = (const int*)  d_in[1];
    const float* Wg  = (const float*)d_in[2];
    const float* bg  = (const float*)d_in[3];
    const float* lng = (const float*)d_in[4];
    const float* lnb = (const float*)d_in[5];
    const float* W1  = (const float*)d_in[6];
    const float* b1  = (const float*)d_in[7];
    const float* W2  = (const float*)d_in[8];
    const float* b2  = (const float*)d_in[9];
    float* out = (float*)d_out;

    const int N = in_sizes[0] / D;
    const int E = in_sizes[1] / 2;
    const int* srcp = ei;
    const int* dstp = ei + E;

    char* ws = (char*)d_ws;
    size_t off = 0;
    auto alloc = [&](size_t bytes) -> void* {
        void* p = ws + off;
        off += (bytes + 511) & ~(size_t)511;
        return p;
    };
    int*   cnt    = (int*)  alloc((size_t)N * 4);
    int*   rowptr = (int*)  alloc((size_t)(N + 1) * 4);
    int*   cursor = (int*)  alloc((size_t)N * 4);
    int*   bsum   = (int*)  alloc(64 * 4);
    int*   colsrc = (int*)  alloc((size_t)E * 4);
    float* dinv   = (float*)alloc((size_t)N * 4);
    float* hW     = (float*)alloc((size_t)N * HH * 4);       // GEMM fp32 out; reused as z1
    u16*   xcH    = (u16*)  alloc((size_t)N * 512 * 2);      // [x|f1|f2|f3] hi
    u16*   xcL    = (u16*)  alloc((size_t)N * 512 * 2);      // lo
    u16*   WgtH   = (u16*)  alloc((size_t)NLAYERS * D * HH * 2);
    u16*   WgtL   = (u16*)  alloc((size_t)NLAYERS * D * HH * 2);
    u16*   W1tH   = (u16*)  alloc((size_t)(D + NLAYERS * HH) * HH * 2);
    u16*   W1tL   = (u16*)  alloc((size_t)(D + NLAYERS * HH) * HH * 2);
    u16*   W2tH   = (u16*)  alloc((size_t)HH * CC * 2);
    u16*   W2tL   = (u16*)  alloc((size_t)HH * CC * 2);

    const int B = 256;
    const int gN = (N + B - 1) / B;
    const int gE = (E + B - 1) / B;
    const int nsb = (N + 1023) / 1024;

    k_zero_cnt<<<gN, B, 0, stream>>>(cnt, N);
    k_count<<<gE, B, 0, stream>>>(dstp, cnt, E);
    k_dinv<<<gN, B, 0, stream>>>(cnt, dinv, N);
    k_scan_a<<<nsb, 1024, 0, stream>>>(cnt, rowptr, bsum, N);
    k_scan_b<<<1, 64, 0, stream>>>(bsum, nsb);
    k_scan_c<<<gN, B, 0, stream>>>(rowptr, bsum, cursor, N, E);
    k_scatter<<<gE, B, 0, stream>>>(srcp, dstp, cursor, colsrc, E);

    // Split conversions
    k_split_x<<<(N * D + B - 1) / B, B, 0, stream>>>(x, xcH, xcL, N * D);
    for (int l = 0; l < NLAYERS; ++l)
        k_tile_w<<<(D * HH + B - 1) / B, B, 0, stream>>>(Wg + (size_t)l * D * HH,
                                                         WgtH + (size_t)l * D * HH,
                                                         WgtL + (size_t)l * D * HH, D * HH, 7);
    k_tile_w<<<((D + NLAYERS * HH) * HH + B - 1) / B, B, 0, stream>>>(W1, W1tH, W1tL,
                                                                      (D + NLAYERS * HH) * HH, 7);
    k_tile_w<<<(HH * CC + B - 1) / B, B, 0, stream>>>(W2, W2tH, W2tL, HH * CC, 6);

    const int gemmBlocks = (N + 63) / 64;
    const int waveBlocks = (N + 3) / 4;

    for (int l = 0; l < NLAYERS; ++l) {
        // hW = h @ Wg[l]  (bias added after aggregation)
        k_gemm_mfma<<<gemmBlocks, B, 0, stream>>>(xcH, xcL, l * HH,
                                                  WgtH + (size_t)l * D * HH,
                                                  WgtL + (size_t)l * D * HH,
                                                  nullptr, hW, N, D, 0);
        k_agg_ln<<<waveBlocks, B, 0, stream>>>(hW, rowptr, colsrc, dinv,
                                               bg + (size_t)l * HH,
                                               lng + (size_t)l * HH,
                                               lnb + (size_t)l * HH,
                                               xcH + (size_t)(l + 1) * HH,
                                               xcL + (size_t)(l + 1) * HH, N);
    }

    // z1 = relu([x|f1|f2|f3] @ W1 + b1) -> hW
    k_gemm_mfma<<<gemmBlocks, B, 0, stream>>>(xcH, xcL, 0, W1tH, W1tL,
                                              b1, hW, N, D + NLAYERS * HH, 1);

    // out = softmax(z1 @ W2 + b2)
    k_mlp2_mfma<<<gemmBlocks, B, 0, stream>>>(hW, W2tH, W2tL, b2, out, N);
}

// Round 4
// 398.837 us; speedup vs baseline: 1.6284x; 1.1054x over previous
//
#include <hip/hip_runtime.h>
#include <math.h>

// Problem constants (shapes fixed by the reference)
#define D 128
#define HH 128
#define CC 64
#define NLAYERS 3
#define LN_EPS 1e-5f

typedef __attribute__((ext_vector_type(8))) short bf16x8;
typedef __attribute__((ext_vector_type(4))) float f32x4;
typedef unsigned short u16;
typedef unsigned int u32;

// round-to-nearest-even fp32 -> bf16 bits
__device__ __forceinline__ u16 f2bf(float f) {
    u32 u = __float_as_uint(f);
    u32 r = u + 0x7FFFu + ((u >> 16) & 1u);
    return (u16)(r >> 16);
}
__device__ __forceinline__ float bf2f(u16 h) {
    return __uint_as_float(((u32)h) << 16);
}

// ---------------------------------------------------------------------------
// Setup kernels: degree, CSR build (count -> scan -> scatter)
// ---------------------------------------------------------------------------

__global__ void k_zero_cnt(int* __restrict__ cnt, int n) {
    int i = blockIdx.x * blockDim.x + threadIdx.x;
    if (i < n) cnt[i] = 0;
}

__global__ void k_count(const int* __restrict__ dst, int* __restrict__ cnt, int E) {
    int i = blockIdx.x * blockDim.x + threadIdx.x;
    if (i < E) atomicAdd(&cnt[dst[i]], 1);
}

__global__ void k_dinv(const int* __restrict__ cnt, float* __restrict__ dinv, int N) {
    int i = blockIdx.x * blockDim.x + threadIdx.x;
    if (i < N) dinv[i] = rsqrtf(1.0f + (float)cnt[i]);
}

__global__ void k_scan_a(const int* __restrict__ cnt, int* __restrict__ rowptr,
                         int* __restrict__ bsum, int N) {
    __shared__ int s[1024];
    int tid = threadIdx.x;
    int i = blockIdx.x * 1024 + tid;
    int v = (i < N) ? cnt[i] : 0;
    s[tid] = v;
    __syncthreads();
    for (int off = 1; off < 1024; off <<= 1) {
        int t = (tid >= off) ? s[tid - off] : 0;
        __syncthreads();
        s[tid] += t;
        __syncthreads();
    }
    if (i < N) rowptr[i] = s[tid] - v;
    if (tid == 1023) bsum[blockIdx.x] = s[tid];
}

__global__ void k_scan_b(int* __restrict__ bsum, int nb) {
    int t = threadIdx.x;
    int v = (t < nb) ? bsum[t] : 0;
    int incl = v;
    for (int off = 1; off < 64; off <<= 1) {
        int u = __shfl_up(incl, off, 64);
        if (t >= off) incl += u;
    }
    if (t < nb) bsum[t] = incl - v;
}

__global__ void k_scan_c(int* __restrict__ rowptr, const int* __restrict__ bsum,
                         int* __restrict__ cursor, int N, int E) {
    int i = blockIdx.x * blockDim.x + threadIdx.x;
    if (i < N) {
        int v = rowptr[i] + bsum[i >> 10];
        rowptr[i] = v;
        cursor[i] = v;
    }
    if (i == 0) rowptr[N] = E;
}

// Scatter edges into CSR; pack src index + precomputed coef (dinv_s * dinv_d)
__global__ void k_scatter(const int* __restrict__ src, const int* __restrict__ dst,
                          const float* __restrict__ dinv,
                          int* __restrict__ cursor, int2* __restrict__ ecol, int E) {
    int i = blockIdx.x * blockDim.x + threadIdx.x;
    if (i < E) {
        int s = src[i], d = dst[i];
        int p = atomicAdd(&cursor[d], 1);
        float c = dinv[s] * dinv[d];
        ecol[p] = make_int2(s, __float_as_int(c));
    }
}

// ---------------------------------------------------------------------------
// Split conversions: x -> xc cols 0:128 (hi/lo bf16); weights -> MFMA-tiled hi/lo
// ---------------------------------------------------------------------------

__global__ void k_split_x(const float* __restrict__ x, u16* __restrict__ xh,
                          u16* __restrict__ xl, int total) {
    int i = blockIdx.x * blockDim.x + threadIdx.x;
    if (i >= total) return;
    int row = i >> 7, c = i & 127;
    float v = x[i];
    u16 h = f2bf(v);
    u16 l = f2bf(v - bf2f(h));
    xh[(size_t)row * 512 + c] = h;
    xl[(size_t)row * 512 + c] = l;
}

// W[K][Ncols] (row-major, Ncols = 1<<nshift) -> tiled [kc][q][n][j], k = kc*32+q*8+j
__global__ void k_tile_w(const float* __restrict__ W, u16* __restrict__ th,
                         u16* __restrict__ tl, int KN, int nshift) {
    int idx = blockIdx.x * blockDim.x + threadIdx.x;
    if (idx >= KN) return;
    int k = idx >> nshift, n = idx & ((1 << nshift) - 1);
    int kc = k >> 5, q = (k >> 3) & 3, j = k & 7;
    float v = W[idx];
    u16 h = f2bf(v);
    u16 l = f2bf(v - bf2f(h));
    int o = (((kc * 4 + q) << nshift) + n) * 8 + j;
    th[o] = h;
    tl[o] = l;
}

// ---------------------------------------------------------------------------
// Split-bf16 MFMA GEMM: OUT[N][128] = A[N][Kdim] @ W[Kdim][128] (+bias)(+relu)
// C = Ah@Wh + Ah@Wl + Al@Wh. Output either fp32 (OUT) or bf16 (OUTb).
// ---------------------------------------------------------------------------
__global__ __launch_bounds__(256) void k_gemm_mfma(
    const u16* __restrict__ Ahi, const u16* __restrict__ Alo, int colOff,
    const u16* __restrict__ Bhi, const u16* __restrict__ Blo,
    const float* __restrict__ bias, float* __restrict__ OUT,
    u16* __restrict__ OUTb,
    int N, int Kdim, int do_relu)
{
    __shared__ u16 sAh[4 * 64 * 8];    // [q][r][j]
    __shared__ u16 sAl[4 * 64 * 8];
    __shared__ u16 sBh[4 * 128 * 8];   // [q][n][j]
    __shared__ u16 sBl[4 * 128 * 8];

    const int tid  = threadIdx.x;
    const int lane = tid & 63;
    const int wave = tid >> 6;
    const int wr   = wave & 1;   // row half -> 32 rows
    const int wc   = wave >> 1;  // col half -> 64 cols
    const int quad = lane >> 4;
    const int l15  = lane & 15;
    const int row0 = blockIdx.x * 64;

    const int sq = tid >> 6;
    const int sr = tid & 63;
    int arow = row0 + sr;
    if (arow >= N) arow = N - 1;
    const size_t aoff = (size_t)arow * 512 + colOff + sq * 8;

    const int bq0 = tid >> 7, bn0 = tid & 127;
    const int bq1 = bq0 + 2;

    f32x4 acc[2][4];
    #pragma unroll
    for (int i = 0; i < 2; ++i)
        #pragma unroll
        for (int j = 0; j < 4; ++j)
            #pragma unroll
            for (int r = 0; r < 4; ++r) acc[i][j][r] = 0.f;

    const int nch = Kdim >> 5;
    for (int kc = 0; kc < nch; ++kc) {
        if (kc) __syncthreads();
        *(uint4*)&sAh[(sq * 64 + sr) * 8] = *(const uint4*)(Ahi + aoff + kc * 32);
        *(uint4*)&sAl[(sq * 64 + sr) * 8] = *(const uint4*)(Alo + aoff + kc * 32);
        {
            const size_t base = (size_t)kc * 4096;
            *(uint4*)&sBh[(bq0 * 128 + bn0) * 8] = *(const uint4*)&Bhi[base + (bq0 * 128 + bn0) * 8];
            *(uint4*)&sBh[(bq1 * 128 + bn0) * 8] = *(const uint4*)&Bhi[base + (bq1 * 128 + bn0) * 8];
            *(uint4*)&sBl[(bq0 * 128 + bn0) * 8] = *(const uint4*)&Blo[base + (bq0 * 128 + bn0) * 8];
            *(uint4*)&sBl[(bq1 * 128 + bn0) * 8] = *(const uint4*)&Blo[base + (bq1 * 128 + bn0) * 8];
        }
        __syncthreads();

        bf16x8 ah[2], al[2], bh[4], bl[4];
        #pragma unroll
        for (int i = 0; i < 2; ++i) {
            int r = wr * 32 + i * 16 + l15;
            ah[i] = *(const bf16x8*)&sAh[(quad * 64 + r) * 8];
            al[i] = *(const bf16x8*)&sAl[(quad * 64 + r) * 8];
        }
        #pragma unroll
        for (int j = 0; j < 4; ++j) {
            int n = wc * 64 + j * 16 + l15;
            bh[j] = *(const bf16x8*)&sBh[(quad * 128 + n) * 8];
            bl[j] = *(const bf16x8*)&sBl[(quad * 128 + n) * 8];
        }
        #pragma unroll
        for (int i = 0; i < 2; ++i)
            #pragma unroll
            for (int j = 0; j < 4; ++j) {
                acc[i][j] = __builtin_amdgcn_mfma_f32_16x16x32_bf16(ah[i], bh[j], acc[i][j], 0, 0, 0);
                acc[i][j] = __builtin_amdgcn_mfma_f32_16x16x32_bf16(ah[i], bl[j], acc[i][j], 0, 0, 0);
                acc[i][j] = __builtin_amdgcn_mfma_f32_16x16x32_bf16(al[i], bh[j], acc[i][j], 0, 0, 0);
            }
    }

    #pragma unroll
    for (int i = 0; i < 2; ++i) {
        #pragma unroll
        for (int j = 0; j < 4; ++j) {
            int col = wc * 64 + j * 16 + l15;
            float bv = bias ? bias[col] : 0.f;
            #pragma unroll
            for (int r = 0; r < 4; ++r) {
                int grow = row0 + wr * 32 + i * 16 + quad * 4 + r;
                if (grow < N) {
                    float v = acc[i][j][r] + bv;
                    if (do_relu) v = fmaxf(v, 0.f);
                    if (OUTb) OUTb[(size_t)grow * 128 + col] = f2bf(v);
                    else      OUT [(size_t)grow * 128 + col] = v;
                }
            }
        }
    }
}

// ---------------------------------------------------------------------------
// Aggregation (symmetric-normalized, self-loop) + bias + LayerNorm + ReLU.
// hW gathered as bf16 (256 B/row). One wave per node; lane owns 2 features.
// Edge loop unrolled x4 with independent accumulators; per-edge coef packed
// into the CSR entry (int2{src, coef}).
// ---------------------------------------------------------------------------
__global__ __launch_bounds__(256) void k_agg_ln(
    const u16* __restrict__ hWb,
    const int* __restrict__ rowptr, const int2* __restrict__ ecol,
    const float* __restrict__ dinv,
    const float* __restrict__ bg, const float* __restrict__ g,
    const float* __restrict__ b,
    u16* __restrict__ outHi, u16* __restrict__ outLo, int N)
{
    int wid = blockIdx.x * 4 + (threadIdx.x >> 6);
    int lane = threadIdx.x & 63;
    if (wid >= N) return;

    int f0 = lane * 2;
    float di = dinv[wid];
    float sc = di * di;

    u32 hv = *(const u32*)(hWb + (size_t)wid * HH + f0);
    float ax  = bf2f((u16)hv) * sc;
    float ay  = bf2f((u16)(hv >> 16)) * sc;
    float ax1 = 0.f, ay1 = 0.f, ax2 = 0.f, ay2 = 0.f, ax3 = 0.f, ay3 = 0.f;

    int e0 = rowptr[wid];
    int e1 = rowptr[wid + 1];
    int e = e0;
    for (; e + 4 <= e1; e += 4) {
        int2 p0 = ecol[e];
        int2 p1 = ecol[e + 1];
        int2 p2 = ecol[e + 2];
        int2 p3 = ecol[e + 3];
        u32 v0 = *(const u32*)(hWb + (size_t)p0.x * HH + f0);
        u32 v1 = *(const u32*)(hWb + (size_t)p1.x * HH + f0);
        u32 v2 = *(const u32*)(hWb + (size_t)p2.x * HH + f0);
        u32 v3 = *(const u32*)(hWb + (size_t)p3.x * HH + f0);
        float c0 = __int_as_float(p0.y);
        float c1 = __int_as_float(p1.y);
        float c2 = __int_as_float(p2.y);
        float c3 = __int_as_float(p3.y);
        ax  += bf2f((u16)v0) * c0;  ay  += bf2f((u16)(v0 >> 16)) * c0;
        ax1 += bf2f((u16)v1) * c1;  ay1 += bf2f((u16)(v1 >> 16)) * c1;
        ax2 += bf2f((u16)v2) * c2;  ay2 += bf2f((u16)(v2 >> 16)) * c2;
        ax3 += bf2f((u16)v3) * c3;  ay3 += bf2f((u16)(v3 >> 16)) * c3;
    }
    for (; e < e1; ++e) {
        int2 p = ecol[e];
        u32 v = *(const u32*)(hWb + (size_t)p.x * HH + f0);
        float c = __int_as_float(p.y);
        ax += bf2f((u16)v) * c;
        ay += bf2f((u16)(v >> 16)) * c;
    }
    ax += ax1 + ax2 + ax3;
    ay += ay1 + ay2 + ay3;
    ax += bg[f0];
    ay += bg[f0 + 1];

    float ssum = ax + ay;
    #pragma unroll
    for (int off = 32; off; off >>= 1) ssum += __shfl_xor(ssum, off, 64);
    float mu = ssum * (1.0f / 128.0f);
    float dx = ax - mu, dy = ay - mu;
    float vsum = dx * dx + dy * dy;
    #pragma unroll
    for (int off = 32; off; off >>= 1) vsum += __shfl_xor(vsum, off, 64);
    float rstd = rsqrtf(vsum * (1.0f / 128.0f) + LN_EPS);

    float ox = fmaxf(g[f0] * dx * rstd + b[f0], 0.f);
    float oy = fmaxf(g[f0 + 1] * dy * rstd + b[f0 + 1], 0.f);

    u16 hx = f2bf(ox); u16 lx = f2bf(ox - bf2f(hx));
    u16 hy = f2bf(oy); u16 ly = f2bf(oy - bf2f(hy));
    *(u32*)&outHi[(size_t)wid * 512 + f0] = (u32)hx | ((u32)hy << 16);
    *(u32*)&outLo[(size_t)wid * 512 + f0] = (u32)lx | ((u32)ly << 16);
}

// ---------------------------------------------------------------------------
// MLP layer 2 (128 -> 64) + softmax, via split-bf16 MFMA.
// ---------------------------------------------------------------------------
__global__ __launch_bounds__(256) void k_mlp2_mfma(
    const float* __restrict__ z1,
    const u16* __restrict__ Bhi, const u16* __restrict__ Blo,
    const float* __restrict__ b2, float* __restrict__ out, int N)
{
    __shared__ u16 sZh[64 * 128];   // [(qq*64 + r)*8 + j], k = qq*8+j
    __shared__ u16 sZl[64 * 128];

    const int tid  = threadIdx.x;
    const int lane = tid & 63;
    const int wave = tid >> 6;
    const int quad = lane >> 4;
    const int l15  = lane & 15;
    const int row0 = blockIdx.x * 64;

    {
        const int r  = tid >> 2;
        const int kq = tid & 3;
        int arow = row0 + r;
        if (arow >= N) arow = N - 1;
        const float* src = z1 + (size_t)arow * 128 + kq * 32;
        #pragma unroll
        for (int p = 0; p < 4; ++p) {
            float4 v0 = *(const float4*)(src + p * 8);
            float4 v1 = *(const float4*)(src + p * 8 + 4);
            u16 h[8], l[8];
            float vv[8] = {v0.x, v0.y, v0.z, v0.w, v1.x, v1.y, v1.z, v1.w};
            #pragma unroll
            for (int t = 0; t < 8; ++t) {
                h[t] = f2bf(vv[t]);
                l[t] = f2bf(vv[t] - bf2f(h[t]));
            }
            int qq = kq * 4 + p;
            *(uint4*)&sZh[(qq * 64 + r) * 8] = *(uint4*)h;
            *(uint4*)&sZl[(qq * 64 + r) * 8] = *(uint4*)l;
        }
    }
    __syncthreads();

    f32x4 acc[4];
    #pragma unroll
    for (int j = 0; j < 4; ++j)
        #pragma unroll
        for (int r = 0; r < 4; ++r) acc[j][r] = 0.f;

    #pragma unroll
    for (int kc = 0; kc < 4; ++kc) {
        int qq = kc * 4 + quad;
        bf16x8 ah = *(const bf16x8*)&sZh[(qq * 64 + wave * 16 + l15) * 8];
        bf16x8 al = *(const bf16x8*)&sZl[(qq * 64 + wave * 16 + l15) * 8];
        #pragma unroll
        for (int jt = 0; jt < 4; ++jt) {
            int n = jt * 16 + l15;
            bf16x8 bh = *(const bf16x8*)&Bhi[(qq * 64 + n) * 8];
            bf16x8 bl = *(const bf16x8*)&Blo[(qq * 64 + n) * 8];
            acc[jt] = __builtin_amdgcn_mfma_f32_16x16x32_bf16(ah, bh, acc[jt], 0, 0, 0);
            acc[jt] = __builtin_amdgcn_mfma_f32_16x16x32_bf16(ah, bl, acc[jt], 0, 0, 0);
            acc[jt] = __builtin_amdgcn_mfma_f32_16x16x32_bf16(al, bh, acc[jt], 0, 0, 0);
        }
    }

    #pragma unroll
    for (int jt = 0; jt < 4; ++jt) {
        float bv = b2[jt * 16 + l15];
        #pragma unroll
        for (int r = 0; r < 4; ++r) acc[jt][r] += bv;
    }
    #pragma unroll
    for (int r = 0; r < 4; ++r) {
        float m = fmaxf(fmaxf(acc[0][r], acc[1][r]), fmaxf(acc[2][r], acc[3][r]));
        #pragma unroll
        for (int mask = 8; mask; mask >>= 1) m = fmaxf(m, __shfl_xor(m, mask, 64));
        float p0 = __expf(acc[0][r] - m);
        float p1 = __expf(acc[1][r] - m);
        float p2 = __expf(acc[2][r] - m);
        float p3 = __expf(acc[3][r] - m);
        float s = p0 + p1 + p2 + p3;
        #pragma unroll
        for (int mask = 8; mask; mask >>= 1) s += __shfl_xor(s, mask, 64);
        float inv = 1.0f / s;
        int grow = row0 + wave * 16 + quad * 4 + r;
        if (grow < N) {
            float* o = out + (size_t)grow * CC + l15;
            o[0]  = p0 * inv;
            o[16] = p1 * inv;
            o[32] = p2 * inv;
            o[48] = p3 * inv;
        }
    }
}

// ---------------------------------------------------------------------------
// Host launcher
// ---------------------------------------------------------------------------
extern "C" void kernel_launch(void* const* d_in, const int* in_sizes, int n_in,
                              void* d_out, int out_size, void* d_ws, size_t ws_size,
                              hipStream_t stream) {
    const float* x   = (const float*)d_in[0];
    const int*   ei  = (const int*)  d_in[1];
    const float* Wg  = (const float*)d_in[2];
    const float* bg  = (const float*)d_in[3];
    const float* lng = (const float*)d_in[4];
    const float* lnb = (const float*)d_in[5];
    const float* W1  = (const float*)d_in[6];
    const float* b1  = (const float*)d_in[7];
    const float* W2  = (const float*)d_in[8];
    const float* b2  = (const float*)d_in[9];
    float* out = (float*)d_out;

    const int N = in_sizes[0] / D;
    const int E = in_sizes[1] / 2;
    const int* srcp = ei;
    const int* dstp = ei + E;

    char* ws = (char*)d_ws;
    size_t off = 0;
    auto alloc = [&](size_t bytes) -> void* {
        void* p = ws + off;
        off += (bytes + 511) & ~(size_t)511;
        return p;
    };
    int*   cnt    = (int*)  alloc((size_t)N * 4);
    int*   rowptr = (int*)  alloc((size_t)(N + 1) * 4);
    int*   cursor = (int*)  alloc((size_t)N * 4);
    int*   bsum   = (int*)  alloc(64 * 4);
    int2*  ecol   = (int2*) alloc((size_t)E * 8);
    float* dinv   = (float*)alloc((size_t)N * 4);
    float* z1     = (float*)alloc((size_t)N * HH * 4);       // MLP1 fp32 out
    u16*   hWb    = (u16*)  alloc((size_t)N * HH * 2);       // layer GEMM bf16 out
    u16*   xcH    = (u16*)  alloc((size_t)N * 512 * 2);      // [x|f1|f2|f3] hi
    u16*   xcL    = (u16*)  alloc((size_t)N * 512 * 2);      // lo
    u16*   WgtH   = (u16*)  alloc((size_t)NLAYERS * D * HH * 2);
    u16*   WgtL   = (u16*)  alloc((size_t)NLAYERS * D * HH * 2);
    u16*   W1tH   = (u16*)  alloc((size_t)(D + NLAYERS * HH) * HH * 2);
    u16*   W1tL   = (u16*)  alloc((size_t)(D + NLAYERS * HH) * HH * 2);
    u16*   W2tH   = (u16*)  alloc((size_t)HH * CC * 2);
    u16*   W2tL   = (u16*)  alloc((size_t)HH * CC * 2);

    const int B = 256;
    const int gN = (N + B - 1) / B;
    const int gE = (E + B - 1) / B;
    const int nsb = (N + 1023) / 1024;

    k_zero_cnt<<<gN, B, 0, stream>>>(cnt, N);
    k_count<<<gE, B, 0, stream>>>(dstp, cnt, E);
    k_dinv<<<gN, B, 0, stream>>>(cnt, dinv, N);
    k_scan_a<<<nsb, 1024, 0, stream>>>(cnt, rowptr, bsum, N);
    k_scan_b<<<1, 64, 0, stream>>>(bsum, nsb);
    k_scan_c<<<gN, B, 0, stream>>>(rowptr, bsum, cursor, N, E);
    k_scatter<<<gE, B, 0, stream>>>(srcp, dstp, dinv, cursor, ecol, E);

    // Split conversions
    k_split_x<<<(N * D + B - 1) / B, B, 0, stream>>>(x, xcH, xcL, N * D);
    for (int l = 0; l < NLAYERS; ++l)
        k_tile_w<<<(D * HH + B - 1) / B, B, 0, stream>>>(Wg + (size_t)l * D * HH,
                                                         WgtH + (size_t)l * D * HH,
                                                         WgtL + (size_t)l * D * HH, D * HH, 7);
    k_tile_w<<<((D + NLAYERS * HH) * HH + B - 1) / B, B, 0, stream>>>(W1, W1tH, W1tL,
                                                                      (D + NLAYERS * HH) * HH, 7);
    k_tile_w<<<(HH * CC + B - 1) / B, B, 0, stream>>>(W2, W2tH, W2tL, HH * CC, 6);

    const int gemmBlocks = (N + 63) / 64;
    const int waveBlocks = (N + 3) / 4;

    for (int l = 0; l < NLAYERS; ++l) {
        // hWb = bf16(h @ Wg[l])  (bias added after aggregation)
        k_gemm_mfma<<<gemmBlocks, B, 0, stream>>>(xcH, xcL, l * HH,
                                                  WgtH + (size_t)l * D * HH,
                                                  WgtL + (size_t)l * D * HH,
                                                  nullptr, nullptr, hWb, N, D, 0);
        k_agg_ln<<<waveBlocks, B, 0, stream>>>(hWb, rowptr, ecol, dinv,
                                               bg + (size_t)l * HH,
                                               lng + (size_t)l * HH,
                                               lnb + (size_t)l * HH,
                                               xcH + (size_t)(l + 1) * HH,
                                               xcL + (size_t)(l + 1) * HH, N);
    }

    // z1 = relu([x|f1|f2|f3] @ W1 + b1)  (fp32 out)
    k_gemm_mfma<<<gemmBlocks, B, 0, stream>>>(xcH, xcL, 0, W1tH, W1tL,
                                              b1, z1, nullptr, N, D + NLAYERS * HH, 1);

    // out = softmax(z1 @ W2 + b2)
    k_mlp2_mfma<<<gemmBlocks, B, 0, stream>>>(z1, W2tH, W2tL, b2, out, N);
}

// Round 5
// 387.216 us; speedup vs baseline: 1.6772x; 1.0300x over previous
//
#include <hip/hip_runtime.h>
#include <math.h>

// Problem constants (shapes fixed by the reference)
#define D 128
#define HH 128
#define CC 64
#define NLAYERS 3
#define LN_EPS 1e-5f

typedef __attribute__((ext_vector_type(8))) short bf16x8;
typedef __attribute__((ext_vector_type(4))) float f32x4;
typedef unsigned short u16;
typedef unsigned int u32;

// round-to-nearest-even fp32 -> bf16 bits
__device__ __forceinline__ u16 f2bf(float f) {
    u32 u = __float_as_uint(f);
    u32 r = u + 0x7FFFu + ((u >> 16) & 1u);
    return (u16)(r >> 16);
}
__device__ __forceinline__ float bf2f(u16 h) {
    return __uint_as_float(((u32)h) << 16);
}

// async global->LDS copy, 16 B per lane. LDS dest must be wave-uniform base;
// HW deposits lane i's 16 B at ldsbase + i*16. Per-lane global addrs allowed.
__device__ __forceinline__ void async16(void* lds, const void* g) {
    __builtin_amdgcn_global_load_lds(
        (const __attribute__((address_space(1))) u32*)g,
        (__attribute__((address_space(3))) u32*)lds, 16, 0, 0);
}

// ---------------------------------------------------------------------------
// Setup kernels: degree, CSR build (count -> scan -> scatter)
// ---------------------------------------------------------------------------

__global__ void k_zero_cnt(int* __restrict__ cnt, int n) {
    int i = blockIdx.x * blockDim.x + threadIdx.x;
    if (i < n) cnt[i] = 0;
}

__global__ void k_count(const int* __restrict__ dst, int* __restrict__ cnt, int E) {
    int i = blockIdx.x * blockDim.x + threadIdx.x;
    if (i < E) atomicAdd(&cnt[dst[i]], 1);
}

__global__ void k_dinv(const int* __restrict__ cnt, float* __restrict__ dinv, int N) {
    int i = blockIdx.x * blockDim.x + threadIdx.x;
    if (i < N) dinv[i] = rsqrtf(1.0f + (float)cnt[i]);
}

__global__ void k_scan_a(const int* __restrict__ cnt, int* __restrict__ rowptr,
                         int* __restrict__ bsum, int N) {
    __shared__ int s[1024];
    int tid = threadIdx.x;
    int i = blockIdx.x * 1024 + tid;
    int v = (i < N) ? cnt[i] : 0;
    s[tid] = v;
    __syncthreads();
    for (int off = 1; off < 1024; off <<= 1) {
        int t = (tid >= off) ? s[tid - off] : 0;
        __syncthreads();
        s[tid] += t;
        __syncthreads();
    }
    if (i < N) rowptr[i] = s[tid] - v;
    if (tid == 1023) bsum[blockIdx.x] = s[tid];
}

__global__ void k_scan_b(int* __restrict__ bsum, int nb) {
    int t = threadIdx.x;
    int v = (t < nb) ? bsum[t] : 0;
    int incl = v;
    for (int off = 1; off < 64; off <<= 1) {
        int u = __shfl_up(incl, off, 64);
        if (t >= off) incl += u;
    }
    if (t < nb) bsum[t] = incl - v;
}

__global__ void k_scan_c(int* __restrict__ rowptr, const int* __restrict__ bsum,
                         int* __restrict__ cursor, int N, int E) {
    int i = blockIdx.x * blockDim.x + threadIdx.x;
    if (i < N) {
        int v = rowptr[i] + bsum[i >> 10];
        rowptr[i] = v;
        cursor[i] = v;
    }
    if (i == 0) rowptr[N] = E;
}

// Scatter edges into CSR; pack src index + precomputed coef (dinv_s * dinv_d)
__global__ void k_scatter(const int* __restrict__ src, const int* __restrict__ dst,
                          const float* __restrict__ dinv,
                          int* __restrict__ cursor, int2* __restrict__ ecol, int E) {
    int i = blockIdx.x * blockDim.x + threadIdx.x;
    if (i < E) {
        int s = src[i], d = dst[i];
        int p = atomicAdd(&cursor[d], 1);
        float c = dinv[s] * dinv[d];
        ecol[p] = make_int2(s, __float_as_int(c));
    }
}

// ---------------------------------------------------------------------------
// Split conversions: x -> xc cols 0:128 (hi/lo bf16); weights -> MFMA-tiled hi/lo
// ---------------------------------------------------------------------------

__global__ void k_split_x(const float* __restrict__ x, u16* __restrict__ xh,
                          u16* __restrict__ xl, int total) {
    int i = blockIdx.x * blockDim.x + threadIdx.x;
    if (i >= total) return;
    int row = i >> 7, c = i & 127;
    float v = x[i];
    u16 h = f2bf(v);
    u16 l = f2bf(v - bf2f(h));
    xh[(size_t)row * 512 + c] = h;
    xl[(size_t)row * 512 + c] = l;
}

// W[K][Ncols] (row-major, Ncols = 1<<nshift) -> tiled [kc][q][n][j], k = kc*32+q*8+j
__global__ void k_tile_w(const float* __restrict__ W, u16* __restrict__ th,
                         u16* __restrict__ tl, int KN, int nshift) {
    int idx = blockIdx.x * blockDim.x + threadIdx.x;
    if (idx >= KN) return;
    int k = idx >> nshift, n = idx & ((1 << nshift) - 1);
    int kc = k >> 5, q = (k >> 3) & 3, j = k & 7;
    float v = W[idx];
    u16 h = f2bf(v);
    u16 l = f2bf(v - bf2f(h));
    int o = (((kc * 4 + q) << nshift) + n) * 8 + j;
    th[o] = h;
    tl[o] = l;
}

// ---------------------------------------------------------------------------
// Split-2 bf16 MFMA GEMM: OUT[N][128] = A[N][Kdim] @ W[Kdim][128] (+bias)(+relu)
// C = Ah@Bh + Al@Bh (= exact-A @ bf16-W; W rounding err ~2^-9 rel).
// All staging via global_load_lds width=16 (no VGPR round-trip).
// Block: 256 thr = 4 waves; tile 64 rows x 128 cols; wave = 32x64; BK=32.
// ---------------------------------------------------------------------------
__global__ __launch_bounds__(256) void k_gemm_mfma(
    const u16* __restrict__ Ahi, const u16* __restrict__ Alo, int colOff,
    const u16* __restrict__ Bhi,
    const float* __restrict__ bias, float* __restrict__ OUT,
    u16* __restrict__ OUTb,
    int N, int Kdim, int do_relu)
{
    __shared__ u16 sAh[4 * 64 * 8];    // [(q*64+r)*8+j]  4 KB
    __shared__ u16 sAl[4 * 64 * 8];    // 4 KB
    __shared__ u16 sBh[4 * 128 * 8];   // [(q*128+n)*8+j] 8 KB

    const int tid  = threadIdx.x;
    const int lane = tid & 63;
    const int wave = tid >> 6;
    const int wr   = wave & 1;   // row half -> 32 rows
    const int wc   = wave >> 1;  // col half -> 64 cols
    const int quad = lane >> 4;
    const int l15  = lane & 15;
    const int row0 = blockIdx.x * 64;

    // A staging: wave w covers q=w; lane r -> row0+r, k = kc*32 + w*8 + j.
    // LDS slot (w*64 + lane)*8 u16 == wave base + lane*16 B. Exact match.
    int arow = row0 + lane;
    if (arow >= N) arow = N - 1;
    const u16* agh = Ahi + (size_t)arow * 512 + colOff + wave * 8;
    const u16* agl = Alo + (size_t)arow * 512 + colOff + wave * 8;
    // B staging: linear slots s = w*128 + i*64 + lane; global chunk is the
    // same linear layout (pre-tiled), so contiguous copy.
    const size_t bso0 = (size_t)(wave * 128 + lane) * 8;
    const size_t bso1 = (size_t)(wave * 128 + 64 + lane) * 8;

    f32x4 acc[2][4];
    #pragma unroll
    for (int i = 0; i < 2; ++i)
        #pragma unroll
        for (int j = 0; j < 4; ++j)
            #pragma unroll
            for (int r = 0; r < 4; ++r) acc[i][j][r] = 0.f;

    const int nch = Kdim >> 5;
    for (int kc = 0; kc < nch; ++kc) {
        if (kc) __syncthreads();
        async16(&sAh[wave * 512], agh + kc * 32);
        async16(&sAl[wave * 512], agl + kc * 32);
        async16(&sBh[(wave * 128) * 8],      Bhi + (size_t)kc * 4096 + bso0);
        async16(&sBh[(wave * 128 + 64) * 8], Bhi + (size_t)kc * 4096 + bso1);
        __syncthreads();   // drains vmcnt incl. global_load_lds

        bf16x8 ah[2], al[2], bh[4];
        #pragma unroll
        for (int i = 0; i < 2; ++i) {
            int r = wr * 32 + i * 16 + l15;
            ah[i] = *(const bf16x8*)&sAh[(quad * 64 + r) * 8];
            al[i] = *(const bf16x8*)&sAl[(quad * 64 + r) * 8];
        }
        #pragma unroll
        for (int j = 0; j < 4; ++j) {
            int n = wc * 64 + j * 16 + l15;
            bh[j] = *(const bf16x8*)&sBh[(quad * 128 + n) * 8];
        }
        #pragma unroll
        for (int i = 0; i < 2; ++i)
            #pragma unroll
            for (int j = 0; j < 4; ++j) {
                acc[i][j] = __builtin_amdgcn_mfma_f32_16x16x32_bf16(ah[i], bh[j], acc[i][j], 0, 0, 0);
                acc[i][j] = __builtin_amdgcn_mfma_f32_16x16x32_bf16(al[i], bh[j], acc[i][j], 0, 0, 0);
            }
    }

    // epilogue: C/D layout col = lane&15, row = quad*4 + reg
    #pragma unroll
    for (int i = 0; i < 2; ++i) {
        #pragma unroll
        for (int j = 0; j < 4; ++j) {
            int col = wc * 64 + j * 16 + l15;
            float bv = bias ? bias[col] : 0.f;
            #pragma unroll
            for (int r = 0; r < 4; ++r) {
                int grow = row0 + wr * 32 + i * 16 + quad * 4 + r;
                if (grow < N) {
                    float v = acc[i][j][r] + bv;
                    if (do_relu) v = fmaxf(v, 0.f);
                    if (OUTb) OUTb[(size_t)grow * 128 + col] = f2bf(v);
                    else      OUT [(size_t)grow * 128 + col] = v;
                }
            }
        }
    }
}

// ---------------------------------------------------------------------------
// Aggregation (symmetric-normalized, self-loop) + bias + LayerNorm + ReLU.
// hW gathered as bf16 (256 B/row). One wave per node; lane owns 2 features.
// ---------------------------------------------------------------------------
__global__ __launch_bounds__(256) void k_agg_ln(
    const u16* __restrict__ hWb,
    const int* __restrict__ rowptr, const int2* __restrict__ ecol,
    const float* __restrict__ dinv,
    const float* __restrict__ bg, const float* __restrict__ g,
    const float* __restrict__ b,
    u16* __restrict__ outHi, u16* __restrict__ outLo, int N)
{
    int wid = blockIdx.x * 4 + (threadIdx.x >> 6);
    int lane = threadIdx.x & 63;
    if (wid >= N) return;

    int f0 = lane * 2;
    float di = dinv[wid];
    float sc = di * di;

    u32 hv = *(const u32*)(hWb + (size_t)wid * HH + f0);
    float ax  = bf2f((u16)hv) * sc;
    float ay  = bf2f((u16)(hv >> 16)) * sc;
    float ax1 = 0.f, ay1 = 0.f, ax2 = 0.f, ay2 = 0.f, ax3 = 0.f, ay3 = 0.f;

    int e0 = rowptr[wid];
    int e1 = rowptr[wid + 1];
    int e = e0;
    for (; e + 4 <= e1; e += 4) {
        int2 p0 = ecol[e];
        int2 p1 = ecol[e + 1];
        int2 p2 = ecol[e + 2];
        int2 p3 = ecol[e + 3];
        u32 v0 = *(const u32*)(hWb + (size_t)p0.x * HH + f0);
        u32 v1 = *(const u32*)(hWb + (size_t)p1.x * HH + f0);
        u32 v2 = *(const u32*)(hWb + (size_t)p2.x * HH + f0);
        u32 v3 = *(const u32*)(hWb + (size_t)p3.x * HH + f0);
        float c0 = __int_as_float(p0.y);
        float c1 = __int_as_float(p1.y);
        float c2 = __int_as_float(p2.y);
        float c3 = __int_as_float(p3.y);
        ax  += bf2f((u16)v0) * c0;  ay  += bf2f((u16)(v0 >> 16)) * c0;
        ax1 += bf2f((u16)v1) * c1;  ay1 += bf2f((u16)(v1 >> 16)) * c1;
        ax2 += bf2f((u16)v2) * c2;  ay2 += bf2f((u16)(v2 >> 16)) * c2;
        ax3 += bf2f((u16)v3) * c3;  ay3 += bf2f((u16)(v3 >> 16)) * c3;
    }
    for (; e < e1; ++e) {
        int2 p = ecol[e];
        u32 v = *(const u32*)(hWb + (size_t)p.x * HH + f0);
        float c = __int_as_float(p.y);
        ax += bf2f((u16)v) * c;
        ay += bf2f((u16)(v >> 16)) * c;
    }
    ax += ax1 + ax2 + ax3;
    ay += ay1 + ay2 + ay3;
    ax += bg[f0];
    ay += bg[f0 + 1];

    float ssum = ax + ay;
    #pragma unroll
    for (int off = 32; off; off >>= 1) ssum += __shfl_xor(ssum, off, 64);
    float mu = ssum * (1.0f / 128.0f);
    float dx = ax - mu, dy = ay - mu;
    float vsum = dx * dx + dy * dy;
    #pragma unroll
    for (int off = 32; off; off >>= 1) vsum += __shfl_xor(vsum, off, 64);
    float rstd = rsqrtf(vsum * (1.0f / 128.0f) + LN_EPS);

    float ox = fmaxf(g[f0] * dx * rstd + b[f0], 0.f);
    float oy = fmaxf(g[f0 + 1] * dy * rstd + b[f0 + 1], 0.f);

    u16 hx = f2bf(ox); u16 lx = f2bf(ox - bf2f(hx));
    u16 hy = f2bf(oy); u16 ly = f2bf(oy - bf2f(hy));
    *(u32*)&outHi[(size_t)wid * 512 + f0] = (u32)hx | ((u32)hy << 16);
    *(u32*)&outLo[(size_t)wid * 512 + f0] = (u32)lx | ((u32)ly << 16);
}

// ---------------------------------------------------------------------------
// MLP layer 2 (128 -> 64) + softmax, via split-bf16 MFMA (split-3 kept:
// W2 rounding hits logits directly and this kernel is not a bottleneck).
// ---------------------------------------------------------------------------
__global__ __launch_bounds__(256) void k_mlp2_mfma(
    const float* __restrict__ z1,
    const u16* __restrict__ Bhi, const u16* __restrict__ Blo,
    const float* __restrict__ b2, float* __restrict__ out, int N)
{
    __shared__ u16 sZh[64 * 128];   // [(qq*64 + r)*8 + j], k = qq*8+j
    __shared__ u16 sZl[64 * 128];

    const int tid  = threadIdx.x;
    const int lane = tid & 63;
    const int wave = tid >> 6;
    const int quad = lane >> 4;
    const int l15  = lane & 15;
    const int row0 = blockIdx.x * 64;

    {
        const int r  = tid >> 2;
        const int kq = tid & 3;
        int arow = row0 + r;
        if (arow >= N) arow = N - 1;
        const float* src = z1 + (size_t)arow * 128 + kq * 32;
        #pragma unroll
        for (int p = 0; p < 4; ++p) {
            float4 v0 = *(const float4*)(src + p * 8);
            float4 v1 = *(const float4*)(src + p * 8 + 4);
            u16 h[8], l[8];
            float vv[8] = {v0.x, v0.y, v0.z, v0.w, v1.x, v1.y, v1.z, v1.w};
            #pragma unroll
            for (int t = 0; t < 8; ++t) {
                h[t] = f2bf(vv[t]);
                l[t] = f2bf(vv[t] - bf2f(h[t]));
            }
            int qq = kq * 4 + p;
            *(uint4*)&sZh[(qq * 64 + r) * 8] = *(uint4*)h;
            *(uint4*)&sZl[(qq * 64 + r) * 8] = *(uint4*)l;
        }
    }
    __syncthreads();

    f32x4 acc[4];
    #pragma unroll
    for (int j = 0; j < 4; ++j)
        #pragma unroll
        for (int r = 0; r < 4; ++r) acc[j][r] = 0.f;

    #pragma unroll
    for (int kc = 0; kc < 4; ++kc) {
        int qq = kc * 4 + quad;
        bf16x8 ah = *(const bf16x8*)&sZh[(qq * 64 + wave * 16 + l15) * 8];
        bf16x8 al = *(const bf16x8*)&sZl[(qq * 64 + wave * 16 + l15) * 8];
        #pragma unroll
        for (int jt = 0; jt < 4; ++jt) {
            int n = jt * 16 + l15;
            bf16x8 bh = *(const bf16x8*)&Bhi[(qq * 64 + n) * 8];
            bf16x8 bl = *(const bf16x8*)&Blo[(qq * 64 + n) * 8];
            acc[jt] = __builtin_amdgcn_mfma_f32_16x16x32_bf16(ah, bh, acc[jt], 0, 0, 0);
            acc[jt] = __builtin_amdgcn_mfma_f32_16x16x32_bf16(ah, bl, acc[jt], 0, 0, 0);
            acc[jt] = __builtin_amdgcn_mfma_f32_16x16x32_bf16(al, bh, acc[jt], 0, 0, 0);
        }
    }

    #pragma unroll
    for (int jt = 0; jt < 4; ++jt) {
        float bv = b2[jt * 16 + l15];
        #pragma unroll
        for (int r = 0; r < 4; ++r) acc[jt][r] += bv;
    }
    #pragma unroll
    for (int r = 0; r < 4; ++r) {
        float m = fmaxf(fmaxf(acc[0][r], acc[1][r]), fmaxf(acc[2][r], acc[3][r]));
        #pragma unroll
        for (int mask = 8; mask; mask >>= 1) m = fmaxf(m, __shfl_xor(m, mask, 64));
        float p0 = __expf(acc[0][r] - m);
        float p1 = __expf(acc[1][r] - m);
        float p2 = __expf(acc[2][r] - m);
        float p3 = __expf(acc[3][r] - m);
        float s = p0 + p1 + p2 + p3;
        #pragma unroll
        for (int mask = 8; mask; mask >>= 1) s += __shfl_xor(s, mask, 64);
        float inv = 1.0f / s;
        int grow = row0 + wave * 16 + quad * 4 + r;
        if (grow < N) {
            float* o = out + (size_t)grow * CC + l15;
            o[0]  = p0 * inv;
            o[16] = p1 * inv;
            o[32] = p2 * inv;
            o[48] = p3 * inv;
        }
    }
}

// ---------------------------------------------------------------------------
// Host launcher
// ---------------------------------------------------------------------------
extern "C" void kernel_launch(void* const* d_in, const int* in_sizes, int n_in,
                              void* d_out, int out_size, void* d_ws, size_t ws_size,
                              hipStream_t stream) {
    const float* x   = (const float*)d_in[0];
    const int*   ei  = (const int*)  d_in[1];
    const float* Wg  = (const float*)d_in[2];
    const float* bg  = (const float*)d_in[3];
    const float* lng = (const float*)d_in[4];
    const float* lnb = (const float*)d_in[5];
    const float* W1  = (const float*)d_in[6];
    const float* b1  = (const float*)d_in[7];
    const float* W2  = (const float*)d_in[8];
    const float* b2  = (const float*)d_in[9];
    float* out = (float*)d_out;

    const int N = in_sizes[0] / D;
    const int E = in_sizes[1] / 2;
    const int* srcp = ei;
    const int* dstp = ei + E;

    char* ws = (char*)d_ws;
    size_t off = 0;
    auto alloc = [&](size_t bytes) -> void* {
        void* p = ws + off;
        off += (bytes + 511) & ~(size_t)511;
        return p;
    };
    int*   cnt    = (int*)  alloc((size_t)N * 4);
    int*   rowptr = (int*)  alloc((size_t)(N + 1) * 4);
    int*   cursor = (int*)  alloc((size_t)N * 4);
    int*   bsum   = (int*)  alloc(64 * 4);
    int2*  ecol   = (int2*) alloc((size_t)E * 8);
    float* dinv   = (float*)alloc((size_t)N * 4);
    float* z1     = (float*)alloc((size_t)N * HH * 4);       // MLP1 fp32 out
    u16*   hWb    = (u16*)  alloc((size_t)N * HH * 2);       // layer GEMM bf16 out
    u16*   xcH    = (u16*)  alloc((size_t)N * 512 * 2);      // [x|f1|f2|f3] hi
    u16*   xcL    = (u16*)  alloc((size_t)N * 512 * 2);      // lo
    u16*   WgtH   = (u16*)  alloc((size_t)NLAYERS * D * HH * 2);
    u16*   WgtL   = (u16*)  alloc((size_t)NLAYERS * D * HH * 2);
    u16*   W1tH   = (u16*)  alloc((size_t)(D + NLAYERS * HH) * HH * 2);
    u16*   W1tL   = (u16*)  alloc((size_t)(D + NLAYERS * HH) * HH * 2);
    u16*   W2tH   = (u16*)  alloc((size_t)HH * CC * 2);
    u16*   W2tL   = (u16*)  alloc((size_t)HH * CC * 2);

    const int B = 256;
    const int gN = (N + B - 1) / B;
    const int gE = (E + B - 1) / B;
    const int nsb = (N + 1023) / 1024;

    k_zero_cnt<<<gN, B, 0, stream>>>(cnt, N);
    k_count<<<gE, B, 0, stream>>>(dstp, cnt, E);
    k_dinv<<<gN, B, 0, stream>>>(cnt, dinv, N);
    k_scan_a<<<nsb, 1024, 0, stream>>>(cnt, rowptr, bsum, N);
    k_scan_b<<<1, 64, 0, stream>>>(bsum, nsb);
    k_scan_c<<<gN, B, 0, stream>>>(rowptr, bsum, cursor, N, E);
    k_scatter<<<gE, B, 0, stream>>>(srcp, dstp, dinv, cursor, ecol, E);

    // Split conversions
    k_split_x<<<(N * D + B - 1) / B, B, 0, stream>>>(x, xcH, xcL, N * D);
    for (int l = 0; l < NLAYERS; ++l)
        k_tile_w<<<(D * HH + B - 1) / B, B, 0, stream>>>(Wg + (size_t)l * D * HH,
                                                         WgtH + (size_t)l * D * HH,
                                                         WgtL + (size_t)l * D * HH, D * HH, 7);
    k_tile_w<<<((D + NLAYERS * HH) * HH + B - 1) / B, B, 0, stream>>>(W1, W1tH, W1tL,
                                                                      (D + NLAYERS * HH) * HH, 7);
    k_tile_w<<<(HH * CC + B - 1) / B, B, 0, stream>>>(W2, W2tH, W2tL, HH * CC, 6);

    const int gemmBlocks = (N + 63) / 64;
    const int waveBlocks = (N + 3) / 4;

    for (int l = 0; l < NLAYERS; ++l) {
        // hWb = bf16(h @ Wg[l])  (bias added after aggregation)
        k_gemm_mfma<<<gemmBlocks, B, 0, stream>>>(xcH, xcL, l * HH,
                                                  WgtH + (size_t)l * D * HH,
                                                  nullptr, nullptr, hWb, N, D, 0);
        k_agg_ln<<<waveBlocks, B, 0, stream>>>(hWb, rowptr, ecol, dinv,
                                               bg + (size_t)l * HH,
                                               lng + (size_t)l * HH,
                                               lnb + (size_t)l * HH,
                                               xcH + (size_t)(l + 1) * HH,
                                               xcL + (size_t)(l + 1) * HH, N);
    }

    // z1 = relu([x|f1|f2|f3] @ W1 + b1)  (fp32 out)
    k_gemm_mfma<<<gemmBlocks, B, 0, stream>>>(xcH, xcL, 0, W1tH,
                                              b1, z1, nullptr, N, D + NLAYERS * HH, 1);

    // out = softmax(z1 @ W2 + b2)
    k_mlp2_mfma<<<gemmBlocks, B, 0, stream>>>(z1, W2tH, W2tL, b2, out, N);
}

// Round 6
// 377.449 us; speedup vs baseline: 1.7206x; 1.0259x over previous
//
#include <hip/hip_runtime.h>
#include <math.h>

// Problem constants (shapes fixed by the reference)
#define D 128
#define HH 128
#define CC 64
#define NLAYERS 3
#define LN_EPS 1e-5f

typedef __attribute__((ext_vector_type(8))) short bf16x8;
typedef __attribute__((ext_vector_type(4))) float f32x4;
typedef unsigned short u16;
typedef unsigned int u32;

// round-to-nearest-even fp32 -> bf16 bits
__device__ __forceinline__ u16 f2bf(float f) {
    u32 u = __float_as_uint(f);
    u32 r = u + 0x7FFFu + ((u >> 16) & 1u);
    return (u16)(r >> 16);
}
__device__ __forceinline__ float bf2f(u16 h) {
    return __uint_as_float(((u32)h) << 16);
}

// async global->LDS copy, 16 B per lane. LDS dest must be wave-uniform base;
// HW deposits lane i's 16 B at ldsbase + i*16. Per-lane global addrs allowed.
__device__ __forceinline__ void async16(void* lds, const void* g) {
    __builtin_amdgcn_global_load_lds(
        (const __attribute__((address_space(1))) u32*)g,
        (__attribute__((address_space(3))) u32*)lds, 16, 0, 0);
}

// ---------------------------------------------------------------------------
// Setup kernels: degree, CSR build (count -> scan -> scatter)
// ---------------------------------------------------------------------------

__global__ void k_zero_cnt(int* __restrict__ cnt, int n) {
    int i = blockIdx.x * blockDim.x + threadIdx.x;
    if (i < n) cnt[i] = 0;
}

__global__ void k_count(const int* __restrict__ dst, int* __restrict__ cnt, int E) {
    int i = blockIdx.x * blockDim.x + threadIdx.x;
    if (i < E) atomicAdd(&cnt[dst[i]], 1);
}

__global__ void k_dinv(const int* __restrict__ cnt, float* __restrict__ dinv, int N) {
    int i = blockIdx.x * blockDim.x + threadIdx.x;
    if (i < N) dinv[i] = rsqrtf(1.0f + (float)cnt[i]);
}

__global__ void k_scan_a(const int* __restrict__ cnt, int* __restrict__ rowptr,
                         int* __restrict__ bsum, int N) {
    __shared__ int s[1024];
    int tid = threadIdx.x;
    int i = blockIdx.x * 1024 + tid;
    int v = (i < N) ? cnt[i] : 0;
    s[tid] = v;
    __syncthreads();
    for (int off = 1; off < 1024; off <<= 1) {
        int t = (tid >= off) ? s[tid - off] : 0;
        __syncthreads();
        s[tid] += t;
        __syncthreads();
    }
    if (i < N) rowptr[i] = s[tid] - v;
    if (tid == 1023) bsum[blockIdx.x] = s[tid];
}

__global__ void k_scan_b(int* __restrict__ bsum, int nb) {
    int t = threadIdx.x;
    int v = (t < nb) ? bsum[t] : 0;
    int incl = v;
    for (int off = 1; off < 64; off <<= 1) {
        int u = __shfl_up(incl, off, 64);
        if (t >= off) incl += u;
    }
    if (t < nb) bsum[t] = incl - v;
}

__global__ void k_scan_c(int* __restrict__ rowptr, const int* __restrict__ bsum,
                         int* __restrict__ cursor, int N, int E) {
    int i = blockIdx.x * blockDim.x + threadIdx.x;
    if (i < N) {
        int v = rowptr[i] + bsum[i >> 10];
        rowptr[i] = v;
        cursor[i] = v;
    }
    if (i == 0) rowptr[N] = E;
}

// Scatter edges into CSR; pack src index + precomputed coef (dinv_s * dinv_d)
__global__ void k_scatter(const int* __restrict__ src, const int* __restrict__ dst,
                          const float* __restrict__ dinv,
                          int* __restrict__ cursor, int2* __restrict__ ecol, int E) {
    int i = blockIdx.x * blockDim.x + threadIdx.x;
    if (i < E) {
        int s = src[i], d = dst[i];
        int p = atomicAdd(&cursor[d], 1);
        float c = dinv[s] * dinv[d];
        ecol[p] = make_int2(s, __float_as_int(c));
    }
}

// ---------------------------------------------------------------------------
// Split conversions: x -> xc cols 0:128 (hi/lo bf16); weights -> MFMA-tiled hi/lo
// ---------------------------------------------------------------------------

__global__ void k_split_x(const float* __restrict__ x, u16* __restrict__ xh,
                          u16* __restrict__ xl, int total) {
    int i = blockIdx.x * blockDim.x + threadIdx.x;
    if (i >= total) return;
    int row = i >> 7, c = i & 127;
    float v = x[i];
    u16 h = f2bf(v);
    u16 l = f2bf(v - bf2f(h));
    xh[(size_t)row * 512 + c] = h;
    xl[(size_t)row * 512 + c] = l;
}

// W[K][Ncols] (row-major, Ncols = 1<<nshift) -> tiled [kc][q][n][j], k = kc*32+q*8+j
__global__ void k_tile_w(const float* __restrict__ W, u16* __restrict__ th,
                         u16* __restrict__ tl, int KN, int nshift) {
    int idx = blockIdx.x * blockDim.x + threadIdx.x;
    if (idx >= KN) return;
    int k = idx >> nshift, n = idx & ((1 << nshift) - 1);
    int kc = k >> 5, q = (k >> 3) & 3, j = k & 7;
    float v = W[idx];
    u16 h = f2bf(v);
    u16 l = f2bf(v - bf2f(h));
    int o = (((kc * 4 + q) << nshift) + n) * 8 + j;
    th[o] = h;
    tl[o] = l;
}

// ---------------------------------------------------------------------------
// Split-2 bf16 MFMA GEMM: OUT[N][128] = A[N][Kdim] @ W[Kdim][128] (+bias)(+relu)
// C = Ah@Bh + Al@Bh (= exact-A @ bf16-W). Staging via global_load_lds w=16.
// Output: fp32 (OUT) | bf16 (OUTb) | bf16 hi/lo pair (OUThi/OUTlo).
// ---------------------------------------------------------------------------
__global__ __launch_bounds__(256) void k_gemm_mfma(
    const u16* __restrict__ Ahi, const u16* __restrict__ Alo, int colOff,
    const u16* __restrict__ Bhi,
    const float* __restrict__ bias, float* __restrict__ OUT,
    u16* __restrict__ OUTb, u16* __restrict__ OUThi, u16* __restrict__ OUTlo,
    int N, int Kdim, int do_relu)
{
    __shared__ u16 sAh[4 * 64 * 8];    // [(q*64+r)*8+j]  4 KB
    __shared__ u16 sAl[4 * 64 * 8];    // 4 KB
    __shared__ u16 sBh[4 * 128 * 8];   // [(q*128+n)*8+j] 8 KB

    const int tid  = threadIdx.x;
    const int lane = tid & 63;
    const int wave = tid >> 6;
    const int wr   = wave & 1;   // row half -> 32 rows
    const int wc   = wave >> 1;  // col half -> 64 cols
    const int quad = lane >> 4;
    const int l15  = lane & 15;
    const int row0 = blockIdx.x * 64;

    int arow = row0 + lane;
    if (arow >= N) arow = N - 1;
    const u16* agh = Ahi + (size_t)arow * 512 + colOff + wave * 8;
    const u16* agl = Alo + (size_t)arow * 512 + colOff + wave * 8;
    const size_t bso0 = (size_t)(wave * 128 + lane) * 8;
    const size_t bso1 = (size_t)(wave * 128 + 64 + lane) * 8;

    f32x4 acc[2][4];
    #pragma unroll
    for (int i = 0; i < 2; ++i)
        #pragma unroll
        for (int j = 0; j < 4; ++j)
            #pragma unroll
            for (int r = 0; r < 4; ++r) acc[i][j][r] = 0.f;

    const int nch = Kdim >> 5;
    for (int kc = 0; kc < nch; ++kc) {
        if (kc) __syncthreads();
        async16(&sAh[wave * 512], agh + kc * 32);
        async16(&sAl[wave * 512], agl + kc * 32);
        async16(&sBh[(wave * 128) * 8],      Bhi + (size_t)kc * 4096 + bso0);
        async16(&sBh[(wave * 128 + 64) * 8], Bhi + (size_t)kc * 4096 + bso1);
        __syncthreads();   // drains vmcnt incl. global_load_lds

        bf16x8 ah[2], al[2], bh[4];
        #pragma unroll
        for (int i = 0; i < 2; ++i) {
            int r = wr * 32 + i * 16 + l15;
            ah[i] = *(const bf16x8*)&sAh[(quad * 64 + r) * 8];
            al[i] = *(const bf16x8*)&sAl[(quad * 64 + r) * 8];
        }
        #pragma unroll
        for (int j = 0; j < 4; ++j) {
            int n = wc * 64 + j * 16 + l15;
            bh[j] = *(const bf16x8*)&sBh[(quad * 128 + n) * 8];
        }
        #pragma unroll
        for (int i = 0; i < 2; ++i)
            #pragma unroll
            for (int j = 0; j < 4; ++j) {
                acc[i][j] = __builtin_amdgcn_mfma_f32_16x16x32_bf16(ah[i], bh[j], acc[i][j], 0, 0, 0);
                acc[i][j] = __builtin_amdgcn_mfma_f32_16x16x32_bf16(al[i], bh[j], acc[i][j], 0, 0, 0);
            }
    }

    // epilogue: C/D layout col = lane&15, row = quad*4 + reg
    #pragma unroll
    for (int i = 0; i < 2; ++i) {
        #pragma unroll
        for (int j = 0; j < 4; ++j) {
            int col = wc * 64 + j * 16 + l15;
            float bv = bias ? bias[col] : 0.f;
            #pragma unroll
            for (int r = 0; r < 4; ++r) {
                int grow = row0 + wr * 32 + i * 16 + quad * 4 + r;
                if (grow < N) {
                    float v = acc[i][j][r] + bv;
                    if (do_relu) v = fmaxf(v, 0.f);
                    size_t o = (size_t)grow * 128 + col;
                    if (OUTb) {
                        OUTb[o] = f2bf(v);
                    } else if (OUThi) {
                        u16 h = f2bf(v);
                        OUThi[o] = h;
                        OUTlo[o] = f2bf(v - bf2f(h));
                    } else {
                        OUT[o] = v;
                    }
                }
            }
        }
    }
}

// ---------------------------------------------------------------------------
// Aggregation (symmetric-normalized, self-loop) + bias + LayerNorm + ReLU.
// Persistent grid-stride waves: one wave handles ~N/(grid*4) nodes; per-feature
// constants hoisted out of the node loop. hW gathered as bf16 (256 B/row).
// ---------------------------------------------------------------------------
__global__ __launch_bounds__(256, 8) void k_agg_ln(
    const u16* __restrict__ hWb,
    const int* __restrict__ rowptr, const int2* __restrict__ ecol,
    const float* __restrict__ dinv,
    const float* __restrict__ bg, const float* __restrict__ g,
    const float* __restrict__ b,
    u16* __restrict__ outHi, u16* __restrict__ outLo, int N)
{
    const int lane = threadIdx.x & 63;
    const int f0 = lane * 2;

    // node-invariant per-feature constants
    const float bgx = bg[f0], bgy = bg[f0 + 1];
    const float gx  = g[f0],  gy  = g[f0 + 1];
    const float bx  = b[f0],  by  = b[f0 + 1];

    const int nwaves = gridDim.x * 4;
    for (int wid = blockIdx.x * 4 + (threadIdx.x >> 6); wid < N; wid += nwaves) {
        float di = dinv[wid];
        float sc = di * di;

        u32 hv = *(const u32*)(hWb + (size_t)wid * HH + f0);
        float ax  = bf2f((u16)hv) * sc;
        float ay  = bf2f((u16)(hv >> 16)) * sc;
        float ax1 = 0.f, ay1 = 0.f, ax2 = 0.f, ay2 = 0.f, ax3 = 0.f, ay3 = 0.f;

        int e0 = rowptr[wid];
        int e1 = rowptr[wid + 1];
        int e = e0;
        for (; e + 4 <= e1; e += 4) {
            int2 p0 = ecol[e];
            int2 p1 = ecol[e + 1];
            int2 p2 = ecol[e + 2];
            int2 p3 = ecol[e + 3];
            u32 v0 = *(const u32*)(hWb + (size_t)p0.x * HH + f0);
            u32 v1 = *(const u32*)(hWb + (size_t)p1.x * HH + f0);
            u32 v2 = *(const u32*)(hWb + (size_t)p2.x * HH + f0);
            u32 v3 = *(const u32*)(hWb + (size_t)p3.x * HH + f0);
            float c0 = __int_as_float(p0.y);
            float c1 = __int_as_float(p1.y);
            float c2 = __int_as_float(p2.y);
            float c3 = __int_as_float(p3.y);
            ax  += bf2f((u16)v0) * c0;  ay  += bf2f((u16)(v0 >> 16)) * c0;
            ax1 += bf2f((u16)v1) * c1;  ay1 += bf2f((u16)(v1 >> 16)) * c1;
            ax2 += bf2f((u16)v2) * c2;  ay2 += bf2f((u16)(v2 >> 16)) * c2;
            ax3 += bf2f((u16)v3) * c3;  ay3 += bf2f((u16)(v3 >> 16)) * c3;
        }
        for (; e < e1; ++e) {
            int2 p = ecol[e];
            u32 v = *(const u32*)(hWb + (size_t)p.x * HH + f0);
            float c = __int_as_float(p.y);
            ax += bf2f((u16)v) * c;
            ay += bf2f((u16)(v >> 16)) * c;
        }
        ax += ax1 + ax2 + ax3;
        ay += ay1 + ay2 + ay3;
        ax += bgx;
        ay += bgy;

        float ssum = ax + ay;
        #pragma unroll
        for (int off = 32; off; off >>= 1) ssum += __shfl_xor(ssum, off, 64);
        float mu = ssum * (1.0f / 128.0f);
        float dx = ax - mu, dy = ay - mu;
        float vsum = dx * dx + dy * dy;
        #pragma unroll
        for (int off = 32; off; off >>= 1) vsum += __shfl_xor(vsum, off, 64);
        float rstd = rsqrtf(vsum * (1.0f / 128.0f) + LN_EPS);

        float ox = fmaxf(gx * dx * rstd + bx, 0.f);
        float oy = fmaxf(gy * dy * rstd + by, 0.f);

        u16 hx = f2bf(ox); u16 lx = f2bf(ox - bf2f(hx));
        u16 hy = f2bf(oy); u16 ly = f2bf(oy - bf2f(hy));
        *(u32*)&outHi[(size_t)wid * 512 + f0] = (u32)hx | ((u32)hy << 16);
        *(u32*)&outLo[(size_t)wid * 512 + f0] = (u32)lx | ((u32)ly << 16);
    }
}

// ---------------------------------------------------------------------------
// MLP layer 2 (128 -> 64) + softmax, via split-bf16 MFMA (split-3 on z1, W2).
// z1 arrives pre-split as bf16 hi/lo row-major -> staged via global_load_lds
// with zero conversion VALU.
// ---------------------------------------------------------------------------
__global__ __launch_bounds__(256) void k_mlp2_mfma(
    const u16* __restrict__ z1h, const u16* __restrict__ z1l,
    const u16* __restrict__ Bhi, const u16* __restrict__ Blo,
    const float* __restrict__ b2, float* __restrict__ out, int N)
{
    __shared__ u16 sZh[64 * 128];   // [(qq*64 + r)*8 + j], k = qq*8+j
    __shared__ u16 sZl[64 * 128];

    const int tid  = threadIdx.x;
    const int lane = tid & 63;
    const int wave = tid >> 6;
    const int quad = lane >> 4;
    const int l15  = lane & 15;
    const int row0 = blockIdx.x * 64;

    // stage: wave w covers qq = w*4 .. w*4+3; lane r -> row row0+r, 16 B at k=qq*8
    {
        int arow = row0 + lane;
        if (arow >= N) arow = N - 1;
        const size_t rbase = (size_t)arow * 128;
        #pragma unroll
        for (int t = 0; t < 4; ++t) {
            int qq = wave * 4 + t;
            async16(&sZh[(qq * 64) * 8], z1h + rbase + qq * 8);
            async16(&sZl[(qq * 64) * 8], z1l + rbase + qq * 8);
        }
    }
    __syncthreads();

    f32x4 acc[4];
    #pragma unroll
    for (int j = 0; j < 4; ++j)
        #pragma unroll
        for (int r = 0; r < 4; ++r) acc[j][r] = 0.f;

    #pragma unroll
    for (int kc = 0; kc < 4; ++kc) {
        int qq = kc * 4 + quad;
        bf16x8 ah = *(const bf16x8*)&sZh[(qq * 64 + wave * 16 + l15) * 8];
        bf16x8 al = *(const bf16x8*)&sZl[(qq * 64 + wave * 16 + l15) * 8];
        #pragma unroll
        for (int jt = 0; jt < 4; ++jt) {
            int n = jt * 16 + l15;
            bf16x8 bh = *(const bf16x8*)&Bhi[(qq * 64 + n) * 8];
            bf16x8 bl = *(const bf16x8*)&Blo[(qq * 64 + n) * 8];
            acc[jt] = __builtin_amdgcn_mfma_f32_16x16x32_bf16(ah, bh, acc[jt], 0, 0, 0);
            acc[jt] = __builtin_amdgcn_mfma_f32_16x16x32_bf16(ah, bl, acc[jt], 0, 0, 0);
            acc[jt] = __builtin_amdgcn_mfma_f32_16x16x32_bf16(al, bh, acc[jt], 0, 0, 0);
        }
    }

    #pragma unroll
    for (int jt = 0; jt < 4; ++jt) {
        float bv = b2[jt * 16 + l15];
        #pragma unroll
        for (int r = 0; r < 4; ++r) acc[jt][r] += bv;
    }
    #pragma unroll
    for (int r = 0; r < 4; ++r) {
        float m = fmaxf(fmaxf(acc[0][r], acc[1][r]), fmaxf(acc[2][r], acc[3][r]));
        #pragma unroll
        for (int mask = 8; mask; mask >>= 1) m = fmaxf(m, __shfl_xor(m, mask, 64));
        float p0 = __expf(acc[0][r] - m);
        float p1 = __expf(acc[1][r] - m);
        float p2 = __expf(acc[2][r] - m);
        float p3 = __expf(acc[3][r] - m);
        float s = p0 + p1 + p2 + p3;
        #pragma unroll
        for (int mask = 8; mask; mask >>= 1) s += __shfl_xor(s, mask, 64);
        float inv = 1.0f / s;
        int grow = row0 + wave * 16 + quad * 4 + r;
        if (grow < N) {
            float* o = out + (size_t)grow * CC + l15;
            o[0]  = p0 * inv;
            o[16] = p1 * inv;
            o[32] = p2 * inv;
            o[48] = p3 * inv;
        }
    }
}

// ---------------------------------------------------------------------------
// Host launcher
// ---------------------------------------------------------------------------
extern "C" void kernel_launch(void* const* d_in, const int* in_sizes, int n_in,
                              void* d_out, int out_size, void* d_ws, size_t ws_size,
                              hipStream_t stream) {
    const float* x   = (const float*)d_in[0];
    const int*   ei  = (const int*)  d_in[1];
    const float* Wg  = (const float*)d_in[2];
    const float* bg  = (const float*)d_in[3];
    const float* lng = (const float*)d_in[4];
    const float* lnb = (const float*)d_in[5];
    const float* W1  = (const float*)d_in[6];
    const float* b1  = (const float*)d_in[7];
    const float* W2  = (const float*)d_in[8];
    const float* b2  = (const float*)d_in[9];
    float* out = (float*)d_out;

    const int N = in_sizes[0] / D;
    const int E = in_sizes[1] / 2;
    const int* srcp = ei;
    const int* dstp = ei + E;

    char* ws = (char*)d_ws;
    size_t off = 0;
    auto alloc = [&](size_t bytes) -> void* {
        void* p = ws + off;
        off += (bytes + 511) & ~(size_t)511;
        return p;
    };
    int*   cnt    = (int*)  alloc((size_t)N * 4);
    int*   rowptr = (int*)  alloc((size_t)(N + 1) * 4);
    int*   cursor = (int*)  alloc((size_t)N * 4);
    int*   bsum   = (int*)  alloc(64 * 4);
    int2*  ecol   = (int2*) alloc((size_t)E * 8);
    float* dinv   = (float*)alloc((size_t)N * 4);
    u16*   z1h    = (u16*)  alloc((size_t)N * HH * 2);       // MLP1 out hi
    u16*   z1l    = (u16*)  alloc((size_t)N * HH * 2);       // MLP1 out lo
    u16*   hWb    = (u16*)  alloc((size_t)N * HH * 2);       // layer GEMM bf16 out
    u16*   xcH    = (u16*)  alloc((size_t)N * 512 * 2);      // [x|f1|f2|f3] hi
    u16*   xcL    = (u16*)  alloc((size_t)N * 512 * 2);      // lo
    u16*   WgtH   = (u16*)  alloc((size_t)NLAYERS * D * HH * 2);
    u16*   WgtL   = (u16*)  alloc((size_t)NLAYERS * D * HH * 2);
    u16*   W1tH   = (u16*)  alloc((size_t)(D + NLAYERS * HH) * HH * 2);
    u16*   W1tL   = (u16*)  alloc((size_t)(D + NLAYERS * HH) * HH * 2);
    u16*   W2tH   = (u16*)  alloc((size_t)HH * CC * 2);
    u16*   W2tL   = (u16*)  alloc((size_t)HH * CC * 2);

    const int B = 256;
    const int gN = (N + B - 1) / B;
    const int gE = (E + B - 1) / B;
    const int nsb = (N + 1023) / 1024;

    k_zero_cnt<<<gN, B, 0, stream>>>(cnt, N);
    k_count<<<gE, B, 0, stream>>>(dstp, cnt, E);
    k_dinv<<<gN, B, 0, stream>>>(cnt, dinv, N);
    k_scan_a<<<nsb, 1024, 0, stream>>>(cnt, rowptr, bsum, N);
    k_scan_b<<<1, 64, 0, stream>>>(bsum, nsb);
    k_scan_c<<<gN, B, 0, stream>>>(rowptr, bsum, cursor, N, E);
    k_scatter<<<gE, B, 0, stream>>>(srcp, dstp, dinv, cursor, ecol, E);

    // Split conversions
    k_split_x<<<(N * D + B - 1) / B, B, 0, stream>>>(x, xcH, xcL, N * D);
    for (int l = 0; l < NLAYERS; ++l)
        k_tile_w<<<(D * HH + B - 1) / B, B, 0, stream>>>(Wg + (size_t)l * D * HH,
                                                         WgtH + (size_t)l * D * HH,
                                                         WgtL + (size_t)l * D * HH, D * HH, 7);
    k_tile_w<<<((D + NLAYERS * HH) * HH + B - 1) / B, B, 0, stream>>>(W1, W1tH, W1tL,
                                                                      (D + NLAYERS * HH) * HH, 7);
    k_tile_w<<<(HH * CC + B - 1) / B, B, 0, stream>>>(W2, W2tH, W2tL, HH * CC, 6);

    const int gemmBlocks = (N + 63) / 64;
    const int aggBlocks = 2048;   // persistent: 8192 waves, ~6 nodes/wave

    for (int l = 0; l < NLAYERS; ++l) {
        // hWb = bf16(h @ Wg[l])  (bias added after aggregation)
        k_gemm_mfma<<<gemmBlocks, B, 0, stream>>>(xcH, xcL, l * HH,
                                                  WgtH + (size_t)l * D * HH,
                                                  nullptr, nullptr, hWb, nullptr, nullptr,
                                                  N, D, 0);
        k_agg_ln<<<aggBlocks, B, 0, stream>>>(hWb, rowptr, ecol, dinv,
                                              bg + (size_t)l * HH,
                                              lng + (size_t)l * HH,
                                              lnb + (size_t)l * HH,
                                              xcH + (size_t)(l + 1) * HH,
                                              xcL + (size_t)(l + 1) * HH, N);
    }

    // z1 = relu([x|f1|f2|f3] @ W1 + b1)  (bf16 hi/lo out)
    k_gemm_mfma<<<gemmBlocks, B, 0, stream>>>(xcH, xcL, 0, W1tH,
                                              b1, nullptr, nullptr, z1h, z1l,
                                              N, D + NLAYERS * HH, 1);

    // out = softmax(z1 @ W2 + b2)
    k_mlp2_mfma<<<gemmBlocks, B, 0, stream>>>(z1h, z1l, W2tH, W2tL, b2, out, N);
}

// Round 7
// 363.857 us; speedup vs baseline: 1.7849x; 1.0374x over previous
//
#include <hip/hip_runtime.h>
#include <math.h>

// Problem constants (shapes fixed by the reference)
#define D 128
#define HH 128
#define CC 64
#define NLAYERS 3
#define LN_EPS 1e-5f

typedef __attribute__((ext_vector_type(8))) short bf16x8;
typedef __attribute__((ext_vector_type(4))) float f32x4;
typedef unsigned short u16;
typedef unsigned int u32;

// round-to-nearest-even fp32 -> bf16 bits
__device__ __forceinline__ u16 f2bf(float f) {
    u32 u = __float_as_uint(f);
    u32 r = u + 0x7FFFu + ((u >> 16) & 1u);
    return (u16)(r >> 16);
}
__device__ __forceinline__ float bf2f(u16 h) {
    return __uint_as_float(((u32)h) << 16);
}

// ---------------------------------------------------------------------------
// Setup kernels: degree, CSR build (count -> scan -> scatter)
// ---------------------------------------------------------------------------

__global__ void k_zero_cnt(int* __restrict__ cnt, int n) {
    int i = blockIdx.x * blockDim.x + threadIdx.x;
    if (i < n) cnt[i] = 0;
}

__global__ void k_count(const int* __restrict__ dst, int* __restrict__ cnt, int E) {
    int i = blockIdx.x * blockDim.x + threadIdx.x;
    if (i < E) atomicAdd(&cnt[dst[i]], 1);
}

__global__ void k_dinv(const int* __restrict__ cnt, float* __restrict__ dinv, int N) {
    int i = blockIdx.x * blockDim.x + threadIdx.x;
    if (i < N) dinv[i] = rsqrtf(1.0f + (float)cnt[i]);
}

__global__ void k_scan_a(const int* __restrict__ cnt, int* __restrict__ rowptr,
                         int* __restrict__ bsum, int N) {
    __shared__ int s[1024];
    int tid = threadIdx.x;
    int i = blockIdx.x * 1024 + tid;
    int v = (i < N) ? cnt[i] : 0;
    s[tid] = v;
    __syncthreads();
    for (int off = 1; off < 1024; off <<= 1) {
        int t = (tid >= off) ? s[tid - off] : 0;
        __syncthreads();
        s[tid] += t;
        __syncthreads();
    }
    if (i < N) rowptr[i] = s[tid] - v;
    if (tid == 1023) bsum[blockIdx.x] = s[tid];
}

__global__ void k_scan_b(int* __restrict__ bsum, int nb) {
    int t = threadIdx.x;
    int v = (t < nb) ? bsum[t] : 0;
    int incl = v;
    for (int off = 1; off < 64; off <<= 1) {
        int u = __shfl_up(incl, off, 64);
        if (t >= off) incl += u;
    }
    if (t < nb) bsum[t] = incl - v;
}

__global__ void k_scan_c(int* __restrict__ rowptr, const int* __restrict__ bsum,
                         int* __restrict__ cursor, int N, int E) {
    int i = blockIdx.x * blockDim.x + threadIdx.x;
    if (i < N) {
        int v = rowptr[i] + bsum[i >> 10];
        rowptr[i] = v;
        cursor[i] = v;
    }
    if (i == 0) rowptr[N] = E;
}

// Scatter edges into CSR; pack src index + precomputed coef (dinv_s * dinv_d)
__global__ void k_scatter(const int* __restrict__ src, const int* __restrict__ dst,
                          const float* __restrict__ dinv,
                          int* __restrict__ cursor, int2* __restrict__ ecol, int E) {
    int i = blockIdx.x * blockDim.x + threadIdx.x;
    if (i < E) {
        int s = src[i], d = dst[i];
        int p = atomicAdd(&cursor[d], 1);
        float c = dinv[s] * dinv[d];
        ecol[p] = make_int2(s, __float_as_int(c));
    }
}

// ---------------------------------------------------------------------------
// Split conversions: x -> xc cols 0:128 (hi/lo bf16); weights -> MFMA-tiled hi/lo
// ---------------------------------------------------------------------------

__global__ void k_split_x(const float* __restrict__ x, u16* __restrict__ xh,
                          u16* __restrict__ xl, int total) {
    int i = blockIdx.x * blockDim.x + threadIdx.x;
    if (i >= total) return;
    int row = i >> 7, c = i & 127;
    float v = x[i];
    u16 h = f2bf(v);
    u16 l = f2bf(v - bf2f(h));
    xh[(size_t)row * 512 + c] = h;
    xl[(size_t)row * 512 + c] = l;
}

// W[K][Ncols] (row-major, Ncols = 1<<nshift) -> tiled [kc][q][n][j], k = kc*32+q*8+j
__global__ void k_tile_w(const float* __restrict__ W, u16* __restrict__ th,
                         u16* __restrict__ tl, int KN, int nshift) {
    int idx = blockIdx.x * blockDim.x + threadIdx.x;
    if (idx >= KN) return;
    int k = idx >> nshift, n = idx & ((1 << nshift) - 1);
    int kc = k >> 5, q = (k >> 3) & 3, j = k & 7;
    float v = W[idx];
    u16 h = f2bf(v);
    u16 l = f2bf(v - bf2f(h));
    int o = (((kc * 4 + q) << nshift) + n) * 8 + j;
    th[o] = h;
    tl[o] = l;
}

// ---------------------------------------------------------------------------
// LDS-free split-2 MFMA GEMM (layer GEMMs): hWb = bf16(A[N][K] @ W[K][128]).
// No LDS, no barriers: each lane loads its MFMA fragments directly from
// global (A 16B-aligned per-row segments; B pre-tiled, L2-resident), with
// register double-buffering. Wave tile 32x64; block 64x128.
// ---------------------------------------------------------------------------
__global__ __launch_bounds__(256) void k_gemm_lf(
    const u16* __restrict__ Ahi, const u16* __restrict__ Alo, int colOff,
    const u16* __restrict__ Bt, u16* __restrict__ OUTb, int N, int nch)
{
    const int tid  = threadIdx.x;
    const int lane = tid & 63;
    const int wave = tid >> 6;
    const int wr   = wave & 1;   // row half
    const int wc   = wave >> 1;  // col half
    const int quad = lane >> 4;
    const int l15  = lane & 15;
    const int row0 = blockIdx.x * 64;

    const u16* pAh[2];
    const u16* pAl[2];
    #pragma unroll
    for (int i = 0; i < 2; ++i) {
        int r = row0 + wr * 32 + i * 16 + l15;
        if (r >= N) r = N - 1;
        size_t o = (size_t)r * 512 + colOff + quad * 8;
        pAh[i] = Ahi + o;
        pAl[i] = Alo + o;
    }
    const u16* pB = Bt + ((size_t)quad * 128 + wc * 64 + l15) * 8;

    f32x4 acc[2][4];
    #pragma unroll
    for (int i = 0; i < 2; ++i)
        #pragma unroll
        for (int j = 0; j < 4; ++j)
            #pragma unroll
            for (int r = 0; r < 4; ++r) acc[i][j][r] = 0.f;

    bf16x8 ah[2], al[2], bh[4];
    #pragma unroll
    for (int i = 0; i < 2; ++i) { ah[i] = *(const bf16x8*)pAh[i]; al[i] = *(const bf16x8*)pAl[i]; }
    #pragma unroll
    for (int j = 0; j < 4; ++j) bh[j] = *(const bf16x8*)(pB + j * 128);

    for (int kc = 0; kc < nch; ++kc) {
        bf16x8 nah[2], nal[2], nbh[4];
        if (kc + 1 < nch) {
            #pragma unroll
            for (int i = 0; i < 2; ++i) {
                nah[i] = *(const bf16x8*)(pAh[i] + (kc + 1) * 32);
                nal[i] = *(const bf16x8*)(pAl[i] + (kc + 1) * 32);
            }
            #pragma unroll
            for (int j = 0; j < 4; ++j)
                nbh[j] = *(const bf16x8*)(pB + (size_t)(kc + 1) * 4096 + j * 128);
        }
        #pragma unroll
        for (int i = 0; i < 2; ++i)
            #pragma unroll
            for (int j = 0; j < 4; ++j) {
                acc[i][j] = __builtin_amdgcn_mfma_f32_16x16x32_bf16(ah[i], bh[j], acc[i][j], 0, 0, 0);
                acc[i][j] = __builtin_amdgcn_mfma_f32_16x16x32_bf16(al[i], bh[j], acc[i][j], 0, 0, 0);
            }
        if (kc + 1 < nch) {
            #pragma unroll
            for (int i = 0; i < 2; ++i) { ah[i] = nah[i]; al[i] = nal[i]; }
            #pragma unroll
            for (int j = 0; j < 4; ++j) bh[j] = nbh[j];
        }
    }

    // epilogue: C/D layout col = lane&15, row = quad*4 + reg
    #pragma unroll
    for (int i = 0; i < 2; ++i) {
        #pragma unroll
        for (int j = 0; j < 4; ++j) {
            int col = wc * 64 + j * 16 + l15;
            #pragma unroll
            for (int r = 0; r < 4; ++r) {
                int grow = row0 + wr * 32 + i * 16 + quad * 4 + r;
                if (grow < N)
                    OUTb[(size_t)grow * 128 + col] = f2bf(acc[i][j][r]);
            }
        }
    }
}

// ---------------------------------------------------------------------------
// Fused MLP: z1 = relu(xc @ W1 + b1) (K=512, LDS-free split-2 K-loop), then
// z1 -> LDS (A-fragment layout, split hi/lo), then out = softmax(z1@W2 + b2)
// via split-3 MFMA. Kills the z1 global round-trip and one launch.
// ---------------------------------------------------------------------------
__global__ __launch_bounds__(256) void k_mlp_fused(
    const u16* __restrict__ Ahi, const u16* __restrict__ Alo,
    const u16* __restrict__ B1t, const float* __restrict__ b1,
    const u16* __restrict__ W2h, const u16* __restrict__ W2l,
    const float* __restrict__ b2, float* __restrict__ out, int N)
{
    __shared__ u16 sZh[64 * 128];   // [(qq*64 + r)*8 + j], k(col) = qq*8+j
    __shared__ u16 sZl[64 * 128];

    const int tid  = threadIdx.x;
    const int lane = tid & 63;
    const int wave = tid >> 6;
    const int wr   = wave & 1;
    const int wc   = wave >> 1;
    const int quad = lane >> 4;
    const int l15  = lane & 15;
    const int row0 = blockIdx.x * 64;

    // ---- phase 1: z1 tile via LDS-free K=512 loop (16 chunks) ----
    const u16* pAh[2];
    const u16* pAl[2];
    #pragma unroll
    for (int i = 0; i < 2; ++i) {
        int r = row0 + wr * 32 + i * 16 + l15;
        if (r >= N) r = N - 1;
        size_t o = (size_t)r * 512 + quad * 8;
        pAh[i] = Ahi + o;
        pAl[i] = Alo + o;
    }
    const u16* pB = B1t + ((size_t)quad * 128 + wc * 64 + l15) * 8;

    f32x4 acc[2][4];
    #pragma unroll
    for (int i = 0; i < 2; ++i)
        #pragma unroll
        for (int j = 0; j < 4; ++j)
            #pragma unroll
            for (int r = 0; r < 4; ++r) acc[i][j][r] = 0.f;

    bf16x8 ah[2], al[2], bh[4];
    #pragma unroll
    for (int i = 0; i < 2; ++i) { ah[i] = *(const bf16x8*)pAh[i]; al[i] = *(const bf16x8*)pAl[i]; }
    #pragma unroll
    for (int j = 0; j < 4; ++j) bh[j] = *(const bf16x8*)(pB + j * 128);

    const int nch = 16;   // K = 512
    for (int kc = 0; kc < nch; ++kc) {
        bf16x8 nah[2], nal[2], nbh[4];
        if (kc + 1 < nch) {
            #pragma unroll
            for (int i = 0; i < 2; ++i) {
                nah[i] = *(const bf16x8*)(pAh[i] + (kc + 1) * 32);
                nal[i] = *(const bf16x8*)(pAl[i] + (kc + 1) * 32);
            }
            #pragma unroll
            for (int j = 0; j < 4; ++j)
                nbh[j] = *(const bf16x8*)(pB + (size_t)(kc + 1) * 4096 + j * 128);
        }
        #pragma unroll
        for (int i = 0; i < 2; ++i)
            #pragma unroll
            for (int j = 0; j < 4; ++j) {
                acc[i][j] = __builtin_amdgcn_mfma_f32_16x16x32_bf16(ah[i], bh[j], acc[i][j], 0, 0, 0);
                acc[i][j] = __builtin_amdgcn_mfma_f32_16x16x32_bf16(al[i], bh[j], acc[i][j], 0, 0, 0);
            }
        if (kc + 1 < nch) {
            #pragma unroll
            for (int i = 0; i < 2; ++i) { ah[i] = nah[i]; al[i] = nal[i]; }
            #pragma unroll
            for (int j = 0; j < 4; ++j) bh[j] = nbh[j];
        }
    }

    // ---- epilogue: bias + relu + split -> LDS in mlp2 A-fragment layout ----
    #pragma unroll
    for (int jt = 0; jt < 4; ++jt) {
        int col = wc * 64 + jt * 16 + l15;
        float bv = b1[col];
        int qq = col >> 3, jj = col & 7;
        #pragma unroll
        for (int i = 0; i < 2; ++i) {
            #pragma unroll
            for (int rr = 0; rr < 4; ++rr) {
                int r = wr * 32 + i * 16 + quad * 4 + rr;
                float v = fmaxf(acc[i][jt][rr] + bv, 0.f);
                u16 h = f2bf(v);
                sZh[(qq * 64 + r) * 8 + jj] = h;
                sZl[(qq * 64 + r) * 8 + jj] = f2bf(v - bf2f(h));
            }
        }
    }
    __syncthreads();

    // ---- phase 2: MLP2 (128->64) + softmax; wave handles rows wave*16..+15
    f32x4 oacc[4];
    #pragma unroll
    for (int j = 0; j < 4; ++j)
        #pragma unroll
        for (int r = 0; r < 4; ++r) oacc[j][r] = 0.f;

    #pragma unroll
    for (int kc = 0; kc < 4; ++kc) {
        int qq = kc * 4 + quad;
        bf16x8 zh = *(const bf16x8*)&sZh[(qq * 64 + wave * 16 + l15) * 8];
        bf16x8 zl = *(const bf16x8*)&sZl[(qq * 64 + wave * 16 + l15) * 8];
        #pragma unroll
        for (int jt = 0; jt < 4; ++jt) {
            int n = jt * 16 + l15;
            bf16x8 wh = *(const bf16x8*)&W2h[(qq * 64 + n) * 8];
            bf16x8 wl = *(const bf16x8*)&W2l[(qq * 64 + n) * 8];
            oacc[jt] = __builtin_amdgcn_mfma_f32_16x16x32_bf16(zh, wh, oacc[jt], 0, 0, 0);
            oacc[jt] = __builtin_amdgcn_mfma_f32_16x16x32_bf16(zh, wl, oacc[jt], 0, 0, 0);
            oacc[jt] = __builtin_amdgcn_mfma_f32_16x16x32_bf16(zl, wh, oacc[jt], 0, 0, 0);
        }
    }

    #pragma unroll
    for (int jt = 0; jt < 4; ++jt) {
        float bv = b2[jt * 16 + l15];
        #pragma unroll
        for (int r = 0; r < 4; ++r) oacc[jt][r] += bv;
    }
    #pragma unroll
    for (int r = 0; r < 4; ++r) {
        float m = fmaxf(fmaxf(oacc[0][r], oacc[1][r]), fmaxf(oacc[2][r], oacc[3][r]));
        #pragma unroll
        for (int mask = 8; mask; mask >>= 1) m = fmaxf(m, __shfl_xor(m, mask, 64));
        float p0 = __expf(oacc[0][r] - m);
        float p1 = __expf(oacc[1][r] - m);
        float p2 = __expf(oacc[2][r] - m);
        float p3 = __expf(oacc[3][r] - m);
        float s = p0 + p1 + p2 + p3;
        #pragma unroll
        for (int mask = 8; mask; mask >>= 1) s += __shfl_xor(s, mask, 64);
        float inv = 1.0f / s;
        int grow = row0 + wave * 16 + quad * 4 + r;
        if (grow < N) {
            float* o = out + (size_t)grow * CC + l15;
            o[0]  = p0 * inv;
            o[16] = p1 * inv;
            o[32] = p2 * inv;
            o[48] = p3 * inv;
        }
    }
}

// ---------------------------------------------------------------------------
// Aggregation (symmetric-normalized, self-loop) + bias + LayerNorm + ReLU.
// Persistent grid-stride waves; hW gathered as bf16 (256 B/row).
// ---------------------------------------------------------------------------
__global__ __launch_bounds__(256, 8) void k_agg_ln(
    const u16* __restrict__ hWb,
    const int* __restrict__ rowptr, const int2* __restrict__ ecol,
    const float* __restrict__ dinv,
    const float* __restrict__ bg, const float* __restrict__ g,
    const float* __restrict__ b,
    u16* __restrict__ outHi, u16* __restrict__ outLo, int N)
{
    const int lane = threadIdx.x & 63;
    const int f0 = lane * 2;

    const float bgx = bg[f0], bgy = bg[f0 + 1];
    const float gx  = g[f0],  gy  = g[f0 + 1];
    const float bx  = b[f0],  by  = b[f0 + 1];

    const int nwaves = gridDim.x * 4;
    for (int wid = blockIdx.x * 4 + (threadIdx.x >> 6); wid < N; wid += nwaves) {
        float di = dinv[wid];
        float sc = di * di;

        u32 hv = *(const u32*)(hWb + (size_t)wid * HH + f0);
        float ax  = bf2f((u16)hv) * sc;
        float ay  = bf2f((u16)(hv >> 16)) * sc;
        float ax1 = 0.f, ay1 = 0.f, ax2 = 0.f, ay2 = 0.f, ax3 = 0.f, ay3 = 0.f;

        int e0 = rowptr[wid];
        int e1 = rowptr[wid + 1];
        int e = e0;
        for (; e + 4 <= e1; e += 4) {
            int2 p0 = ecol[e];
            int2 p1 = ecol[e + 1];
            int2 p2 = ecol[e + 2];
            int2 p3 = ecol[e + 3];
            u32 v0 = *(const u32*)(hWb + (size_t)p0.x * HH + f0);
            u32 v1 = *(const u32*)(hWb + (size_t)p1.x * HH + f0);
            u32 v2 = *(const u32*)(hWb + (size_t)p2.x * HH + f0);
            u32 v3 = *(const u32*)(hWb + (size_t)p3.x * HH + f0);
            float c0 = __int_as_float(p0.y);
            float c1 = __int_as_float(p1.y);
            float c2 = __int_as_float(p2.y);
            float c3 = __int_as_float(p3.y);
            ax  += bf2f((u16)v0) * c0;  ay  += bf2f((u16)(v0 >> 16)) * c0;
            ax1 += bf2f((u16)v1) * c1;  ay1 += bf2f((u16)(v1 >> 16)) * c1;
            ax2 += bf2f((u16)v2) * c2;  ay2 += bf2f((u16)(v2 >> 16)) * c2;
            ax3 += bf2f((u16)v3) * c3;  ay3 += bf2f((u16)(v3 >> 16)) * c3;
        }
        for (; e < e1; ++e) {
            int2 p = ecol[e];
            u32 v = *(const u32*)(hWb + (size_t)p.x * HH + f0);
            float c = __int_as_float(p.y);
            ax += bf2f((u16)v) * c;
            ay += bf2f((u16)(v >> 16)) * c;
        }
        ax += ax1 + ax2 + ax3;
        ay += ay1 + ay2 + ay3;
        ax += bgx;
        ay += bgy;

        float ssum = ax + ay;
        #pragma unroll
        for (int off = 32; off; off >>= 1) ssum += __shfl_xor(ssum, off, 64);
        float mu = ssum * (1.0f / 128.0f);
        float dx = ax - mu, dy = ay - mu;
        float vsum = dx * dx + dy * dy;
        #pragma unroll
        for (int off = 32; off; off >>= 1) vsum += __shfl_xor(vsum, off, 64);
        float rstd = rsqrtf(vsum * (1.0f / 128.0f) + LN_EPS);

        float ox = fmaxf(gx * dx * rstd + bx, 0.f);
        float oy = fmaxf(gy * dy * rstd + by, 0.f);

        u16 hx = f2bf(ox); u16 lx = f2bf(ox - bf2f(hx));
        u16 hy = f2bf(oy); u16 ly = f2bf(oy - bf2f(hy));
        *(u32*)&outHi[(size_t)wid * 512 + f0] = (u32)hx | ((u32)hy << 16);
        *(u32*)&outLo[(size_t)wid * 512 + f0] = (u32)lx | ((u32)ly << 16);
    }
}

// ---------------------------------------------------------------------------
// Host launcher
// ---------------------------------------------------------------------------
extern "C" void kernel_launch(void* const* d_in, const int* in_sizes, int n_in,
                              void* d_out, int out_size, void* d_ws, size_t ws_size,
                              hipStream_t stream) {
    const float* x   = (const float*)d_in[0];
    const int*   ei  = (const int*)  d_in[1];
    const float* Wg  = (const float*)d_in[2];
    const float* bg  = (const float*)d_in[3];
    const float* lng = (const float*)d_in[4];
    const float* lnb = (const float*)d_in[5];
    const float* W1  = (const float*)d_in[6];
    const float* b1  = (const float*)d_in[7];
    const float* W2  = (const float*)d_in[8];
    const float* b2  = (const float*)d_in[9];
    float* out = (float*)d_out;

    const int N = in_sizes[0] / D;
    const int E = in_sizes[1] / 2;
    const int* srcp = ei;
    const int* dstp = ei + E;

    char* ws = (char*)d_ws;
    size_t off = 0;
    auto alloc = [&](size_t bytes) -> void* {
        void* p = ws + off;
        off += (bytes + 511) & ~(size_t)511;
        return p;
    };
    int*   cnt    = (int*)  alloc((size_t)N * 4);
    int*   rowptr = (int*)  alloc((size_t)(N + 1) * 4);
    int*   cursor = (int*)  alloc((size_t)N * 4);
    int*   bsum   = (int*)  alloc(64 * 4);
    int2*  ecol   = (int2*) alloc((size_t)E * 8);
    float* dinv   = (float*)alloc((size_t)N * 4);
    u16*   hWb    = (u16*)  alloc((size_t)N * HH * 2);       // layer GEMM bf16 out
    u16*   xcH    = (u16*)  alloc((size_t)N * 512 * 2);      // [x|f1|f2|f3] hi
    u16*   xcL    = (u16*)  alloc((size_t)N * 512 * 2);      // lo
    u16*   WgtH   = (u16*)  alloc((size_t)NLAYERS * D * HH * 2);
    u16*   WgtL   = (u16*)  alloc((size_t)NLAYERS * D * HH * 2);
    u16*   W1tH   = (u16*)  alloc((size_t)(D + NLAYERS * HH) * HH * 2);
    u16*   W1tL   = (u16*)  alloc((size_t)(D + NLAYERS * HH) * HH * 2);
    u16*   W2tH   = (u16*)  alloc((size_t)HH * CC * 2);
    u16*   W2tL   = (u16*)  alloc((size_t)HH * CC * 2);

    const int B = 256;
    const int gN = (N + B - 1) / B;
    const int gE = (E + B - 1) / B;
    const int nsb = (N + 1023) / 1024;

    k_zero_cnt<<<gN, B, 0, stream>>>(cnt, N);
    k_count<<<gE, B, 0, stream>>>(dstp, cnt, E);
    k_dinv<<<gN, B, 0, stream>>>(cnt, dinv, N);
    k_scan_a<<<nsb, 1024, 0, stream>>>(cnt, rowptr, bsum, N);
    k_scan_b<<<1, 64, 0, stream>>>(bsum, nsb);
    k_scan_c<<<gN, B, 0, stream>>>(rowptr, bsum, cursor, N, E);
    k_scatter<<<gE, B, 0, stream>>>(srcp, dstp, dinv, cursor, ecol, E);

    // Split conversions
    k_split_x<<<(N * D + B - 1) / B, B, 0, stream>>>(x, xcH, xcL, N * D);
    for (int l = 0; l < NLAYERS; ++l)
        k_tile_w<<<(D * HH + B - 1) / B, B, 0, stream>>>(Wg + (size_t)l * D * HH,
                                                         WgtH + (size_t)l * D * HH,
                                                         WgtL + (size_t)l * D * HH, D * HH, 7);
    k_tile_w<<<((D + NLAYERS * HH) * HH + B - 1) / B, B, 0, stream>>>(W1, W1tH, W1tL,
                                                                      (D + NLAYERS * HH) * HH, 7);
    k_tile_w<<<(HH * CC + B - 1) / B, B, 0, stream>>>(W2, W2tH, W2tL, HH * CC, 6);

    const int gemmBlocks = (N + 63) / 64;
    const int aggBlocks = 2048;   // persistent: 8192 waves, ~6 nodes/wave

    for (int l = 0; l < NLAYERS; ++l) {
        // hWb = bf16(h @ Wg[l])  (bias added after aggregation)
        k_gemm_lf<<<gemmBlocks, B, 0, stream>>>(xcH, xcL, l * HH,
                                                WgtH + (size_t)l * D * HH,
                                                hWb, N, D / 32);
        k_agg_ln<<<aggBlocks, B, 0, stream>>>(hWb, rowptr, ecol, dinv,
                                              bg + (size_t)l * HH,
                                              lng + (size_t)l * HH,
                                              lnb + (size_t)l * HH,
                                              xcH + (size_t)(l + 1) * HH,
                                              xcL + (size_t)(l + 1) * HH, N);
    }

    // out = softmax(relu([x|f1|f2|f3] @ W1 + b1) @ W2 + b2), fused
    k_mlp_fused<<<gemmBlocks, B, 0, stream>>>(xcH, xcL, W1tH, b1,
                                              W2tH, W2tL, b2, out, N);
}

// Round 8
// 356.322 us; speedup vs baseline: 1.8226x; 1.0211x over previous
//
#include <hip/hip_runtime.h>
#include <math.h>

// Problem constants (shapes fixed by the reference)
#define D 128
#define HH 128
#define CC 64
#define NLAYERS 3
#define LN_EPS 1e-5f

typedef __attribute__((ext_vector_type(8))) short bf16x8;
typedef __attribute__((ext_vector_type(4))) float f32x4;
typedef unsigned short u16;
typedef unsigned int u32;

// round-to-nearest-even fp32 -> bf16 bits
__device__ __forceinline__ u16 f2bf(float f) {
    u32 u = __float_as_uint(f);
    u32 r = u + 0x7FFFu + ((u >> 16) & 1u);
    return (u16)(r >> 16);
}
__device__ __forceinline__ float bf2f(u16 h) {
    return __uint_as_float(((u32)h) << 16);
}

// ---------------------------------------------------------------------------
// Setup kernels: degree, CSR build (count -> scan -> scatter)
// ---------------------------------------------------------------------------

__global__ void k_zero_cnt(int* __restrict__ cnt, int n) {
    int i = blockIdx.x * blockDim.x + threadIdx.x;
    if (i < n) cnt[i] = 0;
}

__global__ void k_count(const int* __restrict__ dst, int* __restrict__ cnt, int E) {
    int i = blockIdx.x * blockDim.x + threadIdx.x;
    if (i < E) atomicAdd(&cnt[dst[i]], 1);
}

__global__ void k_dinv(const int* __restrict__ cnt, float* __restrict__ dinv, int N) {
    int i = blockIdx.x * blockDim.x + threadIdx.x;
    if (i < N) dinv[i] = rsqrtf(1.0f + (float)cnt[i]);
}

__global__ void k_scan_a(const int* __restrict__ cnt, int* __restrict__ rowptr,
                         int* __restrict__ bsum, int N) {
    __shared__ int s[1024];
    int tid = threadIdx.x;
    int i = blockIdx.x * 1024 + tid;
    int v = (i < N) ? cnt[i] : 0;
    s[tid] = v;
    __syncthreads();
    for (int off = 1; off < 1024; off <<= 1) {
        int t = (tid >= off) ? s[tid - off] : 0;
        __syncthreads();
        s[tid] += t;
        __syncthreads();
    }
    if (i < N) rowptr[i] = s[tid] - v;
    if (tid == 1023) bsum[blockIdx.x] = s[tid];
}

__global__ void k_scan_b(int* __restrict__ bsum, int nb) {
    int t = threadIdx.x;
    int v = (t < nb) ? bsum[t] : 0;
    int incl = v;
    for (int off = 1; off < 64; off <<= 1) {
        int u = __shfl_up(incl, off, 64);
        if (t >= off) incl += u;
    }
    if (t < nb) bsum[t] = incl - v;
}

__global__ void k_scan_c(int* __restrict__ rowptr, const int* __restrict__ bsum,
                         int* __restrict__ cursor, int N, int E) {
    int i = blockIdx.x * blockDim.x + threadIdx.x;
    if (i < N) {
        int v = rowptr[i] + bsum[i >> 10];
        rowptr[i] = v;
        cursor[i] = v;
    }
    if (i == 0) rowptr[N] = E;
}

// Scatter edges into CSR; pack src index + precomputed coef (dinv_s * dinv_d)
__global__ void k_scatter(const int* __restrict__ src, const int* __restrict__ dst,
                          const float* __restrict__ dinv,
                          int* __restrict__ cursor, int2* __restrict__ ecol, int E) {
    int i = blockIdx.x * blockDim.x + threadIdx.x;
    if (i < E) {
        int s = src[i], d = dst[i];
        int p = atomicAdd(&cursor[d], 1);
        float c = dinv[s] * dinv[d];
        ecol[p] = make_int2(s, __float_as_int(c));
    }
}

// ---------------------------------------------------------------------------
// Split conversions
// ---------------------------------------------------------------------------

// x -> xcH cols 0:128 (hi, row stride 512) + xl (lo, row stride 128)
__global__ void k_split_x(const float* __restrict__ x, u16* __restrict__ xh,
                          u16* __restrict__ xl, int total) {
    int i = blockIdx.x * blockDim.x + threadIdx.x;
    if (i >= total) return;
    int row = i >> 7, c = i & 127;
    float v = x[i];
    u16 h = f2bf(v);
    u16 l = f2bf(v - bf2f(h));
    xh[(size_t)row * 512 + c] = h;
    xl[(size_t)row * 128 + c] = l;
}

// W[K][Ncols] (row-major, Ncols = 1<<nshift) -> tiled [kc][q][n][j], k = kc*32+q*8+j
// tl may be nullptr (hi only).
__global__ void k_tile_w(const float* __restrict__ W, u16* __restrict__ th,
                         u16* __restrict__ tl, int KN, int nshift) {
    int idx = blockIdx.x * blockDim.x + threadIdx.x;
    if (idx >= KN) return;
    int k = idx >> nshift, n = idx & ((1 << nshift) - 1);
    int kc = k >> 5, q = (k >> 3) & 3, j = k & 7;
    float v = W[idx];
    u16 h = f2bf(v);
    int o = (((kc * 4 + q) << nshift) + n) * 8 + j;
    th[o] = h;
    if (tl) tl[o] = f2bf(v - bf2f(h));
}

// ---------------------------------------------------------------------------
// Layer GEMM, K=128 fixed (4 chunks): hWb = bf16(A @ W). LDS-free; ALL 24-32
// fragment loads issued up front (one latency exposure), then 32-64 MFMAs.
// SPLIT2: A = hi+lo (exact A @ bf16 W), used for layer 0 (x input).
// Block 64 rows x 128 cols; wave tile 32x64.
// ---------------------------------------------------------------------------
template <bool SPLIT2>
__global__ __launch_bounds__(256) void k_gemm_lf(
    const u16* __restrict__ Ahi, int strideA, int colOff,
    const u16* __restrict__ Alo, int strideAlo,
    const u16* __restrict__ Bt, u16* __restrict__ OUTb, int N)
{
    const int tid  = threadIdx.x;
    const int lane = tid & 63;
    const int wave = tid >> 6;
    const int wr   = wave & 1;
    const int wc   = wave >> 1;
    const int quad = lane >> 4;
    const int l15  = lane & 15;
    const int row0 = blockIdx.x * 64;

    const u16* pAh[2];
    const u16* pAl[2];
    #pragma unroll
    for (int i = 0; i < 2; ++i) {
        int r = row0 + wr * 32 + i * 16 + l15;
        if (r >= N) r = N - 1;
        pAh[i] = Ahi + (size_t)r * strideA + colOff + quad * 8;
        if (SPLIT2) pAl[i] = Alo + (size_t)r * strideAlo + quad * 8;
    }
    const u16* pB = Bt + ((size_t)quad * 128 + wc * 64 + l15) * 8;

    // issue ALL loads up front
    bf16x8 ah[4][2], al[4][2], bh[4][4];
    #pragma unroll
    for (int kc = 0; kc < 4; ++kc) {
        #pragma unroll
        for (int i = 0; i < 2; ++i) {
            ah[kc][i] = *(const bf16x8*)(pAh[i] + kc * 32);
            if (SPLIT2) al[kc][i] = *(const bf16x8*)(pAl[i] + kc * 32);
        }
        #pragma unroll
        for (int j = 0; j < 4; ++j)
            bh[kc][j] = *(const bf16x8*)(pB + (size_t)kc * 4096 + j * 128);
    }

    f32x4 acc[2][4];
    #pragma unroll
    for (int i = 0; i < 2; ++i)
        #pragma unroll
        for (int j = 0; j < 4; ++j)
            #pragma unroll
            for (int r = 0; r < 4; ++r) acc[i][j][r] = 0.f;

    #pragma unroll
    for (int kc = 0; kc < 4; ++kc)
        #pragma unroll
        for (int i = 0; i < 2; ++i)
            #pragma unroll
            for (int j = 0; j < 4; ++j) {
                acc[i][j] = __builtin_amdgcn_mfma_f32_16x16x32_bf16(ah[kc][i], bh[kc][j], acc[i][j], 0, 0, 0);
                if (SPLIT2)
                    acc[i][j] = __builtin_amdgcn_mfma_f32_16x16x32_bf16(al[kc][i], bh[kc][j], acc[i][j], 0, 0, 0);
            }

    #pragma unroll
    for (int i = 0; i < 2; ++i)
        #pragma unroll
        for (int j = 0; j < 4; ++j) {
            int col = wc * 64 + j * 16 + l15;
            #pragma unroll
            for (int r = 0; r < 4; ++r) {
                int grow = row0 + wr * 32 + i * 16 + quad * 4 + r;
                if (grow < N)
                    OUTb[(size_t)grow * 128 + col] = f2bf(acc[i][j][r]);
            }
        }
}

// ---------------------------------------------------------------------------
// Fused MLP: z1 = relu(xc @ W1 + b1), K=512+128(x-lo) as 20 uniform chunks
// with a 3-buffer register pipeline (prefetch distance 2); z1 -> LDS (split
// hi/lo, A-frag layout); out = softmax(z1@W2 + b2). 32-row blocks for TLP.
// ---------------------------------------------------------------------------
__global__ __launch_bounds__(256) void k_mlp_fused(
    const u16* __restrict__ xcH, const u16* __restrict__ xl,
    const u16* __restrict__ B1t, const float* __restrict__ b1,
    const u16* __restrict__ W2h, const u16* __restrict__ W2l,
    const float* __restrict__ b2, float* __restrict__ out, int N)
{
    __shared__ u16 sZh[32 * 128];   // [(qq*32 + r)*8 + j], z1 col = qq*8+j
    __shared__ u16 sZl[32 * 128];

    const int tid  = threadIdx.x;
    const int lane = tid & 63;
    const int wave = tid >> 6;
    const int wr   = wave & 1;   // 16-row half
    const int wc   = wave >> 1;  // 64-col half
    const int quad = lane >> 4;
    const int l15  = lane & 15;
    const int row0 = blockIdx.x * 32;

    int arow = row0 + wr * 16 + l15;
    if (arow >= N) arow = N - 1;
    const u16* pAx = xcH + (size_t)arow * 512 + quad * 8;   // hi chunks 0..15
    const u16* pAl = xl  + (size_t)arow * 128 + quad * 8;   // x-lo chunks 16..19
    const u16* pB  = B1t + ((size_t)quad * 128 + wc * 64 + l15) * 8;

    f32x4 acc[4];
    #pragma unroll
    for (int j = 0; j < 4; ++j)
        #pragma unroll
        for (int r = 0; r < 4; ++r) acc[j][r] = 0.f;

    // 3-buffer pipeline: iter i uses buf[i%3], prefetches i+2 into buf[(i+2)%3]
    bf16x8 abuf[3], bbuf[3][4];
    #define LOADI(i, s)                                                          \
        {                                                                        \
            const int bk = ((i) < 16) ? (i) : ((i) - 16);                        \
            abuf[s] = ((i) < 16) ? *(const bf16x8*)(pAx + (i) * 32)              \
                                 : *(const bf16x8*)(pAl + ((i) - 16) * 32);      \
            _Pragma("unroll")                                                    \
            for (int j = 0; j < 4; ++j)                                          \
                bbuf[s][j] = *(const bf16x8*)(pB + (size_t)bk * 4096 + j * 128); \
        }
    LOADI(0, 0)
    LOADI(1, 1)
    #pragma unroll
    for (int i = 0; i < 20; ++i) {
        if (i + 2 < 20) {
            const int s = (i + 2) % 3;
            LOADI(i + 2, s)
        }
        const int u = i % 3;
        #pragma unroll
        for (int j = 0; j < 4; ++j)
            acc[j] = __builtin_amdgcn_mfma_f32_16x16x32_bf16(abuf[u], bbuf[u][j], acc[j], 0, 0, 0);
    }
    #undef LOADI

    // epilogue: bias + relu + split -> LDS in phase-2 A-fragment layout
    #pragma unroll
    for (int jt = 0; jt < 4; ++jt) {
        int col = wc * 64 + jt * 16 + l15;
        float bv = b1[col];
        int qq = col >> 3, jj = col & 7;
        #pragma unroll
        for (int rr = 0; rr < 4; ++rr) {
            int r = wr * 16 + quad * 4 + rr;
            float v = fmaxf(acc[jt][rr] + bv, 0.f);
            u16 h = f2bf(v);
            sZh[(qq * 32 + r) * 8 + jj] = h;
            sZl[(qq * 32 + r) * 8 + jj] = f2bf(v - bf2f(h));
        }
    }
    __syncthreads();

    // phase 2: MLP2 (128->64) + softmax on waves 0,1 (16 rows each)
    if (wave < 2) {
        f32x4 oacc[4];
        #pragma unroll
        for (int j = 0; j < 4; ++j)
            #pragma unroll
            for (int r = 0; r < 4; ++r) oacc[j][r] = 0.f;

        #pragma unroll
        for (int kc = 0; kc < 4; ++kc) {
            int qq = kc * 4 + quad;
            bf16x8 zh = *(const bf16x8*)&sZh[(qq * 32 + wave * 16 + l15) * 8];
            bf16x8 zl = *(const bf16x8*)&sZl[(qq * 32 + wave * 16 + l15) * 8];
            #pragma unroll
            for (int jt = 0; jt < 4; ++jt) {
                int n = jt * 16 + l15;
                bf16x8 wh = *(const bf16x8*)&W2h[(qq * 64 + n) * 8];
                bf16x8 wl = *(const bf16x8*)&W2l[(qq * 64 + n) * 8];
                oacc[jt] = __builtin_amdgcn_mfma_f32_16x16x32_bf16(zh, wh, oacc[jt], 0, 0, 0);
                oacc[jt] = __builtin_amdgcn_mfma_f32_16x16x32_bf16(zh, wl, oacc[jt], 0, 0, 0);
                oacc[jt] = __builtin_amdgcn_mfma_f32_16x16x32_bf16(zl, wh, oacc[jt], 0, 0, 0);
            }
        }

        #pragma unroll
        for (int jt = 0; jt < 4; ++jt) {
            float bv = b2[jt * 16 + l15];
            #pragma unroll
            for (int r = 0; r < 4; ++r) oacc[jt][r] += bv;
        }
        #pragma unroll
        for (int r = 0; r < 4; ++r) {
            float m = fmaxf(fmaxf(oacc[0][r], oacc[1][r]), fmaxf(oacc[2][r], oacc[3][r]));
            #pragma unroll
            for (int mask = 8; mask; mask >>= 1) m = fmaxf(m, __shfl_xor(m, mask, 64));
            float p0 = __expf(oacc[0][r] - m);
            float p1 = __expf(oacc[1][r] - m);
            float p2 = __expf(oacc[2][r] - m);
            float p3 = __expf(oacc[3][r] - m);
            float s = p0 + p1 + p2 + p3;
            #pragma unroll
            for (int mask = 8; mask; mask >>= 1) s += __shfl_xor(s, mask, 64);
            float inv = 1.0f / s;
            int grow = row0 + wave * 16 + quad * 4 + r;
            if (grow < N) {
                float* o = out + (size_t)grow * CC + l15;
                o[0]  = p0 * inv;
                o[16] = p1 * inv;
                o[32] = p2 * inv;
                o[48] = p3 * inv;
            }
        }
    }
}

// ---------------------------------------------------------------------------
// Aggregation (symmetric-normalized, self-loop) + bias + LayerNorm + ReLU.
// Persistent grid-stride waves; hW gathered as bf16. Output: single bf16
// (hi only) into xcH feature slice.
// ---------------------------------------------------------------------------
__global__ __launch_bounds__(256, 8) void k_agg_ln(
    const u16* __restrict__ hWb,
    const int* __restrict__ rowptr, const int2* __restrict__ ecol,
    const float* __restrict__ dinv,
    const float* __restrict__ bg, const float* __restrict__ g,
    const float* __restrict__ b,
    u16* __restrict__ outHi, int N)
{
    const int lane = threadIdx.x & 63;
    const int f0 = lane * 2;

    const float bgx = bg[f0], bgy = bg[f0 + 1];
    const float gx  = g[f0],  gy  = g[f0 + 1];
    const float bx  = b[f0],  by  = b[f0 + 1];

    const int nwaves = gridDim.x * 4;
    for (int wid = blockIdx.x * 4 + (threadIdx.x >> 6); wid < N; wid += nwaves) {
        float di = dinv[wid];
        float sc = di * di;

        u32 hv = *(const u32*)(hWb + (size_t)wid * HH + f0);
        float ax  = bf2f((u16)hv) * sc;
        float ay  = bf2f((u16)(hv >> 16)) * sc;
        float ax1 = 0.f, ay1 = 0.f, ax2 = 0.f, ay2 = 0.f, ax3 = 0.f, ay3 = 0.f;

        int e0 = rowptr[wid];
        int e1 = rowptr[wid + 1];
        int e = e0;
        for (; e + 4 <= e1; e += 4) {
            int2 p0 = ecol[e];
            int2 p1 = ecol[e + 1];
            int2 p2 = ecol[e + 2];
            int2 p3 = ecol[e + 3];
            u32 v0 = *(const u32*)(hWb + (size_t)p0.x * HH + f0);
            u32 v1 = *(const u32*)(hWb + (size_t)p1.x * HH + f0);
            u32 v2 = *(const u32*)(hWb + (size_t)p2.x * HH + f0);
            u32 v3 = *(const u32*)(hWb + (size_t)p3.x * HH + f0);
            float c0 = __int_as_float(p0.y);
            float c1 = __int_as_float(p1.y);
            float c2 = __int_as_float(p2.y);
            float c3 = __int_as_float(p3.y);
            ax  += bf2f((u16)v0) * c0;  ay  += bf2f((u16)(v0 >> 16)) * c0;
            ax1 += bf2f((u16)v1) * c1;  ay1 += bf2f((u16)(v1 >> 16)) * c1;
            ax2 += bf2f((u16)v2) * c2;  ay2 += bf2f((u16)(v2 >> 16)) * c2;
            ax3 += bf2f((u16)v3) * c3;  ay3 += bf2f((u16)(v3 >> 16)) * c3;
        }
        for (; e < e1; ++e) {
            int2 p = ecol[e];
            u32 v = *(const u32*)(hWb + (size_t)p.x * HH + f0);
            float c = __int_as_float(p.y);
            ax += bf2f((u16)v) * c;
            ay += bf2f((u16)(v >> 16)) * c;
        }
        ax += ax1 + ax2 + ax3;
        ay += ay1 + ay2 + ay3;
        ax += bgx;
        ay += bgy;

        float ssum = ax + ay;
        #pragma unroll
        for (int off = 32; off; off >>= 1) ssum += __shfl_xor(ssum, off, 64);
        float mu = ssum * (1.0f / 128.0f);
        float dx = ax - mu, dy = ay - mu;
        float vsum = dx * dx + dy * dy;
        #pragma unroll
        for (int off = 32; off; off >>= 1) vsum += __shfl_xor(vsum, off, 64);
        float rstd = rsqrtf(vsum * (1.0f / 128.0f) + LN_EPS);

        float ox = fmaxf(gx * dx * rstd + bx, 0.f);
        float oy = fmaxf(gy * dy * rstd + by, 0.f);

        *(u32*)&outHi[(size_t)wid * 512 + f0] = (u32)f2bf(ox) | ((u32)f2bf(oy) << 16);
    }
}

// ---------------------------------------------------------------------------
// Host launcher
// ---------------------------------------------------------------------------
extern "C" void kernel_launch(void* const* d_in, const int* in_sizes, int n_in,
                              void* d_out, int out_size, void* d_ws, size_t ws_size,
                              hipStream_t stream) {
    const float* x   = (const float*)d_in[0];
    const int*   ei  = (const int*)  d_in[1];
    const float* Wg  = (const float*)d_in[2];
    const float* bg  = (const float*)d_in[3];
    const float* lng = (const float*)d_in[4];
    const float* lnb = (const float*)d_in[5];
    const float* W1  = (const float*)d_in[6];
    const float* b1  = (const float*)d_in[7];
    const float* W2  = (const float*)d_in[8];
    const float* b2  = (const float*)d_in[9];
    float* out = (float*)d_out;

    const int N = in_sizes[0] / D;
    const int E = in_sizes[1] / 2;
    const int* srcp = ei;
    const int* dstp = ei + E;

    char* ws = (char*)d_ws;
    size_t off = 0;
    auto alloc = [&](size_t bytes) -> void* {
        void* p = ws + off;
        off += (bytes + 511) & ~(size_t)511;
        return p;
    };
    int*   cnt    = (int*)  alloc((size_t)N * 4);
    int*   rowptr = (int*)  alloc((size_t)(N + 1) * 4);
    int*   cursor = (int*)  alloc((size_t)N * 4);
    int*   bsum   = (int*)  alloc(64 * 4);
    int2*  ecol   = (int2*) alloc((size_t)E * 8);
    float* dinv   = (float*)alloc((size_t)N * 4);
    u16*   hWb    = (u16*)  alloc((size_t)N * HH * 2);       // layer GEMM bf16 out
    u16*   xcH    = (u16*)  alloc((size_t)N * 512 * 2);      // [x_hi|f1|f2|f3]
    u16*   xl     = (u16*)  alloc((size_t)N * 128 * 2);      // x lo plane
    u16*   WgtH   = (u16*)  alloc((size_t)NLAYERS * D * HH * 2);
    u16*   W1tH   = (u16*)  alloc((size_t)(D + NLAYERS * HH) * HH * 2);
    u16*   W2tH   = (u16*)  alloc((size_t)HH * CC * 2);
    u16*   W2tL   = (u16*)  alloc((size_t)HH * CC * 2);

    const int B = 256;
    const int gN = (N + B - 1) / B;
    const int gE = (E + B - 1) / B;
    const int nsb = (N + 1023) / 1024;

    k_zero_cnt<<<gN, B, 0, stream>>>(cnt, N);
    k_count<<<gE, B, 0, stream>>>(dstp, cnt, E);
    k_dinv<<<gN, B, 0, stream>>>(cnt, dinv, N);
    k_scan_a<<<nsb, 1024, 0, stream>>>(cnt, rowptr, bsum, N);
    k_scan_b<<<1, 64, 0, stream>>>(bsum, nsb);
    k_scan_c<<<gN, B, 0, stream>>>(rowptr, bsum, cursor, N, E);
    k_scatter<<<gE, B, 0, stream>>>(srcp, dstp, dinv, cursor, ecol, E);

    // Split conversions
    k_split_x<<<(N * D + B - 1) / B, B, 0, stream>>>(x, xcH, xl, N * D);
    for (int l = 0; l < NLAYERS; ++l)
        k_tile_w<<<(D * HH + B - 1) / B, B, 0, stream>>>(Wg + (size_t)l * D * HH,
                                                         WgtH + (size_t)l * D * HH,
                                                         nullptr, D * HH, 7);
    k_tile_w<<<((D + NLAYERS * HH) * HH + B - 1) / B, B, 0, stream>>>(W1, W1tH, nullptr,
                                                                      (D + NLAYERS * HH) * HH, 7);
    k_tile_w<<<(HH * CC + B - 1) / B, B, 0, stream>>>(W2, W2tH, W2tL, HH * CC, 6);

    const int gemmBlocks = (N + 63) / 64;
    const int mlpBlocks  = (N + 31) / 32;
    const int aggBlocks  = 2048;   // persistent: 8192 waves, ~6 nodes/wave

    for (int l = 0; l < NLAYERS; ++l) {
        // hWb = bf16(h @ Wg[l])  (bias added after aggregation)
        if (l == 0)
            k_gemm_lf<true><<<gemmBlocks, B, 0, stream>>>(xcH, 512, 0, xl, 128,
                                                          WgtH, hWb, N);
        else
            k_gemm_lf<false><<<gemmBlocks, B, 0, stream>>>(xcH, 512, l * HH, nullptr, 0,
                                                           WgtH + (size_t)l * D * HH, hWb, N);
        k_agg_ln<<<aggBlocks, B, 0, stream>>>(hWb, rowptr, ecol, dinv,
                                              bg + (size_t)l * HH,
                                              lng + (size_t)l * HH,
                                              lnb + (size_t)l * HH,
                                              xcH + (size_t)(l + 1) * HH, N);
    }

    // out = softmax(relu([x|f1|f2|f3] @ W1 + b1) @ W2 + b2), fused
    k_mlp_fused<<<mlpBlocks, B, 0, stream>>>(xcH, xl, W1tH, b1,
                                             W2tH, W2tL, b2, out, N);
}

// Round 9
// 346.819 us; speedup vs baseline: 1.8726x; 1.0274x over previous
//
#include <hip/hip_runtime.h>
#include <math.h>

// Problem constants (shapes fixed by the reference)
#define D 128
#define HH 128
#define CC 64
#define NLAYERS 3
#define LN_EPS 1e-5f

typedef __attribute__((ext_vector_type(8))) short bf16x8;
typedef __attribute__((ext_vector_type(4))) float f32x4;
typedef unsigned short u16;
typedef unsigned int u32;

// round-to-nearest-even fp32 -> bf16 bits
__device__ __forceinline__ u16 f2bf(float f) {
    u32 u = __float_as_uint(f);
    u32 r = u + 0x7FFFu + ((u >> 16) & 1u);
    return (u16)(r >> 16);
}
__device__ __forceinline__ float bf2f(u16 h) {
    return __uint_as_float(((u32)h) << 16);
}

// ---------------------------------------------------------------------------
// Setup kernels: degree, CSR build (count -> scan -> scatter)
// ---------------------------------------------------------------------------

__global__ void k_zero_cnt(int* __restrict__ cnt, int n) {
    int i = blockIdx.x * blockDim.x + threadIdx.x;
    if (i < n) cnt[i] = 0;
}

__global__ void k_count(const int* __restrict__ dst, int* __restrict__ cnt, int E) {
    int i = blockIdx.x * blockDim.x + threadIdx.x;
    if (i < E) atomicAdd(&cnt[dst[i]], 1);
}

__global__ void k_scan_a(const int* __restrict__ cnt, int* __restrict__ rowptr,
                         int* __restrict__ bsum, int N) {
    __shared__ int s[1024];
    int tid = threadIdx.x;
    int i = blockIdx.x * 1024 + tid;
    int v = (i < N) ? cnt[i] : 0;
    s[tid] = v;
    __syncthreads();
    for (int off = 1; off < 1024; off <<= 1) {
        int t = (tid >= off) ? s[tid - off] : 0;
        __syncthreads();
        s[tid] += t;
        __syncthreads();
    }
    if (i < N) rowptr[i] = s[tid] - v;
    if (tid == 1023) bsum[blockIdx.x] = s[tid];
}

__global__ void k_scan_b(int* __restrict__ bsum, int nb) {
    int t = threadIdx.x;
    int v = (t < nb) ? bsum[t] : 0;
    int incl = v;
    for (int off = 1; off < 64; off <<= 1) {
        int u = __shfl_up(incl, off, 64);
        if (t >= off) incl += u;
    }
    if (t < nb) bsum[t] = incl - v;
}

// scan finalize + dinv (fused)
__global__ void k_scan_c(int* __restrict__ rowptr, const int* __restrict__ bsum,
                         const int* __restrict__ cnt, float* __restrict__ dinv,
                         int* __restrict__ cursor, int N, int E) {
    int i = blockIdx.x * blockDim.x + threadIdx.x;
    if (i < N) {
        int v = rowptr[i] + bsum[i >> 10];
        rowptr[i] = v;
        cursor[i] = v;
        dinv[i] = rsqrtf(1.0f + (float)cnt[i]);
    }
    if (i == 0) rowptr[N] = E;
}

// Scatter edges into CSR; pack src index + precomputed coef (dinv_s * dinv_d)
__global__ void k_scatter(const int* __restrict__ src, const int* __restrict__ dst,
                          const float* __restrict__ dinv,
                          int* __restrict__ cursor, int2* __restrict__ ecol, int E) {
    int i = blockIdx.x * blockDim.x + threadIdx.x;
    if (i < E) {
        int s = src[i], d = dst[i];
        int p = atomicAdd(&cursor[d], 1);
        float c = dinv[s] * dinv[d];
        ecol[p] = make_int2(s, __float_as_int(c));
    }
}

// ---------------------------------------------------------------------------
// Split conversions
// ---------------------------------------------------------------------------

// x -> xcH cols 0:128 (hi, row stride 512) + xl (lo, row stride 128)
__global__ void k_split_x(const float* __restrict__ x, u16* __restrict__ xh,
                          u16* __restrict__ xl, int total) {
    int i = blockIdx.x * blockDim.x + threadIdx.x;
    if (i >= total) return;
    int row = i >> 7, c = i & 127;
    float v = x[i];
    u16 h = f2bf(v);
    u16 l = f2bf(v - bf2f(h));
    xh[(size_t)row * 512 + c] = h;
    xl[(size_t)row * 128 + c] = l;
}

// W[K][Ncols] (row-major, Ncols = 1<<nshift) -> tiled [kc][q][n][j], k = kc*32+q*8+j
// tl may be nullptr (hi only).
__global__ void k_tile_w(const float* __restrict__ W, u16* __restrict__ th,
                         u16* __restrict__ tl, int KN, int nshift) {
    int idx = blockIdx.x * blockDim.x + threadIdx.x;
    if (idx >= KN) return;
    int k = idx >> nshift, n = idx & ((1 << nshift) - 1);
    int kc = k >> 5, q = (k >> 3) & 3, j = k & 7;
    float v = W[idx];
    u16 h = f2bf(v);
    int o = (((kc * 4 + q) << nshift) + n) * 8 + j;
    th[o] = h;
    if (tl) tl[o] = f2bf(v - bf2f(h));
}

// ---------------------------------------------------------------------------
// Layer GEMM, K=128 fixed (4 chunks): hWb = bf16(A @ W). LDS-free; all
// fragment loads issued up front, then MFMAs. SPLIT2 for layer 0 (x hi+lo).
// Block 64 rows x 128 cols; wave tile 32x64.
// ---------------------------------------------------------------------------
template <bool SPLIT2>
__global__ __launch_bounds__(256) void k_gemm_lf(
    const u16* __restrict__ Ahi, int strideA, int colOff,
    const u16* __restrict__ Alo, int strideAlo,
    const u16* __restrict__ Bt, u16* __restrict__ OUTb, int N)
{
    const int tid  = threadIdx.x;
    const int lane = tid & 63;
    const int wave = tid >> 6;
    const int wr   = wave & 1;
    const int wc   = wave >> 1;
    const int quad = lane >> 4;
    const int l15  = lane & 15;
    const int row0 = blockIdx.x * 64;

    const u16* pAh[2];
    const u16* pAl[2];
    #pragma unroll
    for (int i = 0; i < 2; ++i) {
        int r = row0 + wr * 32 + i * 16 + l15;
        if (r >= N) r = N - 1;
        pAh[i] = Ahi + (size_t)r * strideA + colOff + quad * 8;
        if (SPLIT2) pAl[i] = Alo + (size_t)r * strideAlo + quad * 8;
    }
    const u16* pB = Bt + ((size_t)quad * 128 + wc * 64 + l15) * 8;

    bf16x8 ah[4][2], al[4][2], bh[4][4];
    #pragma unroll
    for (int kc = 0; kc < 4; ++kc) {
        #pragma unroll
        for (int i = 0; i < 2; ++i) {
            ah[kc][i] = *(const bf16x8*)(pAh[i] + kc * 32);
            if (SPLIT2) al[kc][i] = *(const bf16x8*)(pAl[i] + kc * 32);
        }
        #pragma unroll
        for (int j = 0; j < 4; ++j)
            bh[kc][j] = *(const bf16x8*)(pB + (size_t)kc * 4096 + j * 128);
    }

    f32x4 acc[2][4];
    #pragma unroll
    for (int i = 0; i < 2; ++i)
        #pragma unroll
        for (int j = 0; j < 4; ++j)
            #pragma unroll
            for (int r = 0; r < 4; ++r) acc[i][j][r] = 0.f;

    #pragma unroll
    for (int kc = 0; kc < 4; ++kc)
        #pragma unroll
        for (int i = 0; i < 2; ++i)
            #pragma unroll
            for (int j = 0; j < 4; ++j) {
                acc[i][j] = __builtin_amdgcn_mfma_f32_16x16x32_bf16(ah[kc][i], bh[kc][j], acc[i][j], 0, 0, 0);
                if (SPLIT2)
                    acc[i][j] = __builtin_amdgcn_mfma_f32_16x16x32_bf16(al[kc][i], bh[kc][j], acc[i][j], 0, 0, 0);
            }

    #pragma unroll
    for (int i = 0; i < 2; ++i)
        #pragma unroll
        for (int j = 0; j < 4; ++j) {
            int col = wc * 64 + j * 16 + l15;
            #pragma unroll
            for (int r = 0; r < 4; ++r) {
                int grow = row0 + wr * 32 + i * 16 + quad * 4 + r;
                if (grow < N)
                    OUTb[(size_t)grow * 128 + col] = f2bf(acc[i][j][r]);
            }
        }
}

// ---------------------------------------------------------------------------
// Fused MLP v3: z1 = relu(xc @ W1 + b1). Wave tile 32 rows x 64 cols
// (8 MFMAs per chunk vs 6 loads); 4-buffer register pipeline (distance 3,
// ~18 outstanding loads/wave). 20 uniform K-chunks (16 hi + 4 x-lo).
// z1 -> LDS (split hi/lo, A-frag layout); softmax phase uses all 4 waves.
// ---------------------------------------------------------------------------
__global__ __launch_bounds__(256) void k_mlp_fused(
    const u16* __restrict__ xcH, const u16* __restrict__ xl,
    const u16* __restrict__ B1t, const float* __restrict__ b1,
    const u16* __restrict__ W2h, const u16* __restrict__ W2l,
    const float* __restrict__ b2, float* __restrict__ out, int N)
{
    __shared__ u16 sZh[64 * 128];   // [(qq*64 + r)*8 + j], z1 col = qq*8+j
    __shared__ u16 sZl[64 * 128];

    const int tid  = threadIdx.x;
    const int lane = tid & 63;
    const int wave = tid >> 6;
    const int wr   = wave & 1;   // 32-row half
    const int wc   = wave >> 1;  // 64-col half
    const int quad = lane >> 4;
    const int l15  = lane & 15;
    const int row0 = blockIdx.x * 64;

    const u16* pAh[2];
    const u16* pAl[2];
    #pragma unroll
    for (int f = 0; f < 2; ++f) {
        int r = row0 + wr * 32 + f * 16 + l15;
        if (r >= N) r = N - 1;
        pAh[f] = xcH + (size_t)r * 512 + quad * 8;   // hi chunks 0..15
        pAl[f] = xl  + (size_t)r * 128 + quad * 8;   // x-lo chunks 16..19
    }
    const u16* pB = B1t + ((size_t)quad * 128 + wc * 64 + l15) * 8;

    f32x4 acc[2][4];
    #pragma unroll
    for (int f = 0; f < 2; ++f)
        #pragma unroll
        for (int j = 0; j < 4; ++j)
            #pragma unroll
            for (int r = 0; r < 4; ++r) acc[f][j][r] = 0.f;

    // 4-buffer pipeline: iter i uses buf[i&3], prefetches i+3 into buf[(i+3)&3]
    bf16x8 abuf[4][2], bbuf[4][4];
    #define LOADI(i, s)                                                          \
        {                                                                        \
            const int bk = ((i) < 16) ? (i) : ((i) - 16);                        \
            _Pragma("unroll")                                                    \
            for (int f = 0; f < 2; ++f)                                          \
                abuf[s][f] = ((i) < 16)                                          \
                    ? *(const bf16x8*)(pAh[f] + (i) * 32)                        \
                    : *(const bf16x8*)(pAl[f] + ((i) - 16) * 32);                \
            _Pragma("unroll")                                                    \
            for (int j = 0; j < 4; ++j)                                          \
                bbuf[s][j] = *(const bf16x8*)(pB + (size_t)bk * 4096 + j * 128); \
        }
    LOADI(0, 0)
    LOADI(1, 1)
    LOADI(2, 2)
    #pragma unroll
    for (int i = 0; i < 20; ++i) {
        if (i + 3 < 20) {
            const int s = (i + 3) & 3;
            LOADI(i + 3, s)
        }
        const int u = i & 3;
        #pragma unroll
        for (int f = 0; f < 2; ++f)
            #pragma unroll
            for (int j = 0; j < 4; ++j)
                acc[f][j] = __builtin_amdgcn_mfma_f32_16x16x32_bf16(abuf[u][f], bbuf[u][j], acc[f][j], 0, 0, 0);
    }
    #undef LOADI

    // epilogue: bias + relu + split -> LDS in phase-2 A-fragment layout
    #pragma unroll
    for (int jt = 0; jt < 4; ++jt) {
        int col = wc * 64 + jt * 16 + l15;
        float bv = b1[col];
        int qq = col >> 3, jj = col & 7;
        #pragma unroll
        for (int f = 0; f < 2; ++f) {
            #pragma unroll
            for (int rr = 0; rr < 4; ++rr) {
                int r = wr * 32 + f * 16 + quad * 4 + rr;
                float v = fmaxf(acc[f][jt][rr] + bv, 0.f);
                u16 h = f2bf(v);
                sZh[(qq * 64 + r) * 8 + jj] = h;
                sZl[(qq * 64 + r) * 8 + jj] = f2bf(v - bf2f(h));
            }
        }
    }
    __syncthreads();

    // phase 2: MLP2 (128->64) + softmax; each wave handles 16 rows
    f32x4 oacc[4];
    #pragma unroll
    for (int j = 0; j < 4; ++j)
        #pragma unroll
        for (int r = 0; r < 4; ++r) oacc[j][r] = 0.f;

    #pragma unroll
    for (int kc = 0; kc < 4; ++kc) {
        int qq = kc * 4 + quad;
        bf16x8 zh = *(const bf16x8*)&sZh[(qq * 64 + wave * 16 + l15) * 8];
        bf16x8 zl = *(const bf16x8*)&sZl[(qq * 64 + wave * 16 + l15) * 8];
        #pragma unroll
        for (int jt = 0; jt < 4; ++jt) {
            int n = jt * 16 + l15;
            bf16x8 wh = *(const bf16x8*)&W2h[(qq * 64 + n) * 8];
            bf16x8 wl = *(const bf16x8*)&W2l[(qq * 64 + n) * 8];
            oacc[jt] = __builtin_amdgcn_mfma_f32_16x16x32_bf16(zh, wh, oacc[jt], 0, 0, 0);
            oacc[jt] = __builtin_amdgcn_mfma_f32_16x16x32_bf16(zh, wl, oacc[jt], 0, 0, 0);
            oacc[jt] = __builtin_amdgcn_mfma_f32_16x16x32_bf16(zl, wh, oacc[jt], 0, 0, 0);
        }
    }

    #pragma unroll
    for (int jt = 0; jt < 4; ++jt) {
        float bv = b2[jt * 16 + l15];
        #pragma unroll
        for (int r = 0; r < 4; ++r) oacc[jt][r] += bv;
    }
    #pragma unroll
    for (int r = 0; r < 4; ++r) {
        float m = fmaxf(fmaxf(oacc[0][r], oacc[1][r]), fmaxf(oacc[2][r], oacc[3][r]));
        #pragma unroll
        for (int mask = 8; mask; mask >>= 1) m = fmaxf(m, __shfl_xor(m, mask, 64));
        float p0 = __expf(oacc[0][r] - m);
        float p1 = __expf(oacc[1][r] - m);
        float p2 = __expf(oacc[2][r] - m);
        float p3 = __expf(oacc[3][r] - m);
        float s = p0 + p1 + p2 + p3;
        #pragma unroll
        for (int mask = 8; mask; mask >>= 1) s += __shfl_xor(s, mask, 64);
        float inv = 1.0f / s;
        int grow = row0 + wave * 16 + quad * 4 + r;
        if (grow < N) {
            float* o = out + (size_t)grow * CC + l15;
            o[0]  = p0 * inv;
            o[16] = p1 * inv;
            o[32] = p2 * inv;
            o[48] = p3 * inv;
        }
    }
}

// ---------------------------------------------------------------------------
// Aggregation (symmetric-normalized, self-loop) + bias + LayerNorm + ReLU.
// Persistent grid-stride waves; hW gathered as bf16. Edge loop batch-8
// (8 outstanding gathers/lane). Output: single bf16 into xcH feature slice.
// ---------------------------------------------------------------------------
__global__ __launch_bounds__(256, 8) void k_agg_ln(
    const u16* __restrict__ hWb,
    const int* __restrict__ rowptr, const int2* __restrict__ ecol,
    const float* __restrict__ dinv,
    const float* __restrict__ bg, const float* __restrict__ g,
    const float* __restrict__ b,
    u16* __restrict__ outHi, int N)
{
    const int lane = threadIdx.x & 63;
    const int f0 = lane * 2;

    const float bgx = bg[f0], bgy = bg[f0 + 1];
    const float gx  = g[f0],  gy  = g[f0 + 1];
    const float bx  = b[f0],  by  = b[f0 + 1];

    const int nwaves = gridDim.x * 4;
    for (int wid = blockIdx.x * 4 + (threadIdx.x >> 6); wid < N; wid += nwaves) {
        float di = dinv[wid];
        float sc = di * di;

        u32 hv = *(const u32*)(hWb + (size_t)wid * HH + f0);
        float ax  = bf2f((u16)hv) * sc;
        float ay  = bf2f((u16)(hv >> 16)) * sc;
        float ax1 = 0.f, ay1 = 0.f, ax2 = 0.f, ay2 = 0.f, ax3 = 0.f, ay3 = 0.f;

        int e0 = rowptr[wid];
        int e1 = rowptr[wid + 1];
        int e = e0;
        for (; e + 8 <= e1; e += 8) {
            int2 p[8];
            u32  v[8];
            #pragma unroll
            for (int t = 0; t < 8; ++t) p[t] = ecol[e + t];
            #pragma unroll
            for (int t = 0; t < 8; ++t)
                v[t] = *(const u32*)(hWb + (size_t)p[t].x * HH + f0);
            #pragma unroll
            for (int t = 0; t < 8; ++t) {
                float c = __int_as_float(p[t].y);
                float vx = bf2f((u16)v[t]) * c;
                float vy = bf2f((u16)(v[t] >> 16)) * c;
                switch (t & 3) {
                    case 0: ax  += vx; ay  += vy; break;
                    case 1: ax1 += vx; ay1 += vy; break;
                    case 2: ax2 += vx; ay2 += vy; break;
                    default: ax3 += vx; ay3 += vy; break;
                }
            }
        }
        for (; e + 4 <= e1; e += 4) {
            int2 p0 = ecol[e];
            int2 p1 = ecol[e + 1];
            int2 p2 = ecol[e + 2];
            int2 p3 = ecol[e + 3];
            u32 v0 = *(const u32*)(hWb + (size_t)p0.x * HH + f0);
            u32 v1 = *(const u32*)(hWb + (size_t)p1.x * HH + f0);
            u32 v2 = *(const u32*)(hWb + (size_t)p2.x * HH + f0);
            u32 v3 = *(const u32*)(hWb + (size_t)p3.x * HH + f0);
            ax  += bf2f((u16)v0) * __int_as_float(p0.y);  ay  += bf2f((u16)(v0 >> 16)) * __int_as_float(p0.y);
            ax1 += bf2f((u16)v1) * __int_as_float(p1.y);  ay1 += bf2f((u16)(v1 >> 16)) * __int_as_float(p1.y);
            ax2 += bf2f((u16)v2) * __int_as_float(p2.y);  ay2 += bf2f((u16)(v2 >> 16)) * __int_as_float(p2.y);
            ax3 += bf2f((u16)v3) * __int_as_float(p3.y);  ay3 += bf2f((u16)(v3 >> 16)) * __int_as_float(p3.y);
        }
        for (; e < e1; ++e) {
            int2 p = ecol[e];
            u32 v = *(const u32*)(hWb + (size_t)p.x * HH + f0);
            float c = __int_as_float(p.y);
            ax += bf2f((u16)v) * c;
            ay += bf2f((u16)(v >> 16)) * c;
        }
        ax += ax1 + ax2 + ax3;
        ay += ay1 + ay2 + ay3;
        ax += bgx;
        ay += bgy;

        float ssum = ax + ay;
        #pragma unroll
        for (int off = 32; off; off >>= 1) ssum += __shfl_xor(ssum, off, 64);
        float mu = ssum * (1.0f / 128.0f);
        float dx = ax - mu, dy = ay - mu;
        float vsum = dx * dx + dy * dy;
        #pragma unroll
        for (int off = 32; off; off >>= 1) vsum += __shfl_xor(vsum, off, 64);
        float rstd = rsqrtf(vsum * (1.0f / 128.0f) + LN_EPS);

        float ox = fmaxf(gx * dx * rstd + bx, 0.f);
        float oy = fmaxf(gy * dy * rstd + by, 0.f);

        *(u32*)&outHi[(size_t)wid * 512 + f0] = (u32)f2bf(ox) | ((u32)f2bf(oy) << 16);
    }
}

// ---------------------------------------------------------------------------
// Host launcher
// ---------------------------------------------------------------------------
extern "C" void kernel_launch(void* const* d_in, const int* in_sizes, int n_in,
                              void* d_out, int out_size, void* d_ws, size_t ws_size,
                              hipStream_t stream) {
    const float* x   = (const float*)d_in[0];
    const int*   ei  = (const int*)  d_in[1];
    const float* Wg  = (const float*)d_in[2];
    const float* bg  = (const float*)d_in[3];
    const float* lng = (const float*)d_in[4];
    const float* lnb = (const float*)d_in[5];
    const float* W1  = (const float*)d_in[6];
    const float* b1  = (const float*)d_in[7];
    const float* W2  = (const float*)d_in[8];
    const float* b2  = (const float*)d_in[9];
    float* out = (float*)d_out;

    const int N = in_sizes[0] / D;
    const int E = in_sizes[1] / 2;
    const int* srcp = ei;
    const int* dstp = ei + E;

    char* ws = (char*)d_ws;
    size_t off = 0;
    auto alloc = [&](size_t bytes) -> void* {
        void* p = ws + off;
        off += (bytes + 511) & ~(size_t)511;
        return p;
    };
    int*   cnt    = (int*)  alloc((size_t)N * 4);
    int*   rowptr = (int*)  alloc((size_t)(N + 1) * 4);
    int*   cursor = (int*)  alloc((size_t)N * 4);
    int*   bsum   = (int*)  alloc(64 * 4);
    int2*  ecol   = (int2*) alloc((size_t)E * 8);
    float* dinv   = (float*)alloc((size_t)N * 4);
    u16*   hWb    = (u16*)  alloc((size_t)N * HH * 2);       // layer GEMM bf16 out
    u16*   xcH    = (u16*)  alloc((size_t)N * 512 * 2);      // [x_hi|f1|f2|f3]
    u16*   xl     = (u16*)  alloc((size_t)N * 128 * 2);      // x lo plane
    u16*   WgtH   = (u16*)  alloc((size_t)NLAYERS * D * HH * 2);
    u16*   W1tH   = (u16*)  alloc((size_t)(D + NLAYERS * HH) * HH * 2);
    u16*   W2tH   = (u16*)  alloc((size_t)HH * CC * 2);
    u16*   W2tL   = (u16*)  alloc((size_t)HH * CC * 2);

    const int B = 256;
    const int gN = (N + B - 1) / B;
    const int gE = (E + B - 1) / B;
    const int nsb = (N + 1023) / 1024;

    k_zero_cnt<<<gN, B, 0, stream>>>(cnt, N);
    k_count<<<gE, B, 0, stream>>>(dstp, cnt, E);
    k_scan_a<<<nsb, 1024, 0, stream>>>(cnt, rowptr, bsum, N);
    k_scan_b<<<1, 64, 0, stream>>>(bsum, nsb);
    k_scan_c<<<gN, B, 0, stream>>>(rowptr, bsum, cnt, dinv, cursor, N, E);
    k_scatter<<<gE, B, 0, stream>>>(srcp, dstp, dinv, cursor, ecol, E);

    // Split conversions
    k_split_x<<<(N * D + B - 1) / B, B, 0, stream>>>(x, xcH, xl, N * D);
    for (int l = 0; l < NLAYERS; ++l)
        k_tile_w<<<(D * HH + B - 1) / B, B, 0, stream>>>(Wg + (size_t)l * D * HH,
                                                         WgtH + (size_t)l * D * HH,
                                                         nullptr, D * HH, 7);
    k_tile_w<<<((D + NLAYERS * HH) * HH + B - 1) / B, B, 0, stream>>>(W1, W1tH, nullptr,
                                                                      (D + NLAYERS * HH) * HH, 7);
    k_tile_w<<<(HH * CC + B - 1) / B, B, 0, stream>>>(W2, W2tH, W2tL, HH * CC, 6);

    const int gemmBlocks = (N + 63) / 64;
    const int aggBlocks  = 2048;   // persistent: 8192 waves, ~6 nodes/wave

    for (int l = 0; l < NLAYERS; ++l) {
        // hWb = bf16(h @ Wg[l])  (bias added after aggregation)
        if (l == 0)
            k_gemm_lf<true><<<gemmBlocks, B, 0, stream>>>(xcH, 512, 0, xl, 128,
                                                          WgtH, hWb, N);
        else
            k_gemm_lf<false><<<gemmBlocks, B, 0, stream>>>(xcH, 512, l * HH, nullptr, 0,
                                                           WgtH + (size_t)l * D * HH, hWb, N);
        k_agg_ln<<<aggBlocks, B, 0, stream>>>(hWb, rowptr, ecol, dinv,
                                              bg + (size_t)l * HH,
                                              lng + (size_t)l * HH,
                                              lnb + (size_t)l * HH,
                                              xcH + (size_t)(l + 1) * HH, N);
    }

    // out = softmax(relu([x|f1|f2|f3] @ W1 + b1) @ W2 + b2), fused
    k_mlp_fused<<<gemmBlocks, B, 0, stream>>>(xcH, xl, W1tH, b1,
                                              W2tH, W2tL, b2, out, N);
}

// Round 10
// 333.681 us; speedup vs baseline: 1.9463x; 1.0394x over previous
//
#include <hip/hip_runtime.h>
#include <math.h>

// Problem constants (shapes fixed by the reference)
#define D 128
#define HH 128
#define CC 64
#define NLAYERS 3
#define LN_EPS 1e-5f

typedef __attribute__((ext_vector_type(8))) short bf16x8;
typedef __attribute__((ext_vector_type(4))) float f32x4;
typedef unsigned short u16;
typedef unsigned int u32;

// round-to-nearest-even fp32 -> bf16 bits
__device__ __forceinline__ u16 f2bf(float f) {
    u32 u = __float_as_uint(f);
    u32 r = u + 0x7FFFu + ((u >> 16) & 1u);
    return (u16)(r >> 16);
}
__device__ __forceinline__ float bf2f(u16 h) {
    return __uint_as_float(((u32)h) << 16);
}

// ---------------------------------------------------------------------------
// Setup kernels: degree, CSR build (count -> scan -> scatter)
// ---------------------------------------------------------------------------

__global__ void k_zero_cnt(int* __restrict__ cnt, int n) {
    int i = blockIdx.x * blockDim.x + threadIdx.x;
    if (i < n) cnt[i] = 0;
}

__global__ void k_count(const int* __restrict__ dst, int* __restrict__ cnt, int E) {
    int i = blockIdx.x * blockDim.x + threadIdx.x;
    if (i < E) atomicAdd(&cnt[dst[i]], 1);
}

__global__ void k_scan_a(const int* __restrict__ cnt, int* __restrict__ rowptr,
                         int* __restrict__ bsum, int N) {
    __shared__ int s[1024];
    int tid = threadIdx.x;
    int i = blockIdx.x * 1024 + tid;
    int v = (i < N) ? cnt[i] : 0;
    s[tid] = v;
    __syncthreads();
    for (int off = 1; off < 1024; off <<= 1) {
        int t = (tid >= off) ? s[tid - off] : 0;
        __syncthreads();
        s[tid] += t;
        __syncthreads();
    }
    if (i < N) rowptr[i] = s[tid] - v;
    if (tid == 1023) bsum[blockIdx.x] = s[tid];
}

__global__ void k_scan_b(int* __restrict__ bsum, int nb) {
    int t = threadIdx.x;
    int v = (t < nb) ? bsum[t] : 0;
    int incl = v;
    for (int off = 1; off < 64; off <<= 1) {
        int u = __shfl_up(incl, off, 64);
        if (t >= off) incl += u;
    }
    if (t < nb) bsum[t] = incl - v;
}

// scan finalize + dinv (fused)
__global__ void k_scan_c(int* __restrict__ rowptr, const int* __restrict__ bsum,
                         const int* __restrict__ cnt, float* __restrict__ dinv,
                         int* __restrict__ cursor, int N, int E) {
    int i = blockIdx.x * blockDim.x + threadIdx.x;
    if (i < N) {
        int v = rowptr[i] + bsum[i >> 10];
        rowptr[i] = v;
        cursor[i] = v;
        dinv[i] = rsqrtf(1.0f + (float)cnt[i]);
    }
    if (i == 0) rowptr[N] = E;
}

// Scatter edges into CSR; pack src index + precomputed coef (dinv_s * dinv_d)
__global__ void k_scatter(const int* __restrict__ src, const int* __restrict__ dst,
                          const float* __restrict__ dinv,
                          int* __restrict__ cursor, int2* __restrict__ ecol, int E) {
    int i = blockIdx.x * blockDim.x + threadIdx.x;
    if (i < E) {
        int s = src[i], d = dst[i];
        int p = atomicAdd(&cursor[d], 1);
        float c = dinv[s] * dinv[d];
        ecol[p] = make_int2(s, __float_as_int(c));
    }
}

// ---------------------------------------------------------------------------
// Split conversions
// ---------------------------------------------------------------------------

// x -> xcH cols 0:128 (hi, row stride 512) + xl (lo, row stride 128)
__global__ void k_split_x(const float* __restrict__ x, u16* __restrict__ xh,
                          u16* __restrict__ xl, int total) {
    int i = blockIdx.x * blockDim.x + threadIdx.x;
    if (i >= total) return;
    int row = i >> 7, c = i & 127;
    float v = x[i];
    u16 h = f2bf(v);
    u16 l = f2bf(v - bf2f(h));
    xh[(size_t)row * 512 + c] = h;
    xl[(size_t)row * 128 + c] = l;
}

// W[K][Ncols] (row-major, Ncols = 1<<nshift) -> tiled [kc][q][n][j], k = kc*32+q*8+j
// Tiled layout is linear in kc, so stacked weight matrices tile in one launch.
// tl may be nullptr (hi only).
__global__ void k_tile_w(const float* __restrict__ W, u16* __restrict__ th,
                         u16* __restrict__ tl, int KN, int nshift) {
    int idx = blockIdx.x * blockDim.x + threadIdx.x;
    if (idx >= KN) return;
    int k = idx >> nshift, n = idx & ((1 << nshift) - 1);
    int kc = k >> 5, q = (k >> 3) & 3, j = k & 7;
    float v = W[idx];
    u16 h = f2bf(v);
    int o = (((kc * 4 + q) << nshift) + n) * 8 + j;
    th[o] = h;
    if (tl) tl[o] = f2bf(v - bf2f(h));
}

// ---------------------------------------------------------------------------
// Layer GEMM, K=128 fixed (4 chunks): hWb = bf16(A @ W). LDS-free; all
// fragment loads issued up front, then MFMAs. SPLIT2 for layer 0 (x hi+lo).
// Block 64 rows x 128 cols; wave tile 32x64.
// ---------------------------------------------------------------------------
template <bool SPLIT2>
__global__ __launch_bounds__(256) void k_gemm_lf(
    const u16* __restrict__ Ahi, int strideA, int colOff,
    const u16* __restrict__ Alo, int strideAlo,
    const u16* __restrict__ Bt, u16* __restrict__ OUTb, int N)
{
    const int tid  = threadIdx.x;
    const int lane = tid & 63;
    const int wave = tid >> 6;
    const int wr   = wave & 1;
    const int wc   = wave >> 1;
    const int quad = lane >> 4;
    const int l15  = lane & 15;
    const int row0 = blockIdx.x * 64;

    const u16* pAh[2];
    const u16* pAl[2];
    #pragma unroll
    for (int i = 0; i < 2; ++i) {
        int r = row0 + wr * 32 + i * 16 + l15;
        if (r >= N) r = N - 1;
        pAh[i] = Ahi + (size_t)r * strideA + colOff + quad * 8;
        if (SPLIT2) pAl[i] = Alo + (size_t)r * strideAlo + quad * 8;
    }
    const u16* pB = Bt + ((size_t)quad * 128 + wc * 64 + l15) * 8;

    bf16x8 ah[4][2], al[4][2], bh[4][4];
    #pragma unroll
    for (int kc = 0; kc < 4; ++kc) {
        #pragma unroll
        for (int i = 0; i < 2; ++i) {
            ah[kc][i] = *(const bf16x8*)(pAh[i] + kc * 32);
            if (SPLIT2) al[kc][i] = *(const bf16x8*)(pAl[i] + kc * 32);
        }
        #pragma unroll
        for (int j = 0; j < 4; ++j)
            bh[kc][j] = *(const bf16x8*)(pB + (size_t)kc * 4096 + j * 128);
    }

    f32x4 acc[2][4];
    #pragma unroll
    for (int i = 0; i < 2; ++i)
        #pragma unroll
        for (int j = 0; j < 4; ++j)
            #pragma unroll
            for (int r = 0; r < 4; ++r) acc[i][j][r] = 0.f;

    #pragma unroll
    for (int kc = 0; kc < 4; ++kc)
        #pragma unroll
        for (int i = 0; i < 2; ++i)
            #pragma unroll
            for (int j = 0; j < 4; ++j) {
                acc[i][j] = __builtin_amdgcn_mfma_f32_16x16x32_bf16(ah[kc][i], bh[kc][j], acc[i][j], 0, 0, 0);
                if (SPLIT2)
                    acc[i][j] = __builtin_amdgcn_mfma_f32_16x16x32_bf16(al[kc][i], bh[kc][j], acc[i][j], 0, 0, 0);
            }

    #pragma unroll
    for (int i = 0; i < 2; ++i)
        #pragma unroll
        for (int j = 0; j < 4; ++j) {
            int col = wc * 64 + j * 16 + l15;
            #pragma unroll
            for (int r = 0; r < 4; ++r) {
                int grow = row0 + wr * 32 + i * 16 + quad * 4 + r;
                if (grow < N)
                    OUTb[(size_t)grow * 128 + col] = f2bf(acc[i][j][r]);
            }
        }
}

// ---------------------------------------------------------------------------
// Fused MLP v4 (K-split): 32-row blocks (grid ~1563 for TLP), 4 waves.
// Wave w: col half wc = w&1, K-group kg = w>>1. Each wave: 32 rows x 64 cols,
// 10 K-chunks (kg=0: 0-9, kg=1: 10-19), 8 MFMA/chunk, 3-buffer pipeline.
// kg=1 partials summed into kg=0 via padded LDS (stride 132, 2-way = free).
// Then bias+relu+split -> sZ; softmax phase on waves 0-1.
// ---------------------------------------------------------------------------
__global__ __launch_bounds__(256) void k_mlp_fused(
    const u16* __restrict__ xcH, const u16* __restrict__ xl,
    const u16* __restrict__ B1t, const float* __restrict__ b1,
    const u16* __restrict__ W2h, const u16* __restrict__ W2l,
    const float* __restrict__ b2, float* __restrict__ out, int N)
{
    __shared__ float sAcc[32 * 132];   // K-split partial sums (padded stride)
    __shared__ u16 sZh[32 * 128];      // [(qq*32 + r)*8 + j], z1 col = qq*8+j
    __shared__ u16 sZl[32 * 128];

    const int tid  = threadIdx.x;
    const int lane = tid & 63;
    const int wave = tid >> 6;
    const int wc   = wave & 1;   // 64-col half
    const int kg   = wave >> 1;  // K-group
    const int quad = lane >> 4;
    const int l15  = lane & 15;
    const int row0 = blockIdx.x * 32;

    const u16* pAh[2];
    const u16* pAl[2];
    #pragma unroll
    for (int f = 0; f < 2; ++f) {
        int r = row0 + f * 16 + l15;
        if (r >= N) r = N - 1;
        pAh[f] = xcH + (size_t)r * 512 + quad * 8;   // hi chunks 0..15
        pAl[f] = xl  + (size_t)r * 128 + quad * 8;   // x-lo chunks 16..19
    }
    const u16* pB = B1t + ((size_t)quad * 128 + wc * 64 + l15) * 8;

    f32x4 acc[2][4];
    #pragma unroll
    for (int f = 0; f < 2; ++f)
        #pragma unroll
        for (int j = 0; j < 4; ++j)
            #pragma unroll
            for (int r = 0; r < 4; ++r) acc[f][j][r] = 0.f;

    // 3-buffer pipeline over this wave's 10 chunks (global chunk g = kg*10 + t)
    bf16x8 abuf[3][2], bbuf[3][4];
    #define LOADI(t, s)                                                          \
        {                                                                        \
            const int g = kg * 10 + (t);                                         \
            const int hi = (g < 16);                                             \
            const int bk = hi ? g : g - 16;                                      \
            _Pragma("unroll")                                                    \
            for (int f = 0; f < 2; ++f) {                                        \
                const u16* pa = hi ? (pAh[f] + g * 32)                           \
                                   : (pAl[f] + (g - 16) * 32);                   \
                abuf[s][f] = *(const bf16x8*)pa;                                 \
            }                                                                    \
            _Pragma("unroll")                                                    \
            for (int j = 0; j < 4; ++j)                                          \
                bbuf[s][j] = *(const bf16x8*)(pB + (size_t)bk * 4096 + j * 128); \
        }
    LOADI(0, 0)
    LOADI(1, 1)
    #pragma unroll
    for (int t = 0; t < 10; ++t) {
        if (t + 2 < 10) {
            const int s = (t + 2) % 3;
            LOADI(t + 2, s)
        }
        const int u = t % 3;
        #pragma unroll
        for (int f = 0; f < 2; ++f)
            #pragma unroll
            for (int j = 0; j < 4; ++j)
                acc[f][j] = __builtin_amdgcn_mfma_f32_16x16x32_bf16(abuf[u][f], bbuf[u][j], acc[f][j], 0, 0, 0);
    }
    #undef LOADI

    // K-split reduction: kg=1 stores partials; kg=0 adds.
    if (kg == 1) {
        #pragma unroll
        for (int f = 0; f < 2; ++f)
            #pragma unroll
            for (int jt = 0; jt < 4; ++jt) {
                int col = wc * 64 + jt * 16 + l15;
                #pragma unroll
                for (int r = 0; r < 4; ++r) {
                    int row = f * 16 + quad * 4 + r;
                    sAcc[row * 132 + col] = acc[f][jt][r];
                }
            }
    }
    __syncthreads();
    if (kg == 0) {
        #pragma unroll
        for (int jt = 0; jt < 4; ++jt) {
            int col = wc * 64 + jt * 16 + l15;
            float bv = b1[col];
            int qq = col >> 3, jj = col & 7;
            #pragma unroll
            for (int f = 0; f < 2; ++f) {
                #pragma unroll
                for (int rr = 0; rr < 4; ++rr) {
                    int row = f * 16 + quad * 4 + rr;
                    float v = fmaxf(acc[f][jt][rr] + sAcc[row * 132 + col] + bv, 0.f);
                    u16 h = f2bf(v);
                    sZh[(qq * 32 + row) * 8 + jj] = h;
                    sZl[(qq * 32 + row) * 8 + jj] = f2bf(v - bf2f(h));
                }
            }
        }
    }
    __syncthreads();

    // phase 2: MLP2 (128->64) + softmax on waves 0,1 (16 rows each)
    if (kg == 0) {
        f32x4 oacc[4];
        #pragma unroll
        for (int j = 0; j < 4; ++j)
            #pragma unroll
            for (int r = 0; r < 4; ++r) oacc[j][r] = 0.f;

        #pragma unroll
        for (int kc = 0; kc < 4; ++kc) {
            int qq = kc * 4 + quad;
            bf16x8 zh = *(const bf16x8*)&sZh[(qq * 32 + wc * 16 + l15) * 8];
            bf16x8 zl = *(const bf16x8*)&sZl[(qq * 32 + wc * 16 + l15) * 8];
            #pragma unroll
            for (int jt = 0; jt < 4; ++jt) {
                int n = jt * 16 + l15;
                bf16x8 wh = *(const bf16x8*)&W2h[(qq * 64 + n) * 8];
                bf16x8 wl = *(const bf16x8*)&W2l[(qq * 64 + n) * 8];
                oacc[jt] = __builtin_amdgcn_mfma_f32_16x16x32_bf16(zh, wh, oacc[jt], 0, 0, 0);
                oacc[jt] = __builtin_amdgcn_mfma_f32_16x16x32_bf16(zh, wl, oacc[jt], 0, 0, 0);
                oacc[jt] = __builtin_amdgcn_mfma_f32_16x16x32_bf16(zl, wh, oacc[jt], 0, 0, 0);
            }
        }

        #pragma unroll
        for (int jt = 0; jt < 4; ++jt) {
            float bv = b2[jt * 16 + l15];
            #pragma unroll
            for (int r = 0; r < 4; ++r) oacc[jt][r] += bv;
        }
        #pragma unroll
        for (int r = 0; r < 4; ++r) {
            float m = fmaxf(fmaxf(oacc[0][r], oacc[1][r]), fmaxf(oacc[2][r], oacc[3][r]));
            #pragma unroll
            for (int mask = 8; mask; mask >>= 1) m = fmaxf(m, __shfl_xor(m, mask, 64));
            float p0 = __expf(oacc[0][r] - m);
            float p1 = __expf(oacc[1][r] - m);
            float p2 = __expf(oacc[2][r] - m);
            float p3 = __expf(oacc[3][r] - m);
            float s = p0 + p1 + p2 + p3;
            #pragma unroll
            for (int mask = 8; mask; mask >>= 1) s += __shfl_xor(s, mask, 64);
            float inv = 1.0f / s;
            int grow = row0 + wc * 16 + quad * 4 + r;
            if (grow < N) {
                float* o = out + (size_t)grow * CC + l15;
                o[0]  = p0 * inv;
                o[16] = p1 * inv;
                o[32] = p2 * inv;
                o[48] = p3 * inv;
            }
        }
    }
}

// ---------------------------------------------------------------------------
// Aggregation (symmetric-normalized, self-loop) + bias + LayerNorm + ReLU.
// Persistent grid-stride waves; hW gathered as bf16. Edge loop batch-8
// (8 outstanding gathers/lane). Output: single bf16 into xcH feature slice.
// ---------------------------------------------------------------------------
__global__ __launch_bounds__(256, 8) void k_agg_ln(
    const u16* __restrict__ hWb,
    const int* __restrict__ rowptr, const int2* __restrict__ ecol,
    const float* __restrict__ dinv,
    const float* __restrict__ bg, const float* __restrict__ g,
    const float* __restrict__ b,
    u16* __restrict__ outHi, int N)
{
    const int lane = threadIdx.x & 63;
    const int f0 = lane * 2;

    const float bgx = bg[f0], bgy = bg[f0 + 1];
    const float gx  = g[f0],  gy  = g[f0 + 1];
    const float bx  = b[f0],  by  = b[f0 + 1];

    const int nwaves = gridDim.x * 4;
    for (int wid = blockIdx.x * 4 + (threadIdx.x >> 6); wid < N; wid += nwaves) {
        float di = dinv[wid];
        float sc = di * di;

        u32 hv = *(const u32*)(hWb + (size_t)wid * HH + f0);
        float ax  = bf2f((u16)hv) * sc;
        float ay  = bf2f((u16)(hv >> 16)) * sc;
        float ax1 = 0.f, ay1 = 0.f, ax2 = 0.f, ay2 = 0.f, ax3 = 0.f, ay3 = 0.f;

        int e0 = rowptr[wid];
        int e1 = rowptr[wid + 1];
        int e = e0;
        for (; e + 8 <= e1; e += 8) {
            int2 p[8];
            u32  v[8];
            #pragma unroll
            for (int t = 0; t < 8; ++t) p[t] = ecol[e + t];
            #pragma unroll
            for (int t = 0; t < 8; ++t)
                v[t] = *(const u32*)(hWb + (size_t)p[t].x * HH + f0);
            #pragma unroll
            for (int t = 0; t < 8; ++t) {
                float c = __int_as_float(p[t].y);
                float vx = bf2f((u16)v[t]) * c;
                float vy = bf2f((u16)(v[t] >> 16)) * c;
                switch (t & 3) {
                    case 0: ax  += vx; ay  += vy; break;
                    case 1: ax1 += vx; ay1 += vy; break;
                    case 2: ax2 += vx; ay2 += vy; break;
                    default: ax3 += vx; ay3 += vy; break;
                }
            }
        }
        for (; e + 4 <= e1; e += 4) {
            int2 p0 = ecol[e];
            int2 p1 = ecol[e + 1];
            int2 p2 = ecol[e + 2];
            int2 p3 = ecol[e + 3];
            u32 v0 = *(const u32*)(hWb + (size_t)p0.x * HH + f0);
            u32 v1 = *(const u32*)(hWb + (size_t)p1.x * HH + f0);
            u32 v2 = *(const u32*)(hWb + (size_t)p2.x * HH + f0);
            u32 v3 = *(const u32*)(hWb + (size_t)p3.x * HH + f0);
            ax  += bf2f((u16)v0) * __int_as_float(p0.y);  ay  += bf2f((u16)(v0 >> 16)) * __int_as_float(p0.y);
            ax1 += bf2f((u16)v1) * __int_as_float(p1.y);  ay1 += bf2f((u16)(v1 >> 16)) * __int_as_float(p1.y);
            ax2 += bf2f((u16)v2) * __int_as_float(p2.y);  ay2 += bf2f((u16)(v2 >> 16)) * __int_as_float(p2.y);
            ax3 += bf2f((u16)v3) * __int_as_float(p3.y);  ay3 += bf2f((u16)(v3 >> 16)) * __int_as_float(p3.y);
        }
        for (; e < e1; ++e) {
            int2 p = ecol[e];
            u32 v = *(const u32*)(hWb + (size_t)p.x * HH + f0);
            float c = __int_as_float(p.y);
            ax += bf2f((u16)v) * c;
            ay += bf2f((u16)(v >> 16)) * c;
        }
        ax += ax1 + ax2 + ax3;
        ay += ay1 + ay2 + ay3;
        ax += bgx;
        ay += bgy;

        float ssum = ax + ay;
        #pragma unroll
        for (int off = 32; off; off >>= 1) ssum += __shfl_xor(ssum, off, 64);
        float mu = ssum * (1.0f / 128.0f);
        float dx = ax - mu, dy = ay - mu;
        float vsum = dx * dx + dy * dy;
        #pragma unroll
        for (int off = 32; off; off >>= 1) vsum += __shfl_xor(vsum, off, 64);
        float rstd = rsqrtf(vsum * (1.0f / 128.0f) + LN_EPS);

        float ox = fmaxf(gx * dx * rstd + bx, 0.f);
        float oy = fmaxf(gy * dy * rstd + by, 0.f);

        *(u32*)&outHi[(size_t)wid * 512 + f0] = (u32)f2bf(ox) | ((u32)f2bf(oy) << 16);
    }
}

// ---------------------------------------------------------------------------
// Host launcher
// ---------------------------------------------------------------------------
extern "C" void kernel_launch(void* const* d_in, const int* in_sizes, int n_in,
                              void* d_out, int out_size, void* d_ws, size_t ws_size,
                              hipStream_t stream) {
    const float* x   = (const float*)d_in[0];
    const int*   ei  = (const int*)  d_in[1];
    const float* Wg  = (const float*)d_in[2];
    const float* bg  = (const float*)d_in[3];
    const float* lng = (const float*)d_in[4];
    const float* lnb = (const float*)d_in[5];
    const float* W1  = (const float*)d_in[6];
    const float* b1  = (const float*)d_in[7];
    const float* W2  = (const float*)d_in[8];
    const float* b2  = (const float*)d_in[9];
    float* out = (float*)d_out;

    const int N = in_sizes[0] / D;
    const int E = in_sizes[1] / 2;
    const int* srcp = ei;
    const int* dstp = ei + E;

    char* ws = (char*)d_ws;
    size_t off = 0;
    auto alloc = [&](size_t bytes) -> void* {
        void* p = ws + off;
        off += (bytes + 511) & ~(size_t)511;
        return p;
    };
    int*   cnt    = (int*)  alloc((size_t)N * 4);
    int*   rowptr = (int*)  alloc((size_t)(N + 1) * 4);
    int*   cursor = (int*)  alloc((size_t)N * 4);
    int*   bsum   = (int*)  alloc(64 * 4);
    int2*  ecol   = (int2*) alloc((size_t)E * 8);
    float* dinv   = (float*)alloc((size_t)N * 4);
    u16*   hWb    = (u16*)  alloc((size_t)N * HH * 2);       // layer GEMM bf16 out
    u16*   xcH    = (u16*)  alloc((size_t)N * 512 * 2);      // [x_hi|f1|f2|f3]
    u16*   xl     = (u16*)  alloc((size_t)N * 128 * 2);      // x lo plane
    u16*   WgtH   = (u16*)  alloc((size_t)NLAYERS * D * HH * 2);
    u16*   W1tH   = (u16*)  alloc((size_t)(D + NLAYERS * HH) * HH * 2);
    u16*   W2tH   = (u16*)  alloc((size_t)HH * CC * 2);
    u16*   W2tL   = (u16*)  alloc((size_t)HH * CC * 2);

    const int B = 256;
    const int gN = (N + B - 1) / B;
    const int gE = (E + B - 1) / B;
    const int nsb = (N + 1023) / 1024;

    k_zero_cnt<<<gN, B, 0, stream>>>(cnt, N);
    k_count<<<gE, B, 0, stream>>>(dstp, cnt, E);
    k_scan_a<<<nsb, 1024, 0, stream>>>(cnt, rowptr, bsum, N);
    k_scan_b<<<1, 64, 0, stream>>>(bsum, nsb);
    k_scan_c<<<gN, B, 0, stream>>>(rowptr, bsum, cnt, dinv, cursor, N, E);
    k_scatter<<<gE, B, 0, stream>>>(srcp, dstp, dinv, cursor, ecol, E);

    // Split conversions (Wg's 3 layers tile in ONE launch: layout linear in kc)
    k_split_x<<<(N * D + B - 1) / B, B, 0, stream>>>(x, xcH, xl, N * D);
    k_tile_w<<<(NLAYERS * D * HH + B - 1) / B, B, 0, stream>>>(Wg, WgtH, nullptr,
                                                               NLAYERS * D * HH, 7);
    k_tile_w<<<((D + NLAYERS * HH) * HH + B - 1) / B, B, 0, stream>>>(W1, W1tH, nullptr,
                                                                      (D + NLAYERS * HH) * HH, 7);
    k_tile_w<<<(HH * CC + B - 1) / B, B, 0, stream>>>(W2, W2tH, W2tL, HH * CC, 6);

    const int gemmBlocks = (N + 63) / 64;
    const int mlpBlocks  = (N + 31) / 32;
    const int aggBlocks  = 2048;   // persistent: 8192 waves, ~6 nodes/wave

    for (int l = 0; l < NLAYERS; ++l) {
        // hWb = bf16(h @ Wg[l])  (bias added after aggregation)
        if (l == 0)
            k_gemm_lf<true><<<gemmBlocks, B, 0, stream>>>(xcH, 512, 0, xl, 128,
                                                          WgtH, hWb, N);
        else
            k_gemm_lf<false><<<gemmBlocks, B, 0, stream>>>(xcH, 512, l * HH, nullptr, 0,
                                                           WgtH + (size_t)l * D * HH, hWb, N);
        k_agg_ln<<<aggBlocks, B, 0, stream>>>(hWb, rowptr, ecol, dinv,
                                              bg + (size_t)l * HH,
                                              lng + (size_t)l * HH,
                                              lnb + (size_t)l * HH,
                                              xcH + (size_t)(l + 1) * HH, N);
    }

    // out = softmax(relu([x|f1|f2|f3] @ W1 + b1) @ W2 + b2), fused, K-split
    k_mlp_fused<<<mlpBlocks, B, 0, stream>>>(xcH, xl, W1tH, b1,
                                             W2tH, W2tL, b2, out, N);
}

// Round 11
// 316.245 us; speedup vs baseline: 2.0536x; 1.0551x over previous
//
#include <hip/hip_runtime.h>
#include <math.h>

// Problem constants (shapes fixed by the reference)
#define D 128
#define HH 128
#define CC 64
#define NLAYERS 3
#define LN_EPS 1e-5f

typedef __attribute__((ext_vector_type(8))) short bf16x8;
typedef __attribute__((ext_vector_type(4))) float f32x4;
typedef unsigned short u16;
typedef unsigned int u32;

// round-to-nearest-even fp32 -> bf16 bits
__device__ __forceinline__ u16 f2bf(float f) {
    u32 u = __float_as_uint(f);
    u32 r = u + 0x7FFFu + ((u >> 16) & 1u);
    return (u16)(r >> 16);
}
__device__ __forceinline__ float bf2f(u16 h) {
    return __uint_as_float(((u32)h) << 16);
}

// ---------------------------------------------------------------------------
// k_prep: fused setup — zero cnt + x->bf16 (into xcH cols 0:128) +
// tile Wg (3 layers, one segment) + tile W1 + tile W2 (hi/lo).
// Tiled layout: [kc][q][n][j], k = kc*32 + q*8 + j.
// ---------------------------------------------------------------------------
__global__ void k_prep(const float* __restrict__ x, u16* __restrict__ xh,
                       const float* __restrict__ Wg, u16* __restrict__ WgtH,
                       const float* __restrict__ W1, u16* __restrict__ W1tH,
                       const float* __restrict__ W2, u16* __restrict__ W2tH,
                       u16* __restrict__ W2tL,
                       int* __restrict__ cnt, int N)
{
    int i = blockIdx.x * blockDim.x + threadIdx.x;
    // seg 0: zero cnt
    if (i < N) { cnt[i] = 0; return; }
    i -= N;
    // seg 1: x -> bf16 hi
    int nx = N * D;
    if (i < nx) {
        int row = i >> 7, c = i & 127;
        xh[(size_t)row * 512 + c] = f2bf(x[i]);
        return;
    }
    i -= nx;
    // seg 2: Wg (3 stacked 128x128 matrices; layout linear in kc)
    if (i < NLAYERS * D * HH) {
        int k = i >> 7, n = i & 127;
        int kc = k >> 5, q = (k >> 3) & 3, j = k & 7;
        WgtH[(((kc * 4 + q) << 7) + n) * 8 + j] = f2bf(Wg[i]);
        return;
    }
    i -= NLAYERS * D * HH;
    // seg 3: W1 (512x128)
    if (i < (D + NLAYERS * HH) * HH) {
        int k = i >> 7, n = i & 127;
        int kc = k >> 5, q = (k >> 3) & 3, j = k & 7;
        W1tH[(((kc * 4 + q) << 7) + n) * 8 + j] = f2bf(W1[i]);
        return;
    }
    i -= (D + NLAYERS * HH) * HH;
    // seg 4: W2 (128x64), hi + lo (split-3 in mlp phase 2)
    if (i < HH * CC) {
        int k = i >> 6, n = i & 63;
        int kc = k >> 5, q = (k >> 3) & 3, j = k & 7;
        float v = W2[i];
        u16 h = f2bf(v);
        int o = (((kc * 4 + q) << 6) + n) * 8 + j;
        W2tH[o] = h;
        W2tL[o] = f2bf(v - bf2f(h));
    }
}

// ---------------------------------------------------------------------------
// CSR build: count -> scan_a -> scan_c (block-sum scan inlined) -> scatter
// ---------------------------------------------------------------------------

__global__ void k_count(const int* __restrict__ dst, int* __restrict__ cnt, int E) {
    int i = blockIdx.x * blockDim.x + threadIdx.x;
    if (i < E) atomicAdd(&cnt[dst[i]], 1);
}

__global__ void k_scan_a(const int* __restrict__ cnt, int* __restrict__ rowptr,
                         int* __restrict__ bsum, int N) {
    __shared__ int s[1024];
    int tid = threadIdx.x;
    int i = blockIdx.x * 1024 + tid;
    int v = (i < N) ? cnt[i] : 0;
    s[tid] = v;
    __syncthreads();
    for (int off = 1; off < 1024; off <<= 1) {
        int t = (tid >= off) ? s[tid - off] : 0;
        __syncthreads();
        s[tid] += t;
        __syncthreads();
    }
    if (i < N) rowptr[i] = s[tid] - v;
    if (tid == 1023) bsum[blockIdx.x] = s[tid];
}

// finalize: each block re-scans the <=64 block sums (first wave), then applies;
// also computes dinv. Replaces the old separate scan_b launch.
__global__ void k_scan_c(int* __restrict__ rowptr, const int* __restrict__ bsum,
                         const int* __restrict__ cnt, float* __restrict__ dinv,
                         int* __restrict__ cursor, int N, int E, int nsb) {
    __shared__ int sb[64];
    if (threadIdx.x < 64) {
        int t = threadIdx.x;
        int v = (t < nsb) ? bsum[t] : 0;
        int incl = v;
        #pragma unroll
        for (int off = 1; off < 64; off <<= 1) {
            int u = __shfl_up(incl, off, 64);
            if (t >= off) incl += u;
        }
        sb[t] = incl - v;   // exclusive
    }
    __syncthreads();
    int i = blockIdx.x * blockDim.x + threadIdx.x;
    if (i < N) {
        int v = rowptr[i] + sb[i >> 10];
        rowptr[i] = v;
        cursor[i] = v;
        dinv[i] = rsqrtf(1.0f + (float)cnt[i]);
    }
    if (i == 0) rowptr[N] = E;
}

// Scatter edges into CSR; pack src index + precomputed coef (dinv_s * dinv_d)
__global__ void k_scatter(const int* __restrict__ src, const int* __restrict__ dst,
                          const float* __restrict__ dinv,
                          int* __restrict__ cursor, int2* __restrict__ ecol, int E) {
    int i = blockIdx.x * blockDim.x + threadIdx.x;
    if (i < E) {
        int s = src[i], d = dst[i];
        int p = atomicAdd(&cursor[d], 1);
        float c = dinv[s] * dinv[d];
        ecol[p] = make_int2(s, __float_as_int(c));
    }
}

// ---------------------------------------------------------------------------
// Layer GEMM, K=128 (4 chunks): hWb = bf16(A @ W). LDS-free; all fragment
// loads issued up front, then MFMAs. A = bf16 slice of xcH (hi only).
// Block 64 rows x 128 cols; wave tile 32x64.
// ---------------------------------------------------------------------------
__global__ __launch_bounds__(256) void k_gemm_lf(
    const u16* __restrict__ A, int colOff,
    const u16* __restrict__ Bt, u16* __restrict__ OUTb, int N)
{
    const int tid  = threadIdx.x;
    const int lane = tid & 63;
    const int wave = tid >> 6;
    const int wr   = wave & 1;
    const int wc   = wave >> 1;
    const int quad = lane >> 4;
    const int l15  = lane & 15;
    const int row0 = blockIdx.x * 64;

    const u16* pA[2];
    #pragma unroll
    for (int i = 0; i < 2; ++i) {
        int r = row0 + wr * 32 + i * 16 + l15;
        if (r >= N) r = N - 1;
        pA[i] = A + (size_t)r * 512 + colOff + quad * 8;
    }
    const u16* pB = Bt + ((size_t)quad * 128 + wc * 64 + l15) * 8;

    bf16x8 ah[4][2], bh[4][4];
    #pragma unroll
    for (int kc = 0; kc < 4; ++kc) {
        #pragma unroll
        for (int i = 0; i < 2; ++i)
            ah[kc][i] = *(const bf16x8*)(pA[i] + kc * 32);
        #pragma unroll
        for (int j = 0; j < 4; ++j)
            bh[kc][j] = *(const bf16x8*)(pB + (size_t)kc * 4096 + j * 128);
    }

    f32x4 acc[2][4];
    #pragma unroll
    for (int i = 0; i < 2; ++i)
        #pragma unroll
        for (int j = 0; j < 4; ++j)
            #pragma unroll
            for (int r = 0; r < 4; ++r) acc[i][j][r] = 0.f;

    #pragma unroll
    for (int kc = 0; kc < 4; ++kc)
        #pragma unroll
        for (int i = 0; i < 2; ++i)
            #pragma unroll
            for (int j = 0; j < 4; ++j)
                acc[i][j] = __builtin_amdgcn_mfma_f32_16x16x32_bf16(ah[kc][i], bh[kc][j], acc[i][j], 0, 0, 0);

    #pragma unroll
    for (int i = 0; i < 2; ++i)
        #pragma unroll
        for (int j = 0; j < 4; ++j) {
            int col = wc * 64 + j * 16 + l15;
            #pragma unroll
            for (int r = 0; r < 4; ++r) {
                int grow = row0 + wr * 32 + i * 16 + quad * 4 + r;
                if (grow < N)
                    OUTb[(size_t)grow * 128 + col] = f2bf(acc[i][j][r]);
            }
        }
}

// ---------------------------------------------------------------------------
// Fused MLP (K-split): 32-row blocks (grid ~1563 for TLP), 4 waves.
// Wave w: col half wc = w&1, K-group kg = w>>1. Each wave: 32 rows x 64 cols,
// 8 K-chunks (kg=0: 0-7, kg=1: 8-15), 8 MFMA/chunk, 3-buffer pipeline.
// kg=1 partials summed into kg=0 via padded LDS (stride 132, 2-way = free).
// Then bias+relu+split -> sZ; softmax phase on waves 0-1.
// ---------------------------------------------------------------------------
__global__ __launch_bounds__(256) void k_mlp_fused(
    const u16* __restrict__ xcH,
    const u16* __restrict__ B1t, const float* __restrict__ b1,
    const u16* __restrict__ W2h, const u16* __restrict__ W2l,
    const float* __restrict__ b2, float* __restrict__ out, int N)
{
    __shared__ float sAcc[32 * 132];   // K-split partial sums (padded stride)
    __shared__ u16 sZh[32 * 128];      // [(qq*32 + r)*8 + j], z1 col = qq*8+j
    __shared__ u16 sZl[32 * 128];

    const int tid  = threadIdx.x;
    const int lane = tid & 63;
    const int wave = tid >> 6;
    const int wc   = wave & 1;   // 64-col half
    const int kg   = wave >> 1;  // K-group
    const int quad = lane >> 4;
    const int l15  = lane & 15;
    const int row0 = blockIdx.x * 32;

    const u16* pA[2];
    #pragma unroll
    for (int f = 0; f < 2; ++f) {
        int r = row0 + f * 16 + l15;
        if (r >= N) r = N - 1;
        pA[f] = xcH + (size_t)r * 512 + quad * 8;
    }
    const u16* pB = B1t + ((size_t)quad * 128 + wc * 64 + l15) * 8;

    f32x4 acc[2][4];
    #pragma unroll
    for (int f = 0; f < 2; ++f)
        #pragma unroll
        for (int j = 0; j < 4; ++j)
            #pragma unroll
            for (int r = 0; r < 4; ++r) acc[f][j][r] = 0.f;

    // 3-buffer pipeline over this wave's 8 chunks (global chunk g = kg*8 + t)
    bf16x8 abuf[3][2], bbuf[3][4];
    #define LOADI(t, s)                                                          \
        {                                                                        \
            const int g = kg * 8 + (t);                                          \
            _Pragma("unroll")                                                    \
            for (int f = 0; f < 2; ++f)                                          \
                abuf[s][f] = *(const bf16x8*)(pA[f] + g * 32);                   \
            _Pragma("unroll")                                                    \
            for (int j = 0; j < 4; ++j)                                          \
                bbuf[s][j] = *(const bf16x8*)(pB + (size_t)g * 4096 + j * 128);  \
        }
    LOADI(0, 0)
    LOADI(1, 1)
    #pragma unroll
    for (int t = 0; t < 8; ++t) {
        if (t + 2 < 8) {
            const int s = (t + 2) % 3;
            LOADI(t + 2, s)
        }
        const int u = t % 3;
        #pragma unroll
        for (int f = 0; f < 2; ++f)
            #pragma unroll
            for (int j = 0; j < 4; ++j)
                acc[f][j] = __builtin_amdgcn_mfma_f32_16x16x32_bf16(abuf[u][f], bbuf[u][j], acc[f][j], 0, 0, 0);
    }
    #undef LOADI

    // K-split reduction: kg=1 stores partials; kg=0 adds.
    if (kg == 1) {
        #pragma unroll
        for (int f = 0; f < 2; ++f)
            #pragma unroll
            for (int jt = 0; jt < 4; ++jt) {
                int col = wc * 64 + jt * 16 + l15;
                #pragma unroll
                for (int r = 0; r < 4; ++r) {
                    int row = f * 16 + quad * 4 + r;
                    sAcc[row * 132 + col] = acc[f][jt][r];
                }
            }
    }
    __syncthreads();
    if (kg == 0) {
        #pragma unroll
        for (int jt = 0; jt < 4; ++jt) {
            int col = wc * 64 + jt * 16 + l15;
            float bv = b1[col];
            int qq = col >> 3, jj = col & 7;
            #pragma unroll
            for (int f = 0; f < 2; ++f) {
                #pragma unroll
                for (int rr = 0; rr < 4; ++rr) {
                    int row = f * 16 + quad * 4 + rr;
                    float v = fmaxf(acc[f][jt][rr] + sAcc[row * 132 + col] + bv, 0.f);
                    u16 h = f2bf(v);
                    sZh[(qq * 32 + row) * 8 + jj] = h;
                    sZl[(qq * 32 + row) * 8 + jj] = f2bf(v - bf2f(h));
                }
            }
        }
    }
    __syncthreads();

    // phase 2: MLP2 (128->64) + softmax on waves 0,1 (16 rows each)
    if (kg == 0) {
        f32x4 oacc[4];
        #pragma unroll
        for (int j = 0; j < 4; ++j)
            #pragma unroll
            for (int r = 0; r < 4; ++r) oacc[j][r] = 0.f;

        #pragma unroll
        for (int kc = 0; kc < 4; ++kc) {
            int qq = kc * 4 + quad;
            bf16x8 zh = *(const bf16x8*)&sZh[(qq * 32 + wc * 16 + l15) * 8];
            bf16x8 zl = *(const bf16x8*)&sZl[(qq * 32 + wc * 16 + l15) * 8];
            #pragma unroll
            for (int jt = 0; jt < 4; ++jt) {
                int n = jt * 16 + l15;
                bf16x8 wh = *(const bf16x8*)&W2h[(qq * 64 + n) * 8];
                bf16x8 wl = *(const bf16x8*)&W2l[(qq * 64 + n) * 8];
                oacc[jt] = __builtin_amdgcn_mfma_f32_16x16x32_bf16(zh, wh, oacc[jt], 0, 0, 0);
                oacc[jt] = __builtin_amdgcn_mfma_f32_16x16x32_bf16(zh, wl, oacc[jt], 0, 0, 0);
                oacc[jt] = __builtin_amdgcn_mfma_f32_16x16x32_bf16(zl, wh, oacc[jt], 0, 0, 0);
            }
        }

        #pragma unroll
        for (int jt = 0; jt < 4; ++jt) {
            float bv = b2[jt * 16 + l15];
            #pragma unroll
            for (int r = 0; r < 4; ++r) oacc[jt][r] += bv;
        }
        #pragma unroll
        for (int r = 0; r < 4; ++r) {
            float m = fmaxf(fmaxf(oacc[0][r], oacc[1][r]), fmaxf(oacc[2][r], oacc[3][r]));
            #pragma unroll
            for (int mask = 8; mask; mask >>= 1) m = fmaxf(m, __shfl_xor(m, mask, 64));
            float p0 = __expf(oacc[0][r] - m);
            float p1 = __expf(oacc[1][r] - m);
            float p2 = __expf(oacc[2][r] - m);
            float p3 = __expf(oacc[3][r] - m);
            float s = p0 + p1 + p2 + p3;
            #pragma unroll
            for (int mask = 8; mask; mask >>= 1) s += __shfl_xor(s, mask, 64);
            float inv = 1.0f / s;
            int grow = row0 + wc * 16 + quad * 4 + r;
            if (grow < N) {
                float* o = out + (size_t)grow * CC + l15;
                o[0]  = p0 * inv;
                o[16] = p1 * inv;
                o[32] = p2 * inv;
                o[48] = p3 * inv;
            }
        }
    }
}

// ---------------------------------------------------------------------------
// Aggregation (symmetric-normalized, self-loop) + bias + LayerNorm + ReLU.
// Persistent grid-stride waves; hW gathered as bf16. Edge loop batch-8
// (8 outstanding gathers/lane). Output: single bf16 into xcH feature slice.
// ---------------------------------------------------------------------------
__global__ __launch_bounds__(256, 8) void k_agg_ln(
    const u16* __restrict__ hWb,
    const int* __restrict__ rowptr, const int2* __restrict__ ecol,
    const float* __restrict__ dinv,
    const float* __restrict__ bg, const float* __restrict__ g,
    const float* __restrict__ b,
    u16* __restrict__ outHi, int N)
{
    const int lane = threadIdx.x & 63;
    const int f0 = lane * 2;

    const float bgx = bg[f0], bgy = bg[f0 + 1];
    const float gx  = g[f0],  gy  = g[f0 + 1];
    const float bx  = b[f0],  by  = b[f0 + 1];

    const int nwaves = gridDim.x * 4;
    for (int wid = blockIdx.x * 4 + (threadIdx.x >> 6); wid < N; wid += nwaves) {
        float di = dinv[wid];
        float sc = di * di;

        u32 hv = *(const u32*)(hWb + (size_t)wid * HH + f0);
        float ax  = bf2f((u16)hv) * sc;
        float ay  = bf2f((u16)(hv >> 16)) * sc;
        float ax1 = 0.f, ay1 = 0.f, ax2 = 0.f, ay2 = 0.f, ax3 = 0.f, ay3 = 0.f;

        int e0 = rowptr[wid];
        int e1 = rowptr[wid + 1];
        int e = e0;
        for (; e + 8 <= e1; e += 8) {
            int2 p[8];
            u32  v[8];
            #pragma unroll
            for (int t = 0; t < 8; ++t) p[t] = ecol[e + t];
            #pragma unroll
            for (int t = 0; t < 8; ++t)
                v[t] = *(const u32*)(hWb + (size_t)p[t].x * HH + f0);
            #pragma unroll
            for (int t = 0; t < 8; ++t) {
                float c = __int_as_float(p[t].y);
                float vx = bf2f((u16)v[t]) * c;
                float vy = bf2f((u16)(v[t] >> 16)) * c;
                switch (t & 3) {
                    case 0: ax  += vx; ay  += vy; break;
                    case 1: ax1 += vx; ay1 += vy; break;
                    case 2: ax2 += vx; ay2 += vy; break;
                    default: ax3 += vx; ay3 += vy; break;
                }
            }
        }
        for (; e + 4 <= e1; e += 4) {
            int2 p0 = ecol[e];
            int2 p1 = ecol[e + 1];
            int2 p2 = ecol[e + 2];
            int2 p3 = ecol[e + 3];
            u32 v0 = *(const u32*)(hWb + (size_t)p0.x * HH + f0);
            u32 v1 = *(const u32*)(hWb + (size_t)p1.x * HH + f0);
            u32 v2 = *(const u32*)(hWb + (size_t)p2.x * HH + f0);
            u32 v3 = *(const u32*)(hWb + (size_t)p3.x * HH + f0);
            ax  += bf2f((u16)v0) * __int_as_float(p0.y);  ay  += bf2f((u16)(v0 >> 16)) * __int_as_float(p0.y);
            ax1 += bf2f((u16)v1) * __int_as_float(p1.y);  ay1 += bf2f((u16)(v1 >> 16)) * __int_as_float(p1.y);
            ax2 += bf2f((u16)v2) * __int_as_float(p2.y);  ay2 += bf2f((u16)(v2 >> 16)) * __int_as_float(p2.y);
            ax3 += bf2f((u16)v3) * __int_as_float(p3.y);  ay3 += bf2f((u16)(v3 >> 16)) * __int_as_float(p3.y);
        }
        for (; e < e1; ++e) {
            int2 p = ecol[e];
            u32 v = *(const u32*)(hWb + (size_t)p.x * HH + f0);
            float c = __int_as_float(p.y);
            ax += bf2f((u16)v) * c;
            ay += bf2f((u16)(v >> 16)) * c;
        }
        ax += ax1 + ax2 + ax3;
        ay += ay1 + ay2 + ay3;
        ax += bgx;
        ay += bgy;

        float ssum = ax + ay;
        #pragma unroll
        for (int off = 32; off; off >>= 1) ssum += __shfl_xor(ssum, off, 64);
        float mu = ssum * (1.0f / 128.0f);
        float dx = ax - mu, dy = ay - mu;
        float vsum = dx * dx + dy * dy;
        #pragma unroll
        for (int off = 32; off; off >>= 1) vsum += __shfl_xor(vsum, off, 64);
        float rstd = rsqrtf(vsum * (1.0f / 128.0f) + LN_EPS);

        float ox = fmaxf(gx * dx * rstd + bx, 0.f);
        float oy = fmaxf(gy * dy * rstd + by, 0.f);

        *(u32*)&outHi[(size_t)wid * 512 + f0] = (u32)f2bf(ox) | ((u32)f2bf(oy) << 16);
    }
}

// ---------------------------------------------------------------------------
// Host launcher
// ---------------------------------------------------------------------------
extern "C" void kernel_launch(void* const* d_in, const int* in_sizes, int n_in,
                              void* d_out, int out_size, void* d_ws, size_t ws_size,
                              hipStream_t stream) {
    const float* x   = (const float*)d_in[0];
    const int*   ei  = (const int*)  d_in[1];
    const float* Wg  = (const float*)d_in[2];
    const float* bg  = (const float*)d_in[3];
    const float* lng = (const float*)d_in[4];
    const float* lnb = (const float*)d_in[5];
    const float* W1  = (const float*)d_in[6];
    const float* b1  = (const float*)d_in[7];
    const float* W2  = (const float*)d_in[8];
    const float* b2  = (const float*)d_in[9];
    float* out = (float*)d_out;

    const int N = in_sizes[0] / D;
    const int E = in_sizes[1] / 2;
    const int* srcp = ei;
    const int* dstp = ei + E;

    char* ws = (char*)d_ws;
    size_t off = 0;
    auto alloc = [&](size_t bytes) -> void* {
        void* p = ws + off;
        off += (bytes + 511) & ~(size_t)511;
        return p;
    };
    int*   cnt    = (int*)  alloc((size_t)N * 4);
    int*   rowptr = (int*)  alloc((size_t)(N + 1) * 4);
    int*   cursor = (int*)  alloc((size_t)N * 4);
    int*   bsum   = (int*)  alloc(64 * 4);
    int2*  ecol   = (int2*) alloc((size_t)E * 8);
    float* dinv   = (float*)alloc((size_t)N * 4);
    u16*   hWb    = (u16*)  alloc((size_t)N * HH * 2);       // layer GEMM bf16 out
    u16*   xcH    = (u16*)  alloc((size_t)N * 512 * 2);      // [x|f1|f2|f3] bf16
    u16*   WgtH   = (u16*)  alloc((size_t)NLAYERS * D * HH * 2);
    u16*   W1tH   = (u16*)  alloc((size_t)(D + NLAYERS * HH) * HH * 2);
    u16*   W2tH   = (u16*)  alloc((size_t)HH * CC * 2);
    u16*   W2tL   = (u16*)  alloc((size_t)HH * CC * 2);

    const int B = 256;
    const int gE = (E + B - 1) / B;
    const int nsb = (N + 1023) / 1024;

    // fused prep: zero cnt + x->bf16 + all weight tilings (one launch)
    const int prepTotal = N + N * D + NLAYERS * D * HH
                        + (D + NLAYERS * HH) * HH + HH * CC;
    k_prep<<<(prepTotal + B - 1) / B, B, 0, stream>>>(x, xcH, Wg, WgtH, W1, W1tH,
                                                      W2, W2tH, W2tL, cnt, N);
    k_count<<<gE, B, 0, stream>>>(dstp, cnt, E);
    k_scan_a<<<nsb, 1024, 0, stream>>>(cnt, rowptr, bsum, N);
    k_scan_c<<<(N + B - 1) / B, B, 0, stream>>>(rowptr, bsum, cnt, dinv, cursor, N, E, nsb);
    k_scatter<<<gE, B, 0, stream>>>(srcp, dstp, dinv, cursor, ecol, E);

    const int gemmBlocks = (N + 63) / 64;
    const int mlpBlocks  = (N + 31) / 32;
    const int aggBlocks  = 2048;   // persistent: 8192 waves, ~6 nodes/wave

    for (int l = 0; l < NLAYERS; ++l) {
        // hWb = bf16(h @ Wg[l])  (bias added after aggregation)
        k_gemm_lf<<<gemmBlocks, B, 0, stream>>>(xcH, l * HH,
                                                WgtH + (size_t)l * D * HH, hWb, N);
        k_agg_ln<<<aggBlocks, B, 0, stream>>>(hWb, rowptr, ecol, dinv,
                                              bg + (size_t)l * HH,
                                              lng + (size_t)l * HH,
                                              lnb + (size_t)l * HH,
                                              xcH + (size_t)(l + 1) * HH, N);
    }

    // out = softmax(relu([x|f1|f2|f3] @ W1 + b1) @ W2 + b2), fused, K-split
    k_mlp_fused<<<mlpBlocks, B, 0, stream>>>(xcH, W1tH, b1,
                                             W2tH, W2tL, b2, out, N);
}